// Round 13
// baseline (820.879 us; speedup 1.0000x reference)
//
#include <hip/hip_runtime.h>
#include <cmath>

constexpr int N = 4096;
constexpr int EDG = 131072;
constexpr float GEPS = 1e-6f;

// ---------------------------------------------------------------------------
__device__ __forceinline__ float* blk_sums(float* vals, int cnt) {
  __shared__ float part[4][16];
  __shared__ float tot[16];
  const int lane = threadIdx.x & 63, wv = threadIdx.x >> 6;
  for (int c = 0; c < cnt; ++c) {
    float v = vals[c];
    for (int off = 32; off; off >>= 1) v += __shfl_down(v, off);
    if (lane == 0) part[wv][c] = v;
  }
  __syncthreads();
  if (threadIdx.x == 0)
    for (int c = 0; c < cnt; ++c)
      tot[c] = part[0][c] + part[1][c] + part[2][c] + part[3][c];
  __syncthreads();
  return tot;
}

// ---------------------------------------------------------------------------
// CSR build
__global__ void hist_edges(const int* __restrict__ ei, int* __restrict__ cnt) {
  int e = blockIdx.x * 256 + threadIdx.x;
  atomicAdd(&cnt[ei[e]], 1);
  atomicAdd(&cnt[N + ei[EDG + e]], 1);
}

__global__ __launch_bounds__(256) void scan2x(const int* __restrict__ cnt,
                                              int* __restrict__ rowptr,
                                              int* __restrict__ cur) {
  const int b = blockIdx.x;
  const int* c = cnt + b * N;
  int* rp = rowptr + b * (N + 1);
  int* cu = cur + b * N;
  __shared__ int part[256];
  const int t = threadIdx.x;
  int local[16], s = 0;
  const int base = t * 16;
  for (int i = 0; i < 16; ++i) { local[i] = s; s += c[base + i]; }
  part[t] = s;
  __syncthreads();
  if (t == 0) {
    int acc = 0;
    for (int i = 0; i < 256; ++i) { int v = part[i]; part[i] = acc; acc += v; }
  }
  __syncthreads();
  const int off = part[t];
  for (int i = 0; i < 16; ++i) { rp[base + i] = off + local[i]; cu[base + i] = off + local[i]; }
  if (t == 255) rp[N] = off + s;
}

__global__ void scatter_edges(const int* __restrict__ ei, int* __restrict__ cur,
                              int* __restrict__ col_s, int* __restrict__ perm_s,
                              int* __restrict__ col_d, int* __restrict__ perm_d) {
  int e = blockIdx.x * 256 + threadIdx.x;
  int s = ei[e], d = ei[EDG + e];
  int ps = atomicAdd(&cur[s], 1);
  col_s[ps] = d; perm_s[ps] = e;
  int pd = atomicAdd(&cur[N + d], 1);
  col_d[pd] = s; perm_d[pd] = e;
}

// gather edge weights into dst-CSR order + compute dis; optional omega colsums
__global__ void gatherdis_om(const float* __restrict__ s,
                             const int* __restrict__ perm_d,
                             float* __restrict__ wd_, const float* __restrict__ deg,
                             float* __restrict__ dis, const float* __restrict__ om1,
                             const float* __restrict__ om2, float* __restrict__ SC,
                             int omA, int omB) {
  int p = blockIdx.x * 256 + threadIdx.x;
  wd_[p] = s[perm_d[p]];
  if (p < N) dis[p] = rsqrtf(deg[p] + 1.0f);
  if (om1 && blockIdx.x < 16) {
    int n = p;  // < 4096
    float vals[12];
#pragma unroll
    for (int k = 0; k < 6; ++k) {
      vals[k] = om1[(size_t)n * 6 + k];
      vals[6 + k] = om2[(size_t)n * 6 + k];
    }
    float* tot = blk_sums(vals, 12);
    if (threadIdx.x == 0)
      for (int c = 0; c < 6; ++c) {
        atomicAdd(&SC[omA + c], tot[c]);
        atomicAdd(&SC[omB + c], tot[6 + c]);
      }
  }
}

// ---------------------------------------------------------------------------
// Split-K fused layer-1 GEMM (r13: split-K 4 for occupancy; atomics, pre-zeroed)
__global__ __launch_bounds__(256) void gemm512k(const float* __restrict__ A,
                                                const float* __restrict__ W1,
                                                const float* __restrict__ W2,
                                                float* __restrict__ O1,
                                                float* __restrict__ O2) {
  __shared__ float As[16][33];
  __shared__ float Ws[32][128];
  const int t = threadIdx.x;
  const int rt = t >> 4;
  const int ct = t & 15;
  const int r0 = blockIdx.x * 16;
  const int kh = blockIdx.y * 128;
  float acc[8];
#pragma unroll
  for (int j = 0; j < 8; ++j) acc[j] = 0.f;
  for (int kc = 0; kc < 128; kc += 32) {
    const int kb = kh + kc;
    __syncthreads();
    for (int i = t; i < 512; i += 256) {
      int rr = i >> 5, kk = i & 31;
      As[rr][kk] = A[(size_t)(r0 + rr) * 512 + kb + kk];
    }
    for (int i = t; i < 1024; i += 256) {
      int row = i >> 5, c4 = i & 31;
      float4 v;
      if (c4 < 16) v = *(const float4*)&W1[(size_t)(kb + row) * 64 + c4 * 4];
      else         v = *(const float4*)&W2[(size_t)(kb + row) * 64 + (c4 - 16) * 4];
      *(float4*)&Ws[row][c4 * 4] = v;
    }
    __syncthreads();
#pragma unroll
    for (int kk = 0; kk < 32; ++kk) {
      float a = As[rt][kk];
      float4 b0 = *(const float4*)&Ws[kk][ct * 4];
      float4 b1 = *(const float4*)&Ws[kk][64 + ct * 4];
      acc[0] += a * b0.x; acc[1] += a * b0.y;
      acc[2] += a * b0.z; acc[3] += a * b0.w;
      acc[4] += a * b1.x; acc[5] += a * b1.y;
      acc[6] += a * b1.z; acc[7] += a * b1.w;
    }
  }
  const int r = r0 + rt;
#pragma unroll
  for (int j = 0; j < 4; ++j) {
    atomicAdd(&O1[(size_t)r * 64 + ct * 4 + j], acc[j]);
    atomicAdd(&O2[(size_t)r * 64 + ct * 4 + j], acc[4 + j]);
  }
}

// Fused layer-2 GEMM (validated): O1[4096,32]=A@W1, O2[4096,16]=A@W2.
__global__ __launch_bounds__(256) void gemm64(const float* __restrict__ A,
                                              const float* __restrict__ W1,
                                              const float* __restrict__ W2,
                                              float* __restrict__ O1,
                                              float* __restrict__ O2) {
  __shared__ float As[32][65];
  __shared__ float Ws[64][48];
  const int t = threadIdx.x;
  const int r = t >> 3;
  const int cg = t & 7;
  const int r0 = blockIdx.x * 32;
  for (int idx = t; idx < 32 * 64; idx += 256)
    As[idx >> 6][idx & 63] = A[(size_t)(r0 + (idx >> 6)) * 64 + (idx & 63)];
  for (int idx = t; idx < 64 * 48; idx += 256) {
    int kk = idx / 48, c = idx % 48;
    Ws[kk][c] = (c < 32) ? W1[kk * 32 + c] : W2[kk * 16 + c - 32];
  }
  __syncthreads();
  float acc[6] = {0.f, 0.f, 0.f, 0.f, 0.f, 0.f};
  for (int k = 0; k < 64; ++k) {
    float a = As[r][k];
#pragma unroll
    for (int j = 0; j < 6; ++j) acc[j] += a * Ws[k][cg + 8 * j];
  }
  int n = r0 + r;
#pragma unroll
  for (int j = 0; j < 6; ++j) {
    int c = cg + 8 * j;
    if (c < 32) O1[(size_t)n * 32 + c] = acc[j];
    else O2[(size_t)n * 16 + c - 32] = acc[j];
  }
}

// ---------------------------------------------------------------------------
// edge gate 1 (r12 validated: src-CSR, source row broadcast, dest-only gather)
__global__ void edge_gate1c(const float* __restrict__ xw, const int* __restrict__ rp,
                            const int* __restrict__ cl, const int* __restrict__ perm,
                            const float* __restrict__ b1, const float* __restrict__ w2,
                            const float* __restrict__ b2, float* __restrict__ s_out,
                            float* __restrict__ wcs, float* __restrict__ deg,
                            float* __restrict__ SCs) {
  const int lane = threadIdx.x & 63;
  const int wave = threadIdx.x >> 6;
  const int u = lane >> 4;
  const int q = lane & 15;
  const float4 b1q = ((const float4*)b1)[q];
  const float4 w2q = ((const float4*)w2)[q];
  const float b2s = b2[0];
  const float4* xw4 = (const float4*)xw;
  const int r = blockIdx.x * 4 + wave;
  const float4 xsr = xw4[(size_t)r * 16 + q];
  const int e0 = rp[r], e1 = rp[r + 1];
  float lsum = 0.f, lssq = 0.f;
  int e = e0 + u;
  for (; e + 4 < e1; e += 8) {
    int d0 = cl[e], d1 = cl[e + 4];
    float4 xd0 = xw4[(size_t)d0 * 16 + q];
    float4 xd1 = xw4[(size_t)d1 * 16 + q];
    float g0 = fmaxf(xsr.x - xd0.x + b1q.x, 0.f) * w2q.x
             + fmaxf(xsr.y - xd0.y + b1q.y, 0.f) * w2q.y
             + fmaxf(xsr.z - xd0.z + b1q.z, 0.f) * w2q.z
             + fmaxf(xsr.w - xd0.w + b1q.w, 0.f) * w2q.w;
    float g1 = fmaxf(xsr.x - xd1.x + b1q.x, 0.f) * w2q.x
             + fmaxf(xsr.y - xd1.y + b1q.y, 0.f) * w2q.y
             + fmaxf(xsr.z - xd1.z + b1q.z, 0.f) * w2q.z
             + fmaxf(xsr.w - xd1.w + b1q.w, 0.f) * w2q.w;
#pragma unroll
    for (int off = 1; off < 16; off <<= 1) {
      g0 += __shfl_xor(g0, off);
      g1 += __shfl_xor(g1, off);
    }
    if (q == 0) {
      float a0 = g0 + b2s; a0 *= a0;
      float a1 = g1 + b2s; a1 *= a1;
      float s0 = 1.f / (1.f + __expf(-a0));
      float s1 = 1.f / (1.f + __expf(-a1));
      s_out[perm[e]] = s0;     wcs[e] = s0;
      s_out[perm[e + 4]] = s1; wcs[e + 4] = s1;
      atomicAdd(&deg[d0], s0);
      atomicAdd(&deg[d1], s1);
      lsum += s0 + s1; lssq += s0 * s0 + s1 * s1;
    }
  }
  for (; e < e1; e += 4) {
    int d = cl[e];
    float4 xd = xw4[(size_t)d * 16 + q];
    float g = fmaxf(xsr.x - xd.x + b1q.x, 0.f) * w2q.x
            + fmaxf(xsr.y - xd.y + b1q.y, 0.f) * w2q.y
            + fmaxf(xsr.z - xd.z + b1q.z, 0.f) * w2q.z
            + fmaxf(xsr.w - xd.w + b1q.w, 0.f) * w2q.w;
#pragma unroll
    for (int off = 1; off < 16; off <<= 1) g += __shfl_xor(g, off);
    if (q == 0) {
      float a = g + b2s; a *= a;
      float sv = 1.f / (1.f + __expf(-a));
      s_out[perm[e]] = sv; wcs[e] = sv;
      atomicAdd(&deg[d], sv);
      lsum += sv; lssq += sv * sv;
    }
  }
  float* tot = blk_sums(&lsum, 1);
  float* tot2 = blk_sums(&lssq, 1);
  if (threadIdx.x == 0) {
    atomicAdd(&SCs[0], tot[0]);
    atomicAdd(&SCs[1], tot2[0]);
  }
}

// edge gate 2 (r12 validated: src-CSR order, 8 slots x 8 quads)
__global__ void edge_gate2c(const float* __restrict__ xw, const int* __restrict__ rp,
                            const int* __restrict__ cl, const int* __restrict__ perm,
                            const float* __restrict__ b1, const float* __restrict__ w2,
                            const float* __restrict__ b2, float* __restrict__ s_out,
                            float* __restrict__ wcs, float* __restrict__ deg,
                            float* __restrict__ SCs) {
  const int lane = threadIdx.x & 63;
  const int wave = threadIdx.x >> 6;
  const int u = lane >> 3;
  const int q = lane & 7;
  const float4 b1q = ((const float4*)b1)[q];
  const float4 w2q = ((const float4*)w2)[q];
  const float b2s = b2[0];
  const float4* xw4 = (const float4*)xw;
  const int r = blockIdx.x * 4 + wave;
  const float4 xsr = xw4[(size_t)r * 8 + q];
  const int e0 = rp[r], e1 = rp[r + 1];
  float lsum = 0.f, lssq = 0.f;
  int e = e0 + u;
  for (; e + 8 < e1; e += 16) {
    int d0 = cl[e], d1 = cl[e + 8];
    float4 xd0 = xw4[(size_t)d0 * 8 + q];
    float4 xd1 = xw4[(size_t)d1 * 8 + q];
    float g0 = fmaxf(xsr.x - xd0.x + b1q.x, 0.f) * w2q.x
             + fmaxf(xsr.y - xd0.y + b1q.y, 0.f) * w2q.y
             + fmaxf(xsr.z - xd0.z + b1q.z, 0.f) * w2q.z
             + fmaxf(xsr.w - xd0.w + b1q.w, 0.f) * w2q.w;
    float g1 = fmaxf(xsr.x - xd1.x + b1q.x, 0.f) * w2q.x
             + fmaxf(xsr.y - xd1.y + b1q.y, 0.f) * w2q.y
             + fmaxf(xsr.z - xd1.z + b1q.z, 0.f) * w2q.z
             + fmaxf(xsr.w - xd1.w + b1q.w, 0.f) * w2q.w;
#pragma unroll
    for (int off = 1; off < 8; off <<= 1) {
      g0 += __shfl_xor(g0, off);
      g1 += __shfl_xor(g1, off);
    }
    if (q == 0) {
      float a0 = g0 + b2s; a0 *= a0;
      float a1 = g1 + b2s; a1 *= a1;
      float s0 = 1.f / (1.f + __expf(-a0));
      float s1 = 1.f / (1.f + __expf(-a1));
      s_out[perm[e]] = s0;     wcs[e] = s0;
      s_out[perm[e + 8]] = s1; wcs[e + 8] = s1;
      atomicAdd(&deg[d0], s0);
      atomicAdd(&deg[d1], s1);
      lsum += s0 + s1; lssq += s0 * s0 + s1 * s1;
    }
  }
  for (; e < e1; e += 8) {
    int d = cl[e];
    float4 xd = xw4[(size_t)d * 8 + q];
    float g = fmaxf(xsr.x - xd.x + b1q.x, 0.f) * w2q.x
            + fmaxf(xsr.y - xd.y + b1q.y, 0.f) * w2q.y
            + fmaxf(xsr.z - xd.z + b1q.z, 0.f) * w2q.z
            + fmaxf(xsr.w - xd.w + b1q.w, 0.f) * w2q.w;
#pragma unroll
    for (int off = 1; off < 8; off <<= 1) g += __shfl_xor(g, off);
    if (q == 0) {
      float a = g + b2s; a *= a;
      float sv = 1.f / (1.f + __expf(-a));
      s_out[perm[e]] = sv; wcs[e] = sv;
      atomicAdd(&deg[d], sv);
      lsum += sv; lssq += sv * sv;
    }
  }
  float* tot = blk_sums(&lsum, 1);
  float* tot2 = blk_sums(&lssq, 1);
  if (threadIdx.x == 0) {
    atomicAdd(&SCs[2], tot[0]);
    atomicAdd(&SCs[3], tot2[0]);
  }
}

// conv1 fused (r11 validated)
__global__ void conv1f(const int* __restrict__ rp, const int* __restrict__ cl,
                       const float* __restrict__ w, const float* __restrict__ h1,
                       const float* __restrict__ dis, const float* __restrict__ bias,
                       float* __restrict__ x1) {
  const int lane = threadIdx.x & 63, wv = threadIdx.x >> 6;
  const int es = lane >> 4;
  const int q = lane & 15;
  const int r = blockIdx.x * 4 + wv;
  const int e0 = rp[r], e1 = rp[r + 1];
  const float4* h14 = (const float4*)h1;
  float ax = 0.f, ay = 0.f, az = 0.f, aw = 0.f;
  int e = e0 + es;
  for (; e + 4 < e1; e += 8) {
    int c0 = cl[e], c1 = cl[e + 4];
    float w0 = w[e] * dis[c0], w1_ = w[e + 4] * dis[c1];
    float4 h0 = h14[(size_t)c0 * 16 + q];
    float4 h1v = h14[(size_t)c1 * 16 + q];
    ax += w0 * h0.x + w1_ * h1v.x;
    ay += w0 * h0.y + w1_ * h1v.y;
    az += w0 * h0.z + w1_ * h1v.z;
    aw += w0 * h0.w + w1_ * h1v.w;
  }
  for (; e < e1; e += 4) {
    int c = cl[e];
    float wx = w[e] * dis[c];
    float4 hv = h14[(size_t)c * 16 + q];
    ax += wx * hv.x; ay += wx * hv.y; az += wx * hv.z; aw += wx * hv.w;
  }
  ax += __shfl_xor(ax, 16); ax += __shfl_xor(ax, 32);
  ay += __shfl_xor(ay, 16); ay += __shfl_xor(ay, 32);
  az += __shfl_xor(az, 16); az += __shfl_xor(az, 32);
  aw += __shfl_xor(aw, 16); aw += __shfl_xor(aw, 32);
  if (es == 0) {
    float d = dis[r];
    float4 hh = h14[(size_t)r * 16 + q];
    float4 bq = ((const float4*)bias)[q];
    float4 o;
    o.x = fmaxf(d * (ax + d * hh.x) + bq.x, 0.f);
    o.y = fmaxf(d * (ay + d * hh.y) + bq.y, 0.f);
    o.z = fmaxf(d * (az + d * hh.z) + bq.z, 0.f);
    o.w = fmaxf(d * (aw + d * hh.w) + bq.w, 0.f);
    ((float4*)x1)[(size_t)r * 16 + q] = o;
  }
}

// conv2 fused -> logits (r11 validated)
__global__ void conv2f(const int* __restrict__ rp, const int* __restrict__ cl,
                       const float* __restrict__ w, const float* __restrict__ h2,
                       const float* __restrict__ dis, const float* __restrict__ bias,
                       float* __restrict__ xo) {
  const int lane = threadIdx.x & 63, wv = threadIdx.x >> 6;
  const int es = lane >> 2;
  const int q = lane & 3;
  const int r = blockIdx.x * 4 + wv;
  const int e0 = rp[r], e1 = rp[r + 1];
  const float4* h24 = (const float4*)h2;
  float ax = 0.f, ay = 0.f, az = 0.f, aw = 0.f;
  for (int e = e0 + es; e < e1; e += 16) {
    int c = cl[e];
    float wx = w[e] * dis[c];
    float4 hv = h24[(size_t)c * 4 + q];
    ax += wx * hv.x; ay += wx * hv.y; az += wx * hv.z; aw += wx * hv.w;
  }
#pragma unroll
  for (int off = 4; off < 64; off <<= 1) {
    ax += __shfl_xor(ax, off);
    ay += __shfl_xor(ay, off);
    az += __shfl_xor(az, off);
    aw += __shfl_xor(aw, off);
  }
  if (es == 0) {
    float d = dis[r];
    float4 hh = h24[(size_t)r * 4 + q];
    float4 bq = ((const float4*)bias)[q];
    float4 o;
    o.x = d * (ax + d * hh.x) + bq.x;
    o.y = d * (ay + d * hh.y) + bq.y;
    o.z = d * (az + d * hh.z) + bq.z;
    o.w = d * (aw + d * hh.w) + bq.w;
    ((float4*)xo)[(size_t)r * 4 + q] = o;
  }
}

// softmax + calib from logits (validated r3/r5)
__global__ void softmax_calib(const float* __restrict__ xo, float* __restrict__ ls,
                              float* __restrict__ sm, float* __restrict__ SC) {
  const int t = threadIdx.x;
  const int r = blockIdx.x * 256 + t;
  float v[16];
  float mx = -3.0e38f, mx2 = -3.0e38f;
#pragma unroll
  for (int c = 0; c < 16; ++c) {
    v[c] = xo[(size_t)r * 16 + c];
    if (v[c] > mx) { mx2 = mx; mx = v[c]; }
    else if (v[c] > mx2) mx2 = v[c];
  }
  float se = 0.f;
#pragma unroll
  for (int c = 0; c < 16; ++c) se += expf(v[c] - mx);
  const float lse = mx + logf(se);
#pragma unroll
  for (int c = 0; c < 16; ++c) {
    float z = v[c] - lse;
    ls[(size_t)r * 16 + c] = z;
    sm[(size_t)r * 16 + c] = expf(z);
  }
  float calib = mx2 - mx;
  float* tot = blk_sums(&calib, 1);
  if (t == 0) atomicAdd(&SC[4], tot[0]);
}

// ---------------------------------------------------------------------------
// Fused SVD power step (r8) with fp32 Cholesky prologue (r9).
template<int NORM, int SX>
__global__ __launch_bounds__(256) void spmm8f(
    const int* __restrict__ rp, const int* __restrict__ cl,
    const float* __restrict__ wA, const float* __restrict__ wB,
    const float* __restrict__ XA, const float* __restrict__ XB,
    float* __restrict__ OA, float* __restrict__ OB,
    const double* __restrict__ GpA, const double* __restrict__ GpB,
    double* __restrict__ GnA, double* __restrict__ GnB,
    float* __restrict__ SC, int cspA, int cspB, int csoA, int csoB) {
  __shared__ float Rinv[2][36];
  __shared__ float csn[2][8];
  __shared__ float bs[2][8];
  __shared__ float gpart[8][21];
  const int t = threadIdx.x;
  if (NORM) {
    if (t < 2) {
      const double* G = t ? GpB : GpA;
      const float* csp = SC + (t ? cspB : cspA);
      float Gf[6][6];
      int p = 0;
      for (int i = 0; i < 6; ++i)
        for (int j = i; j < 6; ++j) { float gv = (float)G[p]; Gf[i][j] = gv; Gf[j][i] = gv; ++p; }
      float Rm[6][6];
      for (int i = 0; i < 6; ++i) for (int j = 0; j < 6; ++j) Rm[i][j] = 0.f;
      for (int j = 0; j < 6; ++j) {
        float s = Gf[j][j];
        for (int k = 0; k < j; ++k) s -= Rm[k][j] * Rm[k][j];
        float dj = sqrtf(fmaxf(s, 1e-30f));
        Rm[j][j] = dj;
        for (int i = j + 1; i < 6; ++i) {
          float v = Gf[j][i];
          for (int k = 0; k < j; ++k) v -= Rm[k][j] * Rm[k][i];
          Rm[j][i] = v / dj;
        }
      }
      float Ri[6][6];
      for (int j = 0; j < 6; ++j) {
        Ri[j][j] = 1.f / Rm[j][j];
        for (int i = j - 1; i >= 0; --i) {
          float s = 0.f;
          for (int k = i + 1; k <= j; ++k) s += Rm[i][k] * Ri[k][j];
          Ri[i][j] = -s / Rm[i][i];
        }
      }
      for (int i = 0; i < 6; ++i)
        for (int j = 0; j < 6; ++j)
          Rinv[t][i * 6 + j] = (j >= i) ? Ri[i][j] : 0.f;
      for (int f = 0; f < 8; ++f) {
        float s = 0.f;
        if (f < 6)
          for (int j = 0; j <= f; ++j) s += csp[j] * Ri[j][f];
        csn[t][f] = s;
      }
    }
  } else {
    if (t < 16) {
      int h = t >> 3, f = t & 7;
      csn[h][f] = (f < 6) ? SC[(h ? cspB : cspA) + f] : 0.f;
    }
  }
  if (t < 16) bs[t >> 3][t & 7] = 0.f;
  __syncthreads();
  const int lane = t & 63, wv = t >> 6;
  const int half = lane >> 5, la = lane & 31;
  const int f = la & 7, es = la >> 3;
  const float* w = half ? wB : wA;
  const float* X = half ? XB : XA;
  float* O = half ? OB : OA;
  const float* Ri = Rinv[half];
  const float epsf = csn[half][f] * GEPS;
  float gp[6];
#pragma unroll
  for (int j = 0; j < 6; ++j) gp[j] = 0.f;
  for (int rr = 0; rr < 2; ++rr) {
    const int r = blockIdx.x * 8 + wv * 2 + rr;
    const int e0 = rp[r], e1 = rp[r + 1];
    float acc = 0.f;
    if (f < 6) {
      for (int e = e0 + es; e < e1; e += 4) {
        int c = cl[e];
        const float* xr = X + (size_t)c * SX;
        float xn;
        if (NORM) {
          xn = 0.f;
          for (int j = 0; j <= f; ++j) xn += xr[j] * Ri[j * 6 + f];
        } else {
          xn = xr[f];
        }
        acc += w[e] * xn;
      }
    }
    acc += __shfl_xor(acc, 8);
    acc += __shfl_xor(acc, 16);
    float o = acc + epsf;
    float ov[6];
#pragma unroll
    for (int j = 0; j < 6; ++j) ov[j] = __shfl(o, half * 32 + j);
    if (es == 0) {
      O[((size_t)r << 3) + f] = o;
      if (f < 6) {
        atomicAdd(&bs[half][f], o);
#pragma unroll
        for (int j = 0; j < 6; ++j)
          if (j >= f) gp[j - f] += o * ov[j];
      }
    }
  }
  if (es == 0 && f < 6) {
    int p0 = f * 6 - (f * (f - 1)) / 2;
    for (int j = 0; j < 6 - f; ++j) gpart[wv * 2 + half][p0 + j] = gp[j];
  }
  __syncthreads();
  if (t < 42) {
    int h = t / 21, p = t % 21;
    float s = gpart[h][p] + gpart[2 + h][p] + gpart[4 + h][p] + gpart[6 + h][p];
    atomicAdd(&(h ? GnB : GnA)[p], (double)s);
  }
  if (t < 16) {
    int h = t >> 3, ff = t & 7;
    if (ff < 6) atomicAdd(&SC[(h ? csoB : csoA) + ff], bs[h][ff]);
  }
}

// ---------------------------------------------------------------------------
// single-graph SpMM (p-passes)
template<int F, int DIS>
__global__ __launch_bounds__(256) void spmm(const int* __restrict__ rowptr,
                                            const int* __restrict__ col,
                                            const float* __restrict__ w,
                                            const float* __restrict__ X,
                                            const float* __restrict__ dis,
                                            float* __restrict__ OUT,
                                            float* __restrict__ SC, int cs_idx,
                                            float eps, int osum, int ossq) {
  constexpr int ES = 64 / F;
  const int lane = threadIdx.x & 63;
  const int wv = threadIdx.x >> 6;
  const int f = lane & (F - 1);
  const int es = lane / F;
  const int r = blockIdx.x * 4 + wv;
  const int e0 = rowptr[r], e1 = rowptr[r + 1];
  float acc = 0.f;
  for (int e = e0 + es; e < e1; e += ES) {
    int c = col[e];
    float wx = w[e];
    if (DIS) wx *= dis[c];
    acc += wx * X[(size_t)c * F + f];
  }
#pragma unroll
  for (int off = F; off < 64; off <<= 1) acc += __shfl_xor(acc, off);
  float o = acc + ((cs_idx >= 0) ? eps * SC[cs_idx + f] : 0.f);
  if (es == 0) OUT[(size_t)r * F + f] = o;
  if (osum >= 0 || ossq >= 0) {
    __shared__ float bs[8], bq[8];
    if (threadIdx.x < F) { bs[threadIdx.x] = 0.f; bq[threadIdx.x] = 0.f; }
    __syncthreads();
    if (es == 0) {
      if (osum >= 0) atomicAdd(&bs[f], o);
      if (ossq >= 0) atomicAdd(&bq[f], o * o);
    }
    __syncthreads();
    if (threadIdx.x < F) {
      if (osum >= 0) atomicAdd(&SC[osum + threadIdx.x], bs[threadIdx.x]);
      if (ossq >= 0) atomicAdd(&SC[ossq + threadIdx.x], bq[threadIdx.x]);
    }
  }
}

// Batched two-graph SpMM (validated r5)
template<int FA, int FB>
__global__ __launch_bounds__(256) void spmm2(const int* __restrict__ rowptr,
                                             const int* __restrict__ col,
                                             const float* __restrict__ wA,
                                             const float* __restrict__ wB,
                                             const float* __restrict__ XA,
                                             const float* __restrict__ XB,
                                             float* __restrict__ OA,
                                             float* __restrict__ OB,
                                             float* __restrict__ SC,
                                             int csA, int csB, float eps,
                                             int osumA, int ossqA, int osumB, int ossqB) {
  const int lane = threadIdx.x & 63;
  const int wv = threadIdx.x >> 6;
  const int half = lane >> 5;
  const int la = lane & 31;
  const int F = half ? FB : FA;
  const int f = la & (F - 1);
  const int es = la / F;
  const int ES = 32 / F;
  const int r = blockIdx.x * 4 + wv;
  const int e0 = rowptr[r], e1 = rowptr[r + 1];
  const float* w = half ? wB : wA;
  const float* X = half ? XB : XA;
  float acc = 0.f;
  for (int e = e0 + es; e < e1; e += ES)
    acc += w[e] * X[(size_t)col[e] * F + f];
  for (int off = F; off < 32; off <<= 1) acc += __shfl_xor(acc, off);
  const int cs = half ? csB : csA;
  float o = acc + ((cs >= 0) ? eps * SC[cs + f] : 0.f);
  if (es == 0) {
    float* O = half ? OB : OA;
    O[(size_t)r * F + f] = o;
  }
  if (osumA >= 0 || ossqA >= 0 || osumB >= 0 || ossqB >= 0) {
    __shared__ float bs[2][8], bq[2][8];
    if (threadIdx.x < 16) { bs[threadIdx.x >> 3][threadIdx.x & 7] = 0.f;
                            bq[threadIdx.x >> 3][threadIdx.x & 7] = 0.f; }
    __syncthreads();
    const int osum = half ? osumB : osumA, ossq = half ? ossqB : ossqA;
    if (es == 0) {
      if (osum >= 0) atomicAdd(&bs[half][f], o);
      if (ossq >= 0) atomicAdd(&bq[half][f], o * o);
    }
    __syncthreads();
    if (threadIdx.x < 16) {
      int h = threadIdx.x >> 3, ff = threadIdx.x & 7;
      int os_ = h ? osumB : osumA, oq_ = h ? ossqB : ossqA;
      int Fh = h ? FB : FA;
      if (os_ >= 0 && ff < Fh) atomicAdd(&SC[os_ + ff], bs[h][ff]);
      if (oq_ >= 0 && ff < Fh) atomicAdd(&SC[oq_ + ff], bq[h][ff]);
    }
  }
}

// ---------------------------------------------------------------------------
// r13: serial per-thread fp32 6x6 Jacobi (2 threads, one graph each, 6 sweeps
// + early exit). No cross-lane shuffles — shortest dependent chain.
__global__ void jacobi2(const double* __restrict__ GA,
                        const double* __restrict__ GB,
                        float* __restrict__ SMFA, float* __restrict__ SMFB) {
  const int t = threadIdx.x;
  if (t >= 2) return;
  const double* G = t ? GB : GA;
  float* SMF = t ? SMFB : SMFA;
  float A[6][6], V[6][6];
  int p = 0;
  for (int i = 0; i < 6; ++i)
    for (int j = i; j < 6; ++j) { float gv = (float)G[p]; A[i][j] = gv; A[j][i] = gv; ++p; }
  float tr = 0.f;
  for (int i = 0; i < 6; ++i) tr += fabsf(A[i][i]);
  const float tol = 1e-14f * tr * tr + 1e-30f;
  for (int i = 0; i < 6; ++i)
    for (int j = 0; j < 6; ++j) V[i][j] = (i == j) ? 1.f : 0.f;
  for (int sweep = 0; sweep < 6; ++sweep) {
    float off = 0.f;
    for (int i = 0; i < 6; ++i)
      for (int j = i + 1; j < 6; ++j) off += A[i][j] * A[i][j];
    if (off < tol) break;
    for (int pi = 0; pi < 5; ++pi)
      for (int qi = pi + 1; qi < 6; ++qi) {
        float apq = A[pi][qi];
        if (fabsf(apq) < 1e-30f) continue;
        float app = A[pi][pi], aqq = A[qi][qi];
        float tau = (aqq - app) / (2.f * apq);
        float tt = (tau >= 0.f) ? 1.f / (tau + sqrtf(1.f + tau * tau))
                                : 1.f / (tau - sqrtf(1.f + tau * tau));
        float c = rsqrtf(1.f + tt * tt), s = tt * c;
        for (int k = 0; k < 6; ++k) {
          float akp = A[k][pi], akq = A[k][qi];
          A[k][pi] = c * akp - s * akq; A[k][qi] = s * akp + c * akq;
        }
        for (int k = 0; k < 6; ++k) {
          float apk = A[pi][k], aqk = A[qi][k];
          A[pi][k] = c * apk - s * aqk; A[qi][k] = s * apk + c * aqk;
        }
        for (int k = 0; k < 6; ++k) {
          float vkp = V[k][pi], vkq = V[k][qi];
          V[k][pi] = c * vkp - s * vkq; V[k][qi] = s * vkp + c * vkq;
        }
      }
  }
  int idx[6] = {0, 1, 2, 3, 4, 5};
  for (int a = 0; a < 5; ++a)
    for (int b = 0; b < 5 - a; ++b)
      if (A[idx[b]][idx[b]] < A[idx[b + 1]][idx[b + 1]]) {
        int tmp = idx[b]; idx[b] = idx[b + 1]; idx[b + 1] = tmp;
      }
  for (int k = 0; k < 6; ++k) {
    float lam = A[idx[k]][idx[k]];
    SMF[36 + k] = rsqrtf(fmaxf(lam, 1e-30f));
    for (int j = 0; j < 6; ++j) SMF[j * 6 + k] = V[j][idx[k]];
  }
}

// v_scale2 + pack3 fused (r9)
__global__ void v_scale_pack(const float* __restrict__ BtA, const float* __restrict__ SMFA,
                             const float* __restrict__ BtB, const float* __restrict__ SMFB,
                             float* __restrict__ V8A, float* __restrict__ V8B,
                             float* __restrict__ WA, float* __restrict__ WB,
                             float* __restrict__ SC, int sA, int sB) {
  __shared__ float WsA[36], rsA[6], WsB[36], rsB[6];
  if (threadIdx.x < 36) { WsA[threadIdx.x] = SMFA[threadIdx.x]; WsB[threadIdx.x] = SMFB[threadIdx.x]; }
  if (threadIdx.x < 6) { rsA[threadIdx.x] = SMFA[36 + threadIdx.x]; rsB[threadIdx.x] = SMFB[36 + threadIdx.x]; }
  __syncthreads();
  int n = blockIdx.x * 256 + threadIdx.x;
  float ba[6], bb[6];
#pragma unroll
  for (int j = 0; j < 6; ++j) { ba[j] = BtA[(size_t)n * 8 + j]; bb[j] = BtB[(size_t)n * 8 + j]; }
  float vals[6];
#pragma unroll
  for (int k = 0; k < 6; ++k) {
    float sa = 0.f, sb = 0.f;
#pragma unroll
    for (int j = 0; j < 6; ++j) { sa += ba[j] * WsA[j * 6 + k]; sb += bb[j] * WsB[j * 6 + k]; }
    sa *= rsA[k]; sb *= rsB[k];
    V8A[(size_t)n * 8 + k] = sa;
    V8B[(size_t)n * 8 + k] = sb;
    if (k < 3) {
      WA[(size_t)n * 4 + k] = sa;
      WB[(size_t)n * 4 + k] = sb;
      vals[k] = sa; vals[3 + k] = sb;
    }
  }
  V8A[(size_t)n * 8 + 6] = 0.f; V8A[(size_t)n * 8 + 7] = 0.f;
  V8B[(size_t)n * 8 + 6] = 0.f; V8B[(size_t)n * 8 + 7] = 0.f;
  WA[(size_t)n * 4 + 3] = 0.f;
  WB[(size_t)n * 4 + 3] = 0.f;
  float* tot = blk_sums(vals, 6);
  if (threadIdx.x == 0)
    for (int c = 0; c < 3; ++c) {
      atomicAdd(&SC[sA + c], tot[c]);
      atomicAdd(&SC[sB + c], tot[3 + c]);
    }
}

// after 3rd batch3 spmm: accum sigma0-2 + Uv0 scale + p0-W build
__global__ void b3post(const float* __restrict__ YA, const float* __restrict__ YB,
                       const float* __restrict__ ZZB, float* __restrict__ UvA,
                       float* __restrict__ UvB, float* __restrict__ WB,
                       float* __restrict__ SC, int zzA, int nyA, int zzB, int nyB,
                       int sWp) {
  if (blockIdx.x == 0 && threadIdx.x == 0) {
    float add = 0.f;
    for (int k = 0; k < 3; ++k) add += sqrtf(fabsf(SC[zzA + k] / SC[nyA + k]));
    for (int k = 0; k < 3; ++k) add += sqrtf(fabsf(SC[zzB + k] / SC[nyB + k]));
    SC[5] += add;
  }
  int n = blockIdx.x * 256 + threadIdx.x;
  UvA[n] = YA[(size_t)n * 4 + 2] * rsqrtf(SC[nyA + 2]);
  UvB[n] = YB[(size_t)n * 4 + 2] * rsqrtf(SC[nyB + 2]);
  float v = ZZB[(size_t)n * 4 + 2] * rsqrtf(SC[nyB + 2]);
  WB[(size_t)n * 4 + 0] = v;
  WB[(size_t)n * 4 + 1] = 0.f;
  WB[(size_t)n * 4 + 2] = 0.f;
  WB[(size_t)n * 4 + 3] = 0.f;
  float* tot = blk_sums(&v, 1);
  if (threadIdx.x == 0) atomicAdd(&SC[sWp], tot[0]);
}

// batched deflation builds (r5/r9 validated)
__global__ void buildAB(float* __restrict__ WA, int FCpad, int nt, int nu,
                        const float* __restrict__ V8A, int kcol,
                        const float* __restrict__ UvA, float* __restrict__ SC, int sWa,
                        float* __restrict__ WB, const float* __restrict__ V8B,
                        const float* __restrict__ UvB, int nd, int sWb, int Cidx,
                        const float* __restrict__ P4, float* __restrict__ Pv,
                        int pvmode, int prevdp, int prevny) {
  const int bid = blockIdx.x;
  const int n = (bid & 15) * 256 + threadIdx.x;
  if (bid < 16) {
    float bv = V8A[(size_t)n * 8 + kcol];
    float uv[3];
    for (int b = 0; b < 3; ++b) uv[b] = (b < nu) ? UvA[(size_t)b * N + n] : 0.f;
    float vals[8];
    for (int t = 0; t < FCpad; ++t) {
      float v = 0.f;
      if (t < nt) {
        v = bv;
        for (int b = 0; b < nu; ++b)
          if ((t >> b) & 1) v *= uv[b];
      }
      WA[(size_t)n * FCpad + t] = v;
      vals[t] = v;
    }
    float* tot = blk_sums(vals, nt);
    if (threadIdx.x == 0)
      for (int c = 0; c < nt; ++c) atomicAdd(&SC[sWa + c], tot[c]);
  } else {
    if (pvmode == 1) {
      Pv[n] = P4[(size_t)n * 4];
    } else if (pvmode >= 2) {
      float crs = rsqrtf(SC[prevny]);
      float s = P4[(size_t)n * 4];
      s -= SC[prevdp + 1] * crs * Pv[n];
      if (pvmode == 3) s -= SC[prevdp + 3] * crs * Pv[(size_t)N + n];
      Pv[(size_t)(pvmode - 1) * N + n] = s;
    }
    float v = V8B[(size_t)n * 8 + kcol];
    WB[(size_t)n * 4 + 0] = v;
    WB[(size_t)n * 4 + 1] = 0.f;
    WB[(size_t)n * 4 + 2] = 0.f;
    WB[(size_t)n * 4 + 3] = 0.f;
    float vals[4];
    vals[0] = v;
    for (int t = 0; t < 3; ++t) vals[1 + t] = (t < nd) ? UvB[(size_t)t * N + n] * v : 0.f;
    float* tot = blk_sums(vals, 1 + nd);
    if (threadIdx.x == 0) {
      atomicAdd(&SC[sWb], tot[0]);
      for (int t = 0; t < nd; ++t) atomicAdd(&SC[Cidx + t], tot[1 + t]);
    }
  }
}

// fused epilogue + 2nd build (r9 validated)
__global__ void epibuild(const float* __restrict__ YA, int FA, int nt, int nu,
                         const float* __restrict__ UvA, float* __restrict__ yvA, int nyA2,
                         float* __restrict__ WA, int sW2a,
                         const float* __restrict__ YB, const float* __restrict__ Pv,
                         const float* __restrict__ UvB, int nd, float* __restrict__ yvB,
                         int Cidx, int nyB2, int dp, float* __restrict__ WB, int sW2b,
                         float* __restrict__ SC) {
  const int bid = blockIdx.x;
  const int n = (bid & 15) * 256 + threadIdx.x;
  if (bid < 16) {
    float uv[3];
    for (int b = 0; b < 3; ++b) uv[b] = (b < nu) ? UvA[(size_t)b * N + n] : 0.f;
    float s = 0.f;
    for (int t = 0; t < nt; ++t) {
      float w = YA[(size_t)n * FA + t];
      int pc = 0;
      for (int b = 0; b < nu; ++b)
        if ((t >> b) & 1) { w *= uv[b]; ++pc; }
      s += (pc & 1) ? -w : w;
    }
    yvA[n] = s;
    float v = s * s;
    float* tot = blk_sums(&v, 1);
    if (threadIdx.x == 0) atomicAdd(&SC[nyA2], tot[0]);
    float vals[8];
    for (int t = 0; t < FA; ++t) {
      float v2 = 0.f;
      if (t < nt) {
        v2 = s;
        for (int b = 0; b < nu; ++b)
          if ((t >> b) & 1) v2 *= uv[b];
      }
      WA[(size_t)n * FA + t] = v2;
      vals[t] = v2;
    }
    float* tot2 = blk_sums(vals, nt);
    if (threadIdx.x == 0)
      for (int c = 0; c < nt; ++c) atomicAdd(&SC[sW2a + c], tot2[c]);
  } else {
    float y = YB[(size_t)n * 4];
    for (int t = 0; t < nd; ++t) y -= SC[Cidx + t] * Pv[(size_t)t * N + n];
    yvB[n] = y;
    float vals[7];
    vals[0] = y * y;
    for (int t = 0; t < 3; ++t) {
      vals[1 + 2 * t] = (t < nd) ? y * Pv[(size_t)t * N + n] : 0.f;
      vals[2 + 2 * t] = (t < nd) ? UvB[(size_t)t * N + n] * y : 0.f;
    }
    float* tot = blk_sums(vals, 1 + 2 * nd);
    if (threadIdx.x == 0) {
      atomicAdd(&SC[nyB2], tot[0]);
      for (int i = 0; i < 2 * nd; ++i) atomicAdd(&SC[dp + i], tot[1 + i]);
    }
    WB[(size_t)n * 4 + 0] = y;
    WB[(size_t)n * 4 + 1] = 0.f;
    WB[(size_t)n * 4 + 2] = 0.f;
    WB[(size_t)n * 4 + 3] = 0.f;
    float yy = y;
    float* tot2 = blk_sums(&yy, 1);
    if (threadIdx.x == 0) atomicAdd(&SC[sW2b], tot2[0]);
  }
}

// per-k post: accum + (dobuild) Uv scale + next-p W build + (dofin) finalize
__global__ void defpost(float* __restrict__ SC, int zzA2, int nt, int nyA2,
                        int zzB2, int nyB2, int dp, int nd,
                        const float* __restrict__ yvA, const float* __restrict__ yvB,
                        float* __restrict__ UvA, float* __restrict__ UvB, int k,
                        const float* __restrict__ ZZB, float* __restrict__ WB,
                        int sW3, int dobuild, int dofin, float* __restrict__ outp) {
  if (blockIdx.x == 0 && threadIdx.x == 0) {
    float vmv = 0.f;
    for (int t = 0; t < nt; ++t) {
      int pc = __popc(t);
      vmv += (pc & 1) ? -SC[zzA2 + t] : SC[zzA2 + t];
    }
    float add = sqrtf(fabsf(vmv / SC[nyA2]));
    float vb = SC[zzB2];
    for (int t = 0; t < nd; ++t) vb -= SC[dp + 2 * t] * SC[dp + 2 * t + 1];
    add += sqrtf(fabsf(vb / SC[nyB2]));
    SC[5] += add;
    if (dofin) {
      const float Ef = (float)EDG;
      float m1 = SC[0] / Ef, v1 = SC[1] / Ef - m1 * m1;
      float m2 = SC[2] / Ef, v2 = SC[3] / Ef - m2 * m2;
      outp[131072] = 0.01f * (v1 + v2) + 0.01f * SC[5];
      outp[393217] = SC[4] / (float)N;
    }
  }
  if (dobuild) {
    int n = blockIdx.x * 256 + threadIdx.x;
    UvA[(size_t)(k - 2) * N + n] = yvA[n] * rsqrtf(SC[nyA2]);
    UvB[(size_t)(k - 2) * N + n] = yvB[n] * rsqrtf(SC[nyB2]);
    float v = ZZB[(size_t)n * 4 + 0] * rsqrtf(SC[nyB2]);
    WB[(size_t)n * 4 + 0] = v;
    WB[(size_t)n * 4 + 1] = 0.f;
    WB[(size_t)n * 4 + 2] = 0.f;
    WB[(size_t)n * 4 + 3] = 0.f;
    float* tot = blk_sums(&v, 1);
    if (threadIdx.x == 0) atomicAdd(&SC[sW3], tot[0]);
  }
}

// ---------------------------------------------------------------------------
extern "C" void kernel_launch(void* const* d_in, const int* in_sizes, int n_in,
                              void* d_out, int out_size, void* d_ws, size_t ws_size,
                              hipStream_t stream) {
  const float* x      = (const float*)d_in[0];
  const int*   ei     = (const int*)  d_in[1];
  const float* gcn1_w = (const float*)d_in[2];
  const float* gcn1_b = (const float*)d_in[3];
  const float* gcn2_w = (const float*)d_in[4];
  const float* gcn2_b = (const float*)d_in[5];
  const float* p1w1   = (const float*)d_in[6];
  const float* p1b1   = (const float*)d_in[7];
  const float* p1w2   = (const float*)d_in[8];
  const float* p1b2   = (const float*)d_in[9];
  const float* p2w1   = (const float*)d_in[10];
  const float* p2b1   = (const float*)d_in[11];
  const float* p2w2   = (const float*)d_in[12];
  const float* p2b2   = (const float*)d_in[13];
  const float* omega1 = (const float*)d_in[14];
  const float* omega2 = (const float*)d_in[15];
  float* out = (float*)d_out;

  float* ws = (float*)d_ws;
  size_t o = 0;
  auto alloc = [&](size_t nf) { float* p = ws + o; o += nf; return p; };
  // ---- zeroed region (one memset): xw1 | h1 | Gd | cnt | deg1 | deg2 | SC ----
  float* xw1  = alloc((size_t)N * 64);
  float* h1   = alloc((size_t)N * 64);
  double* Gd  = (double*)(ws + o); o += 576;
  int* cnt    = (int*)(ws + o);    o += 2 * N;
  float* deg1 = alloc(N);
  float* deg2 = alloc(N);
  float* SC   = alloc(1024);
  const size_t zero_bytes = o * sizeof(float);
  // ---- rest ----
  float* x1   = alloc((size_t)N * 64);
  float* x1w  = alloc((size_t)N * 32);
  float* h2   = alloc((size_t)N * 16);
  float* xo   = alloc((size_t)N * 16);
  float* dis1 = alloc(N);
  float* dis2 = alloc(N);
  float* QA   = alloc((size_t)N * 8);
  float* QB   = alloc((size_t)N * 8);
  float* ZA   = alloc((size_t)N * 8);
  float* ZB   = alloc((size_t)N * 8);
  float* BtA  = alloc((size_t)N * 8);
  float* BtB  = alloc((size_t)N * 8);
  float* V8A  = alloc((size_t)N * 8);
  float* V8B  = alloc((size_t)N * 8);
  float* WA   = alloc((size_t)N * 8);
  float* WB   = alloc((size_t)N * 4);
  float* TA   = alloc((size_t)N * 8);
  float* TB   = alloc((size_t)N * 4);
  float* YA   = alloc((size_t)N * 8);
  float* YB   = alloc((size_t)N * 4);
  float* ZZA  = alloc((size_t)N * 8);
  float* ZZB  = alloc((size_t)N * 4);
  float* P4   = alloc((size_t)N * 4);
  float* yvA  = alloc(N);
  float* yvB  = alloc(N);
  float* UvA  = alloc((size_t)3 * N);
  float* UvB  = alloc((size_t)3 * N);
  float* Pv   = alloc((size_t)3 * N);
  float* SMFA = alloc(64);
  float* SMFB = alloc(64);
  int* rowptr = (int*)alloc(2 * (N + 1) + 2);
  int* cur    = (int*)alloc(2 * N);
  int* col_s  = (int*)alloc(EDG);
  int* perm_s = (int*)alloc(EDG);
  int* col_d  = (int*)alloc(EDG);
  int* perm_d = (int*)alloc(EDG);
  float* w1s  = alloc(EDG);
  float* w1d  = alloc(EDG);
  float* w2s  = alloc(EDG);
  float* w2d  = alloc(EDG);
  if (ws_size < o * sizeof(float)) return;

  const int* rp_s = rowptr;
  const int* rp_d = rowptr + (N + 1);

  int cs = 8;
  auto NS = [&]() { int s = cs; cs += 8; return s; };
  int gslot = 0;
  auto NG = [&]() { int g = gslot; gslot += 24; return g; };

  // ===================== init + CSR =====================
  hipMemsetAsync(ws, 0, zero_bytes, stream);
  hist_edges<<<512, 256, 0, stream>>>(ei, cnt);
  scan2x<<<2, 256, 0, stream>>>(cnt, rowptr, cur);
  scatter_edges<<<512, 256, 0, stream>>>(ei, cur, col_s, perm_s, col_d, perm_d);

  int omA = NS(), omB = NS();

  // ===================== layer 1 =====================
  gemm512k<<<dim3(256, 4), 256, 0, stream>>>(x, p1w1, gcn1_w, xw1, h1);
  edge_gate1c<<<1024, 256, 0, stream>>>(xw1, rp_s, col_s, perm_s, p1b1, p1w2, p1b2,
                                        out + 131073, w1s, deg1, SC);
  gatherdis_om<<<512, 256, 0, stream>>>(out + 131073, perm_d, w1d,
                                        deg1, dis1, omega1, omega2, SC, omA, omB);
  conv1f<<<1024, 256, 0, stream>>>(rp_d, col_d, w1d, h1, dis1, gcn1_b, x1);

  // ===================== layer 2 =====================
  gemm64<<<128, 256, 0, stream>>>(x1, p2w1, gcn2_w, x1w, h2);
  edge_gate2c<<<1024, 256, 0, stream>>>(x1w, rp_s, col_s, perm_s, p2b1, p2w2, p2b2,
                                        out + 262145, w2s, deg2, SC);
  gatherdis_om<<<512, 256, 0, stream>>>(out + 262145, perm_d, w2d,
                                        deg2, dis2, nullptr, nullptr, SC, 0, 0);
  conv2f<<<1024, 256, 0, stream>>>(rp_d, col_d, w2d, h2, dis2, gcn2_b, xo);
  softmax_calib<<<16, 256, 0, stream>>>(xo, out, out + 65536, SC);

  // ===================== batched SVD: one dispatch per power step ===========
  int g0a = NG(), g0b = NG(), g1a = NG(), g1b = NG(), g2a = NG(), g2b = NG();
  int g3a = NG(), g3b = NG(), g4a = NG(), g4b = NG(), g5a = NG(), g5b = NG();
  int c0a = NS(), c0b = NS(), c1a = NS(), c1b = NS(), c2a = NS(), c2b = NS();
  int c3a = NS(), c3b = NS(), c4a = NS(), c4b = NS(), c5a = NS(), c5b = NS();
  spmm8f<0, 6><<<512, 256, 0, stream>>>(rp_s, col_s, w1s, w2s, omega1, omega2,
                                        QA, QB, nullptr, nullptr, Gd + g0a, Gd + g0b,
                                        SC, omA, omB, c0a, c0b);
  spmm8f<1, 8><<<512, 256, 0, stream>>>(rp_d, col_d, w1d, w2d, QA, QB, ZA, ZB,
                                        Gd + g0a, Gd + g0b, Gd + g1a, Gd + g1b,
                                        SC, c0a, c0b, c1a, c1b);
  spmm8f<1, 8><<<512, 256, 0, stream>>>(rp_s, col_s, w1s, w2s, ZA, ZB, QA, QB,
                                        Gd + g1a, Gd + g1b, Gd + g2a, Gd + g2b,
                                        SC, c1a, c1b, c2a, c2b);
  spmm8f<1, 8><<<512, 256, 0, stream>>>(rp_d, col_d, w1d, w2d, QA, QB, ZA, ZB,
                                        Gd + g2a, Gd + g2b, Gd + g3a, Gd + g3b,
                                        SC, c2a, c2b, c3a, c3b);
  spmm8f<1, 8><<<512, 256, 0, stream>>>(rp_s, col_s, w1s, w2s, ZA, ZB, QA, QB,
                                        Gd + g3a, Gd + g3b, Gd + g4a, Gd + g4b,
                                        SC, c3a, c3b, c4a, c4b);
  spmm8f<1, 8><<<512, 256, 0, stream>>>(rp_d, col_d, w1d, w2d, QA, QB, BtA, BtB,
                                        Gd + g4a, Gd + g4b, Gd + g5a, Gd + g5b,
                                        SC, c4a, c4b, c5a, c5b);
  jacobi2<<<1, 64, 0, stream>>>(Gd + g5a, Gd + g5b, SMFA, SMFB);

  // ===================== batched batch3 =====================
  int sWa = NS(), sWb = NS();
  v_scale_pack<<<16, 256, 0, stream>>>(BtA, SMFA, BtB, SMFB, V8A, V8B, WA, WB,
                                       SC, sWa, sWb);
  int sTa = NS(), sTb = NS();
  spmm2<4, 4><<<1024, 256, 0, stream>>>(rp_d, col_d, w1d, w2d, WA, WB, TA, TB,
                                        SC, sWa, sWb, GEPS, sTa, -1, sTb, -1);
  int sYa = NS(), sYb = NS(), nyA = NS(), nyB = NS();
  spmm2<4, 4><<<1024, 256, 0, stream>>>(rp_s, col_s, w1s, w2s, TA, TB, YA, YB,
                                        SC, sTa, sTb, GEPS, sYa, nyA, sYb, nyB);
  int zzA = NS(), zzB = NS();
  spmm2<4, 4><<<1024, 256, 0, stream>>>(rp_d, col_d, w1d, w2d, YA, YB, ZZA, ZZB,
                                        SC, sYa, sYb, GEPS, -1, zzA, -1, zzB);
  int sWp = NS();
  b3post<<<16, 256, 0, stream>>>(YA, YB, ZZB, UvA, UvB, WB, SC, zzA, nyA, zzB, nyB, sWp);
  spmm<4, 0><<<1024, 256, 0, stream>>>(rp_s, col_s, w2s, WB, nullptr, P4, SC, sWp,
                                       GEPS, -1, -1);

  // ===================== batched deflation k=3,4,5 =====================
  int dp_prev = 0, ny_prev = 0;
  for (int k = 3; k <= 5; ++k) {
    const int nu = k - 2, nt = 1 << nu, nd = k - 2;
    const int FA = (k < 5) ? 4 : 8;
    int dWa = NS(), dWb = NS(), C = NS();
    int dTa = NS(), dTb = NS();
    int nyA2 = NS(), nyB2 = NS(), sW2a = NS(), sW2b = NS(), zzA2 = NS(), zzB2 = NS();
    int dp = NS(), sW3 = NS();
    const int pvmode = (k == 3) ? 1 : (k == 4 ? 2 : 3);
    buildAB<<<32, 256, 0, stream>>>(WA, FA, nt, nu, V8A, k, UvA, SC, dWa,
                                    WB, V8B, UvB, nd, dWb, C, P4, Pv,
                                    pvmode, dp_prev, ny_prev);
    if (FA == 4) {
      spmm2<4, 4><<<1024, 256, 0, stream>>>(rp_d, col_d, w1d, w2d, WA, WB, TA, TB,
                                            SC, dWa, dWb, GEPS, dTa, -1, dTb, -1);
      spmm2<4, 4><<<1024, 256, 0, stream>>>(rp_s, col_s, w1s, w2s, TA, TB, YA, YB,
                                            SC, dTa, dTb, GEPS, -1, -1, -1, -1);
    } else {
      spmm2<8, 4><<<1024, 256, 0, stream>>>(rp_d, col_d, w1d, w2d, WA, WB, TA, TB,
                                            SC, dWa, dWb, GEPS, dTa, -1, dTb, -1);
      spmm2<8, 4><<<1024, 256, 0, stream>>>(rp_s, col_s, w1s, w2s, TA, TB, YA, YB,
                                            SC, dTa, dTb, GEPS, -1, -1, -1, -1);
    }
    epibuild<<<32, 256, 0, stream>>>(YA, FA, nt, nu, UvA, yvA, nyA2, WA, sW2a,
                                     YB, Pv, UvB, nd, yvB, C, nyB2, dp, WB, sW2b, SC);
    if (FA == 4)
      spmm2<4, 4><<<1024, 256, 0, stream>>>(rp_d, col_d, w1d, w2d, WA, WB, ZZA, ZZB,
                                            SC, sW2a, sW2b, GEPS, -1, zzA2, -1, zzB2);
    else
      spmm2<8, 4><<<1024, 256, 0, stream>>>(rp_d, col_d, w1d, w2d, WA, WB, ZZA, ZZB,
                                            SC, sW2a, sW2b, GEPS, -1, zzA2, -1, zzB2);
    if (k < 5) {
      defpost<<<16, 256, 0, stream>>>(SC, zzA2, nt, nyA2, zzB2, nyB2, dp, nd,
                                      yvA, yvB, UvA, UvB, k, ZZB, WB, sW3, 1, 0, out);
      spmm<4, 0><<<1024, 256, 0, stream>>>(rp_s, col_s, w2s, WB, nullptr, P4, SC, sW3,
                                           GEPS, -1, -1);
    } else {
      defpost<<<1, 256, 0, stream>>>(SC, zzA2, nt, nyA2, zzB2, nyB2, dp, nd,
                                     yvA, yvB, UvA, UvB, k, ZZB, WB, sW3, 0, 1, out);
    }
    dp_prev = dp; ny_prev = nyB2;
  }
}

// Round 14
// 819.155 us; speedup vs baseline: 1.0021x; 1.0021x over previous
//
#include <hip/hip_runtime.h>
#include <cmath>

constexpr int N = 4096;
constexpr int EDG = 131072;
constexpr float GEPS = 1e-6f;

// ---------------------------------------------------------------------------
__device__ __forceinline__ float* blk_sums(float* vals, int cnt) {
  __shared__ float part[4][16];
  __shared__ float tot[16];
  const int lane = threadIdx.x & 63, wv = threadIdx.x >> 6;
  for (int c = 0; c < cnt; ++c) {
    float v = vals[c];
    for (int off = 32; off; off >>= 1) v += __shfl_down(v, off);
    if (lane == 0) part[wv][c] = v;
  }
  __syncthreads();
  if (threadIdx.x == 0)
    for (int c = 0; c < cnt; ++c)
      tot[c] = part[0][c] + part[1][c] + part[2][c] + part[3][c];
  __syncthreads();
  return tot;
}

// ---------------------------------------------------------------------------
// CSR build
__global__ void hist_edges(const int* __restrict__ ei, int* __restrict__ cnt) {
  int e = blockIdx.x * 256 + threadIdx.x;
  atomicAdd(&cnt[ei[e]], 1);
  atomicAdd(&cnt[N + ei[EDG + e]], 1);
}

__global__ __launch_bounds__(256) void scan2x(const int* __restrict__ cnt,
                                              int* __restrict__ rowptr,
                                              int* __restrict__ cur) {
  const int b = blockIdx.x;
  const int* c = cnt + b * N;
  int* rp = rowptr + b * (N + 1);
  int* cu = cur + b * N;
  __shared__ int part[256];
  const int t = threadIdx.x;
  int local[16], s = 0;
  const int base = t * 16;
  for (int i = 0; i < 16; ++i) { local[i] = s; s += c[base + i]; }
  part[t] = s;
  __syncthreads();
  if (t == 0) {
    int acc = 0;
    for (int i = 0; i < 256; ++i) { int v = part[i]; part[i] = acc; acc += v; }
  }
  __syncthreads();
  const int off = part[t];
  for (int i = 0; i < 16; ++i) { rp[base + i] = off + local[i]; cu[base + i] = off + local[i]; }
  if (t == 255) rp[N] = off + s;
}

__global__ void scatter_edges(const int* __restrict__ ei, int* __restrict__ cur,
                              int* __restrict__ col_s, int* __restrict__ perm_s,
                              int* __restrict__ col_d, int* __restrict__ perm_d) {
  int e = blockIdx.x * 256 + threadIdx.x;
  int s = ei[e], d = ei[EDG + e];
  int ps = atomicAdd(&cur[s], 1);
  col_s[ps] = d; perm_s[ps] = e;
  int pd = atomicAdd(&cur[N + d], 1);
  col_d[pd] = s; perm_d[pd] = e;
}

// gather edge weights into dst-CSR order + compute dis; optional omega colsums
__global__ void gatherdis_om(const float* __restrict__ s,
                             const int* __restrict__ perm_d,
                             float* __restrict__ wd_, const float* __restrict__ deg,
                             float* __restrict__ dis, const float* __restrict__ om1,
                             const float* __restrict__ om2, float* __restrict__ SC,
                             int omA, int omB) {
  int p = blockIdx.x * 256 + threadIdx.x;
  wd_[p] = s[perm_d[p]];
  if (p < N) dis[p] = rsqrtf(deg[p] + 1.0f);
  if (om1 && blockIdx.x < 16) {
    int n = p;  // < 4096
    float vals[12];
#pragma unroll
    for (int k = 0; k < 6; ++k) {
      vals[k] = om1[(size_t)n * 6 + k];
      vals[6 + k] = om2[(size_t)n * 6 + k];
    }
    float* tot = blk_sums(vals, 12);
    if (threadIdx.x == 0)
      for (int c = 0; c < 6; ++c) {
        atomicAdd(&SC[omA + c], tot[c]);
        atomicAdd(&SC[omB + c], tot[6 + c]);
      }
  }
}

// ---------------------------------------------------------------------------
// Split-K fused layer-1 GEMM (r13 validated: split-K 4)
__global__ __launch_bounds__(256) void gemm512k(const float* __restrict__ A,
                                                const float* __restrict__ W1,
                                                const float* __restrict__ W2,
                                                float* __restrict__ O1,
                                                float* __restrict__ O2) {
  __shared__ float As[16][33];
  __shared__ float Ws[32][128];
  const int t = threadIdx.x;
  const int rt = t >> 4;
  const int ct = t & 15;
  const int r0 = blockIdx.x * 16;
  const int kh = blockIdx.y * 128;
  float acc[8];
#pragma unroll
  for (int j = 0; j < 8; ++j) acc[j] = 0.f;
  for (int kc = 0; kc < 128; kc += 32) {
    const int kb = kh + kc;
    __syncthreads();
    for (int i = t; i < 512; i += 256) {
      int rr = i >> 5, kk = i & 31;
      As[rr][kk] = A[(size_t)(r0 + rr) * 512 + kb + kk];
    }
    for (int i = t; i < 1024; i += 256) {
      int row = i >> 5, c4 = i & 31;
      float4 v;
      if (c4 < 16) v = *(const float4*)&W1[(size_t)(kb + row) * 64 + c4 * 4];
      else         v = *(const float4*)&W2[(size_t)(kb + row) * 64 + (c4 - 16) * 4];
      *(float4*)&Ws[row][c4 * 4] = v;
    }
    __syncthreads();
#pragma unroll
    for (int kk = 0; kk < 32; ++kk) {
      float a = As[rt][kk];
      float4 b0 = *(const float4*)&Ws[kk][ct * 4];
      float4 b1 = *(const float4*)&Ws[kk][64 + ct * 4];
      acc[0] += a * b0.x; acc[1] += a * b0.y;
      acc[2] += a * b0.z; acc[3] += a * b0.w;
      acc[4] += a * b1.x; acc[5] += a * b1.y;
      acc[6] += a * b1.z; acc[7] += a * b1.w;
    }
  }
  const int r = r0 + rt;
#pragma unroll
  for (int j = 0; j < 4; ++j) {
    atomicAdd(&O1[(size_t)r * 64 + ct * 4 + j], acc[j]);
    atomicAdd(&O2[(size_t)r * 64 + ct * 4 + j], acc[4 + j]);
  }
}

// Fused layer-2 GEMM (validated)
__global__ __launch_bounds__(256) void gemm64(const float* __restrict__ A,
                                              const float* __restrict__ W1,
                                              const float* __restrict__ W2,
                                              float* __restrict__ O1,
                                              float* __restrict__ O2) {
  __shared__ float As[32][65];
  __shared__ float Ws[64][48];
  const int t = threadIdx.x;
  const int r = t >> 3;
  const int cg = t & 7;
  const int r0 = blockIdx.x * 32;
  for (int idx = t; idx < 32 * 64; idx += 256)
    As[idx >> 6][idx & 63] = A[(size_t)(r0 + (idx >> 6)) * 64 + (idx & 63)];
  for (int idx = t; idx < 64 * 48; idx += 256) {
    int kk = idx / 48, c = idx % 48;
    Ws[kk][c] = (c < 32) ? W1[kk * 32 + c] : W2[kk * 16 + c - 32];
  }
  __syncthreads();
  float acc[6] = {0.f, 0.f, 0.f, 0.f, 0.f, 0.f};
  for (int k = 0; k < 64; ++k) {
    float a = As[r][k];
#pragma unroll
    for (int j = 0; j < 6; ++j) acc[j] += a * Ws[k][cg + 8 * j];
  }
  int n = r0 + r;
#pragma unroll
  for (int j = 0; j < 6; ++j) {
    int c = cg + 8 * j;
    if (c < 32) O1[(size_t)n * 32 + c] = acc[j];
    else O2[(size_t)n * 16 + c - 32] = acc[j];
  }
}

// ---------------------------------------------------------------------------
// edge gate 1 (r12 validated)
__global__ void edge_gate1c(const float* __restrict__ xw, const int* __restrict__ rp,
                            const int* __restrict__ cl, const int* __restrict__ perm,
                            const float* __restrict__ b1, const float* __restrict__ w2,
                            const float* __restrict__ b2, float* __restrict__ s_out,
                            float* __restrict__ wcs, float* __restrict__ deg,
                            float* __restrict__ SCs) {
  const int lane = threadIdx.x & 63;
  const int wave = threadIdx.x >> 6;
  const int u = lane >> 4;
  const int q = lane & 15;
  const float4 b1q = ((const float4*)b1)[q];
  const float4 w2q = ((const float4*)w2)[q];
  const float b2s = b2[0];
  const float4* xw4 = (const float4*)xw;
  const int r = blockIdx.x * 4 + wave;
  const float4 xsr = xw4[(size_t)r * 16 + q];
  const int e0 = rp[r], e1 = rp[r + 1];
  float lsum = 0.f, lssq = 0.f;
  int e = e0 + u;
  for (; e + 4 < e1; e += 8) {
    int d0 = cl[e], d1 = cl[e + 4];
    float4 xd0 = xw4[(size_t)d0 * 16 + q];
    float4 xd1 = xw4[(size_t)d1 * 16 + q];
    float g0 = fmaxf(xsr.x - xd0.x + b1q.x, 0.f) * w2q.x
             + fmaxf(xsr.y - xd0.y + b1q.y, 0.f) * w2q.y
             + fmaxf(xsr.z - xd0.z + b1q.z, 0.f) * w2q.z
             + fmaxf(xsr.w - xd0.w + b1q.w, 0.f) * w2q.w;
    float g1 = fmaxf(xsr.x - xd1.x + b1q.x, 0.f) * w2q.x
             + fmaxf(xsr.y - xd1.y + b1q.y, 0.f) * w2q.y
             + fmaxf(xsr.z - xd1.z + b1q.z, 0.f) * w2q.z
             + fmaxf(xsr.w - xd1.w + b1q.w, 0.f) * w2q.w;
#pragma unroll
    for (int off = 1; off < 16; off <<= 1) {
      g0 += __shfl_xor(g0, off);
      g1 += __shfl_xor(g1, off);
    }
    if (q == 0) {
      float a0 = g0 + b2s; a0 *= a0;
      float a1 = g1 + b2s; a1 *= a1;
      float s0 = 1.f / (1.f + __expf(-a0));
      float s1 = 1.f / (1.f + __expf(-a1));
      s_out[perm[e]] = s0;     wcs[e] = s0;
      s_out[perm[e + 4]] = s1; wcs[e + 4] = s1;
      atomicAdd(&deg[d0], s0);
      atomicAdd(&deg[d1], s1);
      lsum += s0 + s1; lssq += s0 * s0 + s1 * s1;
    }
  }
  for (; e < e1; e += 4) {
    int d = cl[e];
    float4 xd = xw4[(size_t)d * 16 + q];
    float g = fmaxf(xsr.x - xd.x + b1q.x, 0.f) * w2q.x
            + fmaxf(xsr.y - xd.y + b1q.y, 0.f) * w2q.y
            + fmaxf(xsr.z - xd.z + b1q.z, 0.f) * w2q.z
            + fmaxf(xsr.w - xd.w + b1q.w, 0.f) * w2q.w;
#pragma unroll
    for (int off = 1; off < 16; off <<= 1) g += __shfl_xor(g, off);
    if (q == 0) {
      float a = g + b2s; a *= a;
      float sv = 1.f / (1.f + __expf(-a));
      s_out[perm[e]] = sv; wcs[e] = sv;
      atomicAdd(&deg[d], sv);
      lsum += sv; lssq += sv * sv;
    }
  }
  float* tot = blk_sums(&lsum, 1);
  float* tot2 = blk_sums(&lssq, 1);
  if (threadIdx.x == 0) {
    atomicAdd(&SCs[0], tot[0]);
    atomicAdd(&SCs[1], tot2[0]);
  }
}

// edge gate 2 (r12 validated)
__global__ void edge_gate2c(const float* __restrict__ xw, const int* __restrict__ rp,
                            const int* __restrict__ cl, const int* __restrict__ perm,
                            const float* __restrict__ b1, const float* __restrict__ w2,
                            const float* __restrict__ b2, float* __restrict__ s_out,
                            float* __restrict__ wcs, float* __restrict__ deg,
                            float* __restrict__ SCs) {
  const int lane = threadIdx.x & 63;
  const int wave = threadIdx.x >> 6;
  const int u = lane >> 3;
  const int q = lane & 7;
  const float4 b1q = ((const float4*)b1)[q];
  const float4 w2q = ((const float4*)w2)[q];
  const float b2s = b2[0];
  const float4* xw4 = (const float4*)xw;
  const int r = blockIdx.x * 4 + wave;
  const float4 xsr = xw4[(size_t)r * 8 + q];
  const int e0 = rp[r], e1 = rp[r + 1];
  float lsum = 0.f, lssq = 0.f;
  int e = e0 + u;
  for (; e + 8 < e1; e += 16) {
    int d0 = cl[e], d1 = cl[e + 8];
    float4 xd0 = xw4[(size_t)d0 * 8 + q];
    float4 xd1 = xw4[(size_t)d1 * 8 + q];
    float g0 = fmaxf(xsr.x - xd0.x + b1q.x, 0.f) * w2q.x
             + fmaxf(xsr.y - xd0.y + b1q.y, 0.f) * w2q.y
             + fmaxf(xsr.z - xd0.z + b1q.z, 0.f) * w2q.z
             + fmaxf(xsr.w - xd0.w + b1q.w, 0.f) * w2q.w;
    float g1 = fmaxf(xsr.x - xd1.x + b1q.x, 0.f) * w2q.x
             + fmaxf(xsr.y - xd1.y + b1q.y, 0.f) * w2q.y
             + fmaxf(xsr.z - xd1.z + b1q.z, 0.f) * w2q.z
             + fmaxf(xsr.w - xd1.w + b1q.w, 0.f) * w2q.w;
#pragma unroll
    for (int off = 1; off < 8; off <<= 1) {
      g0 += __shfl_xor(g0, off);
      g1 += __shfl_xor(g1, off);
    }
    if (q == 0) {
      float a0 = g0 + b2s; a0 *= a0;
      float a1 = g1 + b2s; a1 *= a1;
      float s0 = 1.f / (1.f + __expf(-a0));
      float s1 = 1.f / (1.f + __expf(-a1));
      s_out[perm[e]] = s0;     wcs[e] = s0;
      s_out[perm[e + 8]] = s1; wcs[e + 8] = s1;
      atomicAdd(&deg[d0], s0);
      atomicAdd(&deg[d1], s1);
      lsum += s0 + s1; lssq += s0 * s0 + s1 * s1;
    }
  }
  for (; e < e1; e += 8) {
    int d = cl[e];
    float4 xd = xw4[(size_t)d * 8 + q];
    float g = fmaxf(xsr.x - xd.x + b1q.x, 0.f) * w2q.x
            + fmaxf(xsr.y - xd.y + b1q.y, 0.f) * w2q.y
            + fmaxf(xsr.z - xd.z + b1q.z, 0.f) * w2q.z
            + fmaxf(xsr.w - xd.w + b1q.w, 0.f) * w2q.w;
#pragma unroll
    for (int off = 1; off < 8; off <<= 1) g += __shfl_xor(g, off);
    if (q == 0) {
      float a = g + b2s; a *= a;
      float sv = 1.f / (1.f + __expf(-a));
      s_out[perm[e]] = sv; wcs[e] = sv;
      atomicAdd(&deg[d], sv);
      lsum += sv; lssq += sv * sv;
    }
  }
  float* tot = blk_sums(&lsum, 1);
  float* tot2 = blk_sums(&lssq, 1);
  if (threadIdx.x == 0) {
    atomicAdd(&SCs[2], tot[0]);
    atomicAdd(&SCs[3], tot2[0]);
  }
}

// conv1 fused (r11 validated)
__global__ void conv1f(const int* __restrict__ rp, const int* __restrict__ cl,
                       const float* __restrict__ w, const float* __restrict__ h1,
                       const float* __restrict__ dis, const float* __restrict__ bias,
                       float* __restrict__ x1) {
  const int lane = threadIdx.x & 63, wv = threadIdx.x >> 6;
  const int es = lane >> 4;
  const int q = lane & 15;
  const int r = blockIdx.x * 4 + wv;
  const int e0 = rp[r], e1 = rp[r + 1];
  const float4* h14 = (const float4*)h1;
  float ax = 0.f, ay = 0.f, az = 0.f, aw = 0.f;
  int e = e0 + es;
  for (; e + 4 < e1; e += 8) {
    int c0 = cl[e], c1 = cl[e + 4];
    float w0 = w[e] * dis[c0], w1_ = w[e + 4] * dis[c1];
    float4 h0 = h14[(size_t)c0 * 16 + q];
    float4 h1v = h14[(size_t)c1 * 16 + q];
    ax += w0 * h0.x + w1_ * h1v.x;
    ay += w0 * h0.y + w1_ * h1v.y;
    az += w0 * h0.z + w1_ * h1v.z;
    aw += w0 * h0.w + w1_ * h1v.w;
  }
  for (; e < e1; e += 4) {
    int c = cl[e];
    float wx = w[e] * dis[c];
    float4 hv = h14[(size_t)c * 16 + q];
    ax += wx * hv.x; ay += wx * hv.y; az += wx * hv.z; aw += wx * hv.w;
  }
  ax += __shfl_xor(ax, 16); ax += __shfl_xor(ax, 32);
  ay += __shfl_xor(ay, 16); ay += __shfl_xor(ay, 32);
  az += __shfl_xor(az, 16); az += __shfl_xor(az, 32);
  aw += __shfl_xor(aw, 16); aw += __shfl_xor(aw, 32);
  if (es == 0) {
    float d = dis[r];
    float4 hh = h14[(size_t)r * 16 + q];
    float4 bq = ((const float4*)bias)[q];
    float4 o;
    o.x = fmaxf(d * (ax + d * hh.x) + bq.x, 0.f);
    o.y = fmaxf(d * (ay + d * hh.y) + bq.y, 0.f);
    o.z = fmaxf(d * (az + d * hh.z) + bq.z, 0.f);
    o.w = fmaxf(d * (aw + d * hh.w) + bq.w, 0.f);
    ((float4*)x1)[(size_t)r * 16 + q] = o;
  }
}

// conv2 fused -> logits (r11 validated)
__global__ void conv2f(const int* __restrict__ rp, const int* __restrict__ cl,
                       const float* __restrict__ w, const float* __restrict__ h2,
                       const float* __restrict__ dis, const float* __restrict__ bias,
                       float* __restrict__ xo) {
  const int lane = threadIdx.x & 63, wv = threadIdx.x >> 6;
  const int es = lane >> 2;
  const int q = lane & 3;
  const int r = blockIdx.x * 4 + wv;
  const int e0 = rp[r], e1 = rp[r + 1];
  const float4* h24 = (const float4*)h2;
  float ax = 0.f, ay = 0.f, az = 0.f, aw = 0.f;
  for (int e = e0 + es; e < e1; e += 16) {
    int c = cl[e];
    float wx = w[e] * dis[c];
    float4 hv = h24[(size_t)c * 4 + q];
    ax += wx * hv.x; ay += wx * hv.y; az += wx * hv.z; aw += wx * hv.w;
  }
#pragma unroll
  for (int off = 4; off < 64; off <<= 1) {
    ax += __shfl_xor(ax, off);
    ay += __shfl_xor(ay, off);
    az += __shfl_xor(az, off);
    aw += __shfl_xor(aw, off);
  }
  if (es == 0) {
    float d = dis[r];
    float4 hh = h24[(size_t)r * 4 + q];
    float4 bq = ((const float4*)bias)[q];
    float4 o;
    o.x = d * (ax + d * hh.x) + bq.x;
    o.y = d * (ay + d * hh.y) + bq.y;
    o.z = d * (az + d * hh.z) + bq.z;
    o.w = d * (aw + d * hh.w) + bq.w;
    ((float4*)xo)[(size_t)r * 4 + q] = o;
  }
}

// softmax + calib from logits (validated r3/r5)
__global__ void softmax_calib(const float* __restrict__ xo, float* __restrict__ ls,
                              float* __restrict__ sm, float* __restrict__ SC) {
  const int t = threadIdx.x;
  const int r = blockIdx.x * 256 + t;
  float v[16];
  float mx = -3.0e38f, mx2 = -3.0e38f;
#pragma unroll
  for (int c = 0; c < 16; ++c) {
    v[c] = xo[(size_t)r * 16 + c];
    if (v[c] > mx) { mx2 = mx; mx = v[c]; }
    else if (v[c] > mx2) mx2 = v[c];
  }
  float se = 0.f;
#pragma unroll
  for (int c = 0; c < 16; ++c) se += expf(v[c] - mx);
  const float lse = mx + logf(se);
#pragma unroll
  for (int c = 0; c < 16; ++c) {
    float z = v[c] - lse;
    ls[(size_t)r * 16 + c] = z;
    sm[(size_t)r * 16 + c] = expf(z);
  }
  float calib = mx2 - mx;
  float* tot = blk_sums(&calib, 1);
  if (t == 0) atomicAdd(&SC[4], tot[0]);
}

// ---------------------------------------------------------------------------
// Fused SVD power step (r8) with fp32 Cholesky prologue (r9).
template<int NORM, int SX>
__global__ __launch_bounds__(256) void spmm8f(
    const int* __restrict__ rp, const int* __restrict__ cl,
    const float* __restrict__ wA, const float* __restrict__ wB,
    const float* __restrict__ XA, const float* __restrict__ XB,
    float* __restrict__ OA, float* __restrict__ OB,
    const double* __restrict__ GpA, const double* __restrict__ GpB,
    double* __restrict__ GnA, double* __restrict__ GnB,
    float* __restrict__ SC, int cspA, int cspB, int csoA, int csoB) {
  __shared__ float Rinv[2][36];
  __shared__ float csn[2][8];
  __shared__ float bs[2][8];
  __shared__ float gpart[8][21];
  const int t = threadIdx.x;
  if (NORM) {
    if (t < 2) {
      const double* G = t ? GpB : GpA;
      const float* csp = SC + (t ? cspB : cspA);
      float Gf[6][6];
      int p = 0;
      for (int i = 0; i < 6; ++i)
        for (int j = i; j < 6; ++j) { float gv = (float)G[p]; Gf[i][j] = gv; Gf[j][i] = gv; ++p; }
      float Rm[6][6];
      for (int i = 0; i < 6; ++i) for (int j = 0; j < 6; ++j) Rm[i][j] = 0.f;
      for (int j = 0; j < 6; ++j) {
        float s = Gf[j][j];
        for (int k = 0; k < j; ++k) s -= Rm[k][j] * Rm[k][j];
        float dj = sqrtf(fmaxf(s, 1e-30f));
        Rm[j][j] = dj;
        for (int i = j + 1; i < 6; ++i) {
          float v = Gf[j][i];
          for (int k = 0; k < j; ++k) v -= Rm[k][j] * Rm[k][i];
          Rm[j][i] = v / dj;
        }
      }
      float Ri[6][6];
      for (int j = 0; j < 6; ++j) {
        Ri[j][j] = 1.f / Rm[j][j];
        for (int i = j - 1; i >= 0; --i) {
          float s = 0.f;
          for (int k = i + 1; k <= j; ++k) s += Rm[i][k] * Ri[k][j];
          Ri[i][j] = -s / Rm[i][i];
        }
      }
      for (int i = 0; i < 6; ++i)
        for (int j = 0; j < 6; ++j)
          Rinv[t][i * 6 + j] = (j >= i) ? Ri[i][j] : 0.f;
      for (int f = 0; f < 8; ++f) {
        float s = 0.f;
        if (f < 6)
          for (int j = 0; j <= f; ++j) s += csp[j] * Ri[j][f];
        csn[t][f] = s;
      }
    }
  } else {
    if (t < 16) {
      int h = t >> 3, f = t & 7;
      csn[h][f] = (f < 6) ? SC[(h ? cspB : cspA) + f] : 0.f;
    }
  }
  if (t < 16) bs[t >> 3][t & 7] = 0.f;
  __syncthreads();
  const int lane = t & 63, wv = t >> 6;
  const int half = lane >> 5, la = lane & 31;
  const int f = la & 7, es = la >> 3;
  const float* w = half ? wB : wA;
  const float* X = half ? XB : XA;
  float* O = half ? OB : OA;
  const float* Ri = Rinv[half];
  const float epsf = csn[half][f] * GEPS;
  float gp[6];
#pragma unroll
  for (int j = 0; j < 6; ++j) gp[j] = 0.f;
  for (int rr = 0; rr < 2; ++rr) {
    const int r = blockIdx.x * 8 + wv * 2 + rr;
    const int e0 = rp[r], e1 = rp[r + 1];
    float acc = 0.f;
    if (f < 6) {
      for (int e = e0 + es; e < e1; e += 4) {
        int c = cl[e];
        const float* xr = X + (size_t)c * SX;
        float xn;
        if (NORM) {
          xn = 0.f;
          for (int j = 0; j <= f; ++j) xn += xr[j] * Ri[j * 6 + f];
        } else {
          xn = xr[f];
        }
        acc += w[e] * xn;
      }
    }
    acc += __shfl_xor(acc, 8);
    acc += __shfl_xor(acc, 16);
    float o = acc + epsf;
    float ov[6];
#pragma unroll
    for (int j = 0; j < 6; ++j) ov[j] = __shfl(o, half * 32 + j);
    if (es == 0) {
      O[((size_t)r << 3) + f] = o;
      if (f < 6) {
        atomicAdd(&bs[half][f], o);
#pragma unroll
        for (int j = 0; j < 6; ++j)
          if (j >= f) gp[j - f] += o * ov[j];
      }
    }
  }
  if (es == 0 && f < 6) {
    int p0 = f * 6 - (f * (f - 1)) / 2;
    for (int j = 0; j < 6 - f; ++j) gpart[wv * 2 + half][p0 + j] = gp[j];
  }
  __syncthreads();
  if (t < 42) {
    int h = t / 21, p = t % 21;
    float s = gpart[h][p] + gpart[2 + h][p] + gpart[4 + h][p] + gpart[6 + h][p];
    atomicAdd(&(h ? GnB : GnA)[p], (double)s);
  }
  if (t < 16) {
    int h = t >> 3, ff = t & 7;
    if (ff < 6) atomicAdd(&SC[(h ? csoB : csoA) + ff], bs[h][ff]);
  }
}

// ---------------------------------------------------------------------------
// single-graph SpMM (p-passes)
template<int F, int DIS>
__global__ __launch_bounds__(256) void spmm(const int* __restrict__ rowptr,
                                            const int* __restrict__ col,
                                            const float* __restrict__ w,
                                            const float* __restrict__ X,
                                            const float* __restrict__ dis,
                                            float* __restrict__ OUT,
                                            float* __restrict__ SC, int cs_idx,
                                            float eps, int osum, int ossq) {
  constexpr int ES = 64 / F;
  const int lane = threadIdx.x & 63;
  const int wv = threadIdx.x >> 6;
  const int f = lane & (F - 1);
  const int es = lane / F;
  const int r = blockIdx.x * 4 + wv;
  const int e0 = rowptr[r], e1 = rowptr[r + 1];
  float acc = 0.f;
  for (int e = e0 + es; e < e1; e += ES) {
    int c = col[e];
    float wx = w[e];
    if (DIS) wx *= dis[c];
    acc += wx * X[(size_t)c * F + f];
  }
#pragma unroll
  for (int off = F; off < 64; off <<= 1) acc += __shfl_xor(acc, off);
  float o = acc + ((cs_idx >= 0) ? eps * SC[cs_idx + f] : 0.f);
  if (es == 0) OUT[(size_t)r * F + f] = o;
  if (osum >= 0 || ossq >= 0) {
    __shared__ float bs[8], bq[8];
    if (threadIdx.x < F) { bs[threadIdx.x] = 0.f; bq[threadIdx.x] = 0.f; }
    __syncthreads();
    if (es == 0) {
      if (osum >= 0) atomicAdd(&bs[f], o);
      if (ossq >= 0) atomicAdd(&bq[f], o * o);
    }
    __syncthreads();
    if (threadIdx.x < F) {
      if (osum >= 0) atomicAdd(&SC[osum + threadIdx.x], bs[threadIdx.x]);
      if (ossq >= 0) atomicAdd(&SC[ossq + threadIdx.x], bq[threadIdx.x]);
    }
  }
}

// Batched two-graph SpMM (validated r5)
template<int FA, int FB>
__global__ __launch_bounds__(256) void spmm2(const int* __restrict__ rowptr,
                                             const int* __restrict__ col,
                                             const float* __restrict__ wA,
                                             const float* __restrict__ wB,
                                             const float* __restrict__ XA,
                                             const float* __restrict__ XB,
                                             float* __restrict__ OA,
                                             float* __restrict__ OB,
                                             float* __restrict__ SC,
                                             int csA, int csB, float eps,
                                             int osumA, int ossqA, int osumB, int ossqB) {
  const int lane = threadIdx.x & 63;
  const int wv = threadIdx.x >> 6;
  const int half = lane >> 5;
  const int la = lane & 31;
  const int F = half ? FB : FA;
  const int f = la & (F - 1);
  const int es = la / F;
  const int ES = 32 / F;
  const int r = blockIdx.x * 4 + wv;
  const int e0 = rowptr[r], e1 = rowptr[r + 1];
  const float* w = half ? wB : wA;
  const float* X = half ? XB : XA;
  float acc = 0.f;
  for (int e = e0 + es; e < e1; e += ES)
    acc += w[e] * X[(size_t)col[e] * F + f];
  for (int off = F; off < 32; off <<= 1) acc += __shfl_xor(acc, off);
  const int cs = half ? csB : csA;
  float o = acc + ((cs >= 0) ? eps * SC[cs + f] : 0.f);
  if (es == 0) {
    float* O = half ? OB : OA;
    O[(size_t)r * F + f] = o;
  }
  if (osumA >= 0 || ossqA >= 0 || osumB >= 0 || ossqB >= 0) {
    __shared__ float bs[2][8], bq[2][8];
    if (threadIdx.x < 16) { bs[threadIdx.x >> 3][threadIdx.x & 7] = 0.f;
                            bq[threadIdx.x >> 3][threadIdx.x & 7] = 0.f; }
    __syncthreads();
    const int osum = half ? osumB : osumA, ossq = half ? ossqB : ossqA;
    if (es == 0) {
      if (osum >= 0) atomicAdd(&bs[half][f], o);
      if (ossq >= 0) atomicAdd(&bq[half][f], o * o);
    }
    __syncthreads();
    if (threadIdx.x < 16) {
      int h = threadIdx.x >> 3, ff = threadIdx.x & 7;
      int os_ = h ? osumB : osumA, oq_ = h ? ossqB : ossqA;
      int Fh = h ? FB : FA;
      if (os_ >= 0 && ff < Fh) atomicAdd(&SC[os_ + ff], bs[h][ff]);
      if (oq_ >= 0 && ff < Fh) atomicAdd(&SC[oq_ + ff], bq[h][ff]);
    }
  }
}

// ---------------------------------------------------------------------------
// r14: fully-unrolled branch-free serial fp32 6x6 Jacobi (registers only).
// 5 fixed sweeps; NaN-guard via select; final sort/emit through LDS.
__global__ void jacobi2(const double* __restrict__ GA,
                        const double* __restrict__ GB,
                        float* __restrict__ SMFA, float* __restrict__ SMFB) {
  __shared__ float diag_s[2][6];
  __shared__ float V_s[2][36];
  __shared__ int idx_s[2][6];
  const int t = threadIdx.x;
  if (t < 2) {
    const double* G = t ? GB : GA;
    float A[6][6], V[6][6];
    {
      int p = 0;
#pragma unroll
      for (int i = 0; i < 6; ++i)
#pragma unroll
        for (int j = i; j < 6; ++j) {
          float gv = (float)G[p];
          A[i][j] = gv; A[j][i] = gv; ++p;
        }
    }
#pragma unroll
    for (int i = 0; i < 6; ++i)
#pragma unroll
      for (int j = 0; j < 6; ++j) V[i][j] = (i == j) ? 1.f : 0.f;
#pragma unroll
    for (int sweep = 0; sweep < 5; ++sweep) {
#pragma unroll
      for (int pi = 0; pi < 5; ++pi) {
#pragma unroll
        for (int qi = pi + 1; qi < 6; ++qi) {
          float apq = A[pi][qi];
          float app = A[pi][pi], aqq = A[qi][qi];
          float tau = (aqq - app) / (2.f * apq);
          float rt_ = sqrtf(1.f + tau * tau);
          float tt = (tau >= 0.f) ? 1.f / (tau + rt_) : 1.f / (tau - rt_);
          bool ok = fabsf(apq) > 1e-30f;
          float cc = rsqrtf(1.f + tt * tt);
          float c = ok ? cc : 1.f;
          float s = ok ? tt * cc : 0.f;
#pragma unroll
          for (int k = 0; k < 6; ++k) {
            float akp = A[k][pi], akq = A[k][qi];
            A[k][pi] = c * akp - s * akq;
            A[k][qi] = s * akp + c * akq;
          }
#pragma unroll
          for (int k = 0; k < 6; ++k) {
            float apk = A[pi][k], aqk = A[qi][k];
            A[pi][k] = c * apk - s * aqk;
            A[qi][k] = s * apk + c * aqk;
          }
#pragma unroll
          for (int k = 0; k < 6; ++k) {
            float vkp = V[k][pi], vkq = V[k][qi];
            V[k][pi] = c * vkp - s * vkq;
            V[k][qi] = s * vkp + c * vkq;
          }
        }
      }
    }
#pragma unroll
    for (int i = 0; i < 6; ++i) diag_s[t][i] = A[i][i];
#pragma unroll
    for (int i = 0; i < 6; ++i)
#pragma unroll
      for (int j = 0; j < 6; ++j) V_s[t][i * 6 + j] = V[i][j];
    for (int i = 0; i < 6; ++i) idx_s[t][i] = i;
    // bubble sort (descending eigenvalue) via LDS
    for (int a = 0; a < 5; ++a)
      for (int b = 0; b < 5 - a; ++b) {
        int i0 = idx_s[t][b], i1 = idx_s[t][b + 1];
        if (diag_s[t][i0] < diag_s[t][i1]) {
          idx_s[t][b] = i1; idx_s[t][b + 1] = i0;
        }
      }
    float* SMF = t ? SMFB : SMFA;
    for (int k = 0; k < 6; ++k) {
      int ik = idx_s[t][k];
      float lam = diag_s[t][ik];
      SMF[36 + k] = rsqrtf(fmaxf(lam, 1e-30f));
      for (int j = 0; j < 6; ++j) SMF[j * 6 + k] = V_s[t][j * 6 + ik];
    }
  }
}

// v_scale2 + pack3 fused (r9)
__global__ void v_scale_pack(const float* __restrict__ BtA, const float* __restrict__ SMFA,
                             const float* __restrict__ BtB, const float* __restrict__ SMFB,
                             float* __restrict__ V8A, float* __restrict__ V8B,
                             float* __restrict__ WA, float* __restrict__ WB,
                             float* __restrict__ SC, int sA, int sB) {
  __shared__ float WsA[36], rsA[6], WsB[36], rsB[6];
  if (threadIdx.x < 36) { WsA[threadIdx.x] = SMFA[threadIdx.x]; WsB[threadIdx.x] = SMFB[threadIdx.x]; }
  if (threadIdx.x < 6) { rsA[threadIdx.x] = SMFA[36 + threadIdx.x]; rsB[threadIdx.x] = SMFB[36 + threadIdx.x]; }
  __syncthreads();
  int n = blockIdx.x * 256 + threadIdx.x;
  float ba[6], bb[6];
#pragma unroll
  for (int j = 0; j < 6; ++j) { ba[j] = BtA[(size_t)n * 8 + j]; bb[j] = BtB[(size_t)n * 8 + j]; }
  float vals[6];
#pragma unroll
  for (int k = 0; k < 6; ++k) {
    float sa = 0.f, sb = 0.f;
#pragma unroll
    for (int j = 0; j < 6; ++j) { sa += ba[j] * WsA[j * 6 + k]; sb += bb[j] * WsB[j * 6 + k]; }
    sa *= rsA[k]; sb *= rsB[k];
    V8A[(size_t)n * 8 + k] = sa;
    V8B[(size_t)n * 8 + k] = sb;
    if (k < 3) {
      WA[(size_t)n * 4 + k] = sa;
      WB[(size_t)n * 4 + k] = sb;
      vals[k] = sa; vals[3 + k] = sb;
    }
  }
  V8A[(size_t)n * 8 + 6] = 0.f; V8A[(size_t)n * 8 + 7] = 0.f;
  V8B[(size_t)n * 8 + 6] = 0.f; V8B[(size_t)n * 8 + 7] = 0.f;
  WA[(size_t)n * 4 + 3] = 0.f;
  WB[(size_t)n * 4 + 3] = 0.f;
  float* tot = blk_sums(vals, 6);
  if (threadIdx.x == 0)
    for (int c = 0; c < 3; ++c) {
      atomicAdd(&SC[sA + c], tot[c]);
      atomicAdd(&SC[sB + c], tot[3 + c]);
    }
}

// after 3rd batch3 spmm: accum sigma0-2 + Uv0 scale + p0-W build
__global__ void b3post(const float* __restrict__ YA, const float* __restrict__ YB,
                       const float* __restrict__ ZZB, float* __restrict__ UvA,
                       float* __restrict__ UvB, float* __restrict__ WB,
                       float* __restrict__ SC, int zzA, int nyA, int zzB, int nyB,
                       int sWp) {
  if (blockIdx.x == 0 && threadIdx.x == 0) {
    float add = 0.f;
    for (int k = 0; k < 3; ++k) add += sqrtf(fabsf(SC[zzA + k] / SC[nyA + k]));
    for (int k = 0; k < 3; ++k) add += sqrtf(fabsf(SC[zzB + k] / SC[nyB + k]));
    SC[5] += add;
  }
  int n = blockIdx.x * 256 + threadIdx.x;
  UvA[n] = YA[(size_t)n * 4 + 2] * rsqrtf(SC[nyA + 2]);
  UvB[n] = YB[(size_t)n * 4 + 2] * rsqrtf(SC[nyB + 2]);
  float v = ZZB[(size_t)n * 4 + 2] * rsqrtf(SC[nyB + 2]);
  WB[(size_t)n * 4 + 0] = v;
  WB[(size_t)n * 4 + 1] = 0.f;
  WB[(size_t)n * 4 + 2] = 0.f;
  WB[(size_t)n * 4 + 3] = 0.f;
  float* tot = blk_sums(&v, 1);
  if (threadIdx.x == 0) atomicAdd(&SC[sWp], tot[0]);
}

// batched deflation builds (r5/r9 validated)
__global__ void buildAB(float* __restrict__ WA, int FCpad, int nt, int nu,
                        const float* __restrict__ V8A, int kcol,
                        const float* __restrict__ UvA, float* __restrict__ SC, int sWa,
                        float* __restrict__ WB, const float* __restrict__ V8B,
                        const float* __restrict__ UvB, int nd, int sWb, int Cidx,
                        const float* __restrict__ P4, float* __restrict__ Pv,
                        int pvmode, int prevdp, int prevny) {
  const int bid = blockIdx.x;
  const int n = (bid & 15) * 256 + threadIdx.x;
  if (bid < 16) {
    float bv = V8A[(size_t)n * 8 + kcol];
    float uv[3];
    for (int b = 0; b < 3; ++b) uv[b] = (b < nu) ? UvA[(size_t)b * N + n] : 0.f;
    float vals[8];
    for (int t = 0; t < FCpad; ++t) {
      float v = 0.f;
      if (t < nt) {
        v = bv;
        for (int b = 0; b < nu; ++b)
          if ((t >> b) & 1) v *= uv[b];
      }
      WA[(size_t)n * FCpad + t] = v;
      vals[t] = v;
    }
    float* tot = blk_sums(vals, nt);
    if (threadIdx.x == 0)
      for (int c = 0; c < nt; ++c) atomicAdd(&SC[sWa + c], tot[c]);
  } else {
    if (pvmode == 1) {
      Pv[n] = P4[(size_t)n * 4];
    } else if (pvmode >= 2) {
      float crs = rsqrtf(SC[prevny]);
      float s = P4[(size_t)n * 4];
      s -= SC[prevdp + 1] * crs * Pv[n];
      if (pvmode == 3) s -= SC[prevdp + 3] * crs * Pv[(size_t)N + n];
      Pv[(size_t)(pvmode - 1) * N + n] = s;
    }
    float v = V8B[(size_t)n * 8 + kcol];
    WB[(size_t)n * 4 + 0] = v;
    WB[(size_t)n * 4 + 1] = 0.f;
    WB[(size_t)n * 4 + 2] = 0.f;
    WB[(size_t)n * 4 + 3] = 0.f;
    float vals[4];
    vals[0] = v;
    for (int t = 0; t < 3; ++t) vals[1 + t] = (t < nd) ? UvB[(size_t)t * N + n] * v : 0.f;
    float* tot = blk_sums(vals, 1 + nd);
    if (threadIdx.x == 0) {
      atomicAdd(&SC[sWb], tot[0]);
      for (int t = 0; t < nd; ++t) atomicAdd(&SC[Cidx + t], tot[1 + t]);
    }
  }
}

// fused epilogue + 2nd build (r9 validated)
__global__ void epibuild(const float* __restrict__ YA, int FA, int nt, int nu,
                         const float* __restrict__ UvA, float* __restrict__ yvA, int nyA2,
                         float* __restrict__ WA, int sW2a,
                         const float* __restrict__ YB, const float* __restrict__ Pv,
                         const float* __restrict__ UvB, int nd, float* __restrict__ yvB,
                         int Cidx, int nyB2, int dp, float* __restrict__ WB, int sW2b,
                         float* __restrict__ SC) {
  const int bid = blockIdx.x;
  const int n = (bid & 15) * 256 + threadIdx.x;
  if (bid < 16) {
    float uv[3];
    for (int b = 0; b < 3; ++b) uv[b] = (b < nu) ? UvA[(size_t)b * N + n] : 0.f;
    float s = 0.f;
    for (int t = 0; t < nt; ++t) {
      float w = YA[(size_t)n * FA + t];
      int pc = 0;
      for (int b = 0; b < nu; ++b)
        if ((t >> b) & 1) { w *= uv[b]; ++pc; }
      s += (pc & 1) ? -w : w;
    }
    yvA[n] = s;
    float v = s * s;
    float* tot = blk_sums(&v, 1);
    if (threadIdx.x == 0) atomicAdd(&SC[nyA2], tot[0]);
    float vals[8];
    for (int t = 0; t < FA; ++t) {
      float v2 = 0.f;
      if (t < nt) {
        v2 = s;
        for (int b = 0; b < nu; ++b)
          if ((t >> b) & 1) v2 *= uv[b];
      }
      WA[(size_t)n * FA + t] = v2;
      vals[t] = v2;
    }
    float* tot2 = blk_sums(vals, nt);
    if (threadIdx.x == 0)
      for (int c = 0; c < nt; ++c) atomicAdd(&SC[sW2a + c], tot2[c]);
  } else {
    float y = YB[(size_t)n * 4];
    for (int t = 0; t < nd; ++t) y -= SC[Cidx + t] * Pv[(size_t)t * N + n];
    yvB[n] = y;
    float vals[7];
    vals[0] = y * y;
    for (int t = 0; t < 3; ++t) {
      vals[1 + 2 * t] = (t < nd) ? y * Pv[(size_t)t * N + n] : 0.f;
      vals[2 + 2 * t] = (t < nd) ? UvB[(size_t)t * N + n] * y : 0.f;
    }
    float* tot = blk_sums(vals, 1 + 2 * nd);
    if (threadIdx.x == 0) {
      atomicAdd(&SC[nyB2], tot[0]);
      for (int i = 0; i < 2 * nd; ++i) atomicAdd(&SC[dp + i], tot[1 + i]);
    }
    WB[(size_t)n * 4 + 0] = y;
    WB[(size_t)n * 4 + 1] = 0.f;
    WB[(size_t)n * 4 + 2] = 0.f;
    WB[(size_t)n * 4 + 3] = 0.f;
    float yy = y;
    float* tot2 = blk_sums(&yy, 1);
    if (threadIdx.x == 0) atomicAdd(&SC[sW2b], tot2[0]);
  }
}

// per-k post: accum + (dobuild) Uv scale + next-p W build + (dofin) finalize
__global__ void defpost(float* __restrict__ SC, int zzA2, int nt, int nyA2,
                        int zzB2, int nyB2, int dp, int nd,
                        const float* __restrict__ yvA, const float* __restrict__ yvB,
                        float* __restrict__ UvA, float* __restrict__ UvB, int k,
                        const float* __restrict__ ZZB, float* __restrict__ WB,
                        int sW3, int dobuild, int dofin, float* __restrict__ outp) {
  if (blockIdx.x == 0 && threadIdx.x == 0) {
    float vmv = 0.f;
    for (int t = 0; t < nt; ++t) {
      int pc = __popc(t);
      vmv += (pc & 1) ? -SC[zzA2 + t] : SC[zzA2 + t];
    }
    float add = sqrtf(fabsf(vmv / SC[nyA2]));
    float vb = SC[zzB2];
    for (int t = 0; t < nd; ++t) vb -= SC[dp + 2 * t] * SC[dp + 2 * t + 1];
    add += sqrtf(fabsf(vb / SC[nyB2]));
    SC[5] += add;
    if (dofin) {
      const float Ef = (float)EDG;
      float m1 = SC[0] / Ef, v1 = SC[1] / Ef - m1 * m1;
      float m2 = SC[2] / Ef, v2 = SC[3] / Ef - m2 * m2;
      outp[131072] = 0.01f * (v1 + v2) + 0.01f * SC[5];
      outp[393217] = SC[4] / (float)N;
    }
  }
  if (dobuild) {
    int n = blockIdx.x * 256 + threadIdx.x;
    UvA[(size_t)(k - 2) * N + n] = yvA[n] * rsqrtf(SC[nyA2]);
    UvB[(size_t)(k - 2) * N + n] = yvB[n] * rsqrtf(SC[nyB2]);
    float v = ZZB[(size_t)n * 4 + 0] * rsqrtf(SC[nyB2]);
    WB[(size_t)n * 4 + 0] = v;
    WB[(size_t)n * 4 + 1] = 0.f;
    WB[(size_t)n * 4 + 2] = 0.f;
    WB[(size_t)n * 4 + 3] = 0.f;
    float* tot = blk_sums(&v, 1);
    if (threadIdx.x == 0) atomicAdd(&SC[sW3], tot[0]);
  }
}

// ---------------------------------------------------------------------------
extern "C" void kernel_launch(void* const* d_in, const int* in_sizes, int n_in,
                              void* d_out, int out_size, void* d_ws, size_t ws_size,
                              hipStream_t stream) {
  const float* x      = (const float*)d_in[0];
  const int*   ei     = (const int*)  d_in[1];
  const float* gcn1_w = (const float*)d_in[2];
  const float* gcn1_b = (const float*)d_in[3];
  const float* gcn2_w = (const float*)d_in[4];
  const float* gcn2_b = (const float*)d_in[5];
  const float* p1w1   = (const float*)d_in[6];
  const float* p1b1   = (const float*)d_in[7];
  const float* p1w2   = (const float*)d_in[8];
  const float* p1b2   = (const float*)d_in[9];
  const float* p2w1   = (const float*)d_in[10];
  const float* p2b1   = (const float*)d_in[11];
  const float* p2w2   = (const float*)d_in[12];
  const float* p2b2   = (const float*)d_in[13];
  const float* omega1 = (const float*)d_in[14];
  const float* omega2 = (const float*)d_in[15];
  float* out = (float*)d_out;

  float* ws = (float*)d_ws;
  size_t o = 0;
  auto alloc = [&](size_t nf) { float* p = ws + o; o += nf; return p; };
  // ---- zeroed region (one memset): xw1 | h1 | Gd | cnt | deg1 | deg2 | SC ----
  float* xw1  = alloc((size_t)N * 64);
  float* h1   = alloc((size_t)N * 64);
  double* Gd  = (double*)(ws + o); o += 576;
  int* cnt    = (int*)(ws + o);    o += 2 * N;
  float* deg1 = alloc(N);
  float* deg2 = alloc(N);
  float* SC   = alloc(1024);
  const size_t zero_bytes = o * sizeof(float);
  // ---- rest ----
  float* x1   = alloc((size_t)N * 64);
  float* x1w  = alloc((size_t)N * 32);
  float* h2   = alloc((size_t)N * 16);
  float* xo   = alloc((size_t)N * 16);
  float* dis1 = alloc(N);
  float* dis2 = alloc(N);
  float* QA   = alloc((size_t)N * 8);
  float* QB   = alloc((size_t)N * 8);
  float* ZA   = alloc((size_t)N * 8);
  float* ZB   = alloc((size_t)N * 8);
  float* BtA  = alloc((size_t)N * 8);
  float* BtB  = alloc((size_t)N * 8);
  float* V8A  = alloc((size_t)N * 8);
  float* V8B  = alloc((size_t)N * 8);
  float* WA   = alloc((size_t)N * 8);
  float* WB   = alloc((size_t)N * 4);
  float* TA   = alloc((size_t)N * 8);
  float* TB   = alloc((size_t)N * 4);
  float* YA   = alloc((size_t)N * 8);
  float* YB   = alloc((size_t)N * 4);
  float* ZZA  = alloc((size_t)N * 8);
  float* ZZB  = alloc((size_t)N * 4);
  float* P4   = alloc((size_t)N * 4);
  float* yvA  = alloc(N);
  float* yvB  = alloc(N);
  float* UvA  = alloc((size_t)3 * N);
  float* UvB  = alloc((size_t)3 * N);
  float* Pv   = alloc((size_t)3 * N);
  float* SMFA = alloc(64);
  float* SMFB = alloc(64);
  int* rowptr = (int*)alloc(2 * (N + 1) + 2);
  int* cur    = (int*)alloc(2 * N);
  int* col_s  = (int*)alloc(EDG);
  int* perm_s = (int*)alloc(EDG);
  int* col_d  = (int*)alloc(EDG);
  int* perm_d = (int*)alloc(EDG);
  float* w1s  = alloc(EDG);
  float* w1d  = alloc(EDG);
  float* w2s  = alloc(EDG);
  float* w2d  = alloc(EDG);
  if (ws_size < o * sizeof(float)) return;

  const int* rp_s = rowptr;
  const int* rp_d = rowptr + (N + 1);

  int cs = 8;
  auto NS = [&]() { int s = cs; cs += 8; return s; };
  int gslot = 0;
  auto NG = [&]() { int g = gslot; gslot += 24; return g; };

  // ===================== init + CSR =====================
  hipMemsetAsync(ws, 0, zero_bytes, stream);
  hist_edges<<<512, 256, 0, stream>>>(ei, cnt);
  scan2x<<<2, 256, 0, stream>>>(cnt, rowptr, cur);
  scatter_edges<<<512, 256, 0, stream>>>(ei, cur, col_s, perm_s, col_d, perm_d);

  int omA = NS(), omB = NS();

  // ===================== layer 1 =====================
  gemm512k<<<dim3(256, 4), 256, 0, stream>>>(x, p1w1, gcn1_w, xw1, h1);
  edge_gate1c<<<1024, 256, 0, stream>>>(xw1, rp_s, col_s, perm_s, p1b1, p1w2, p1b2,
                                        out + 131073, w1s, deg1, SC);
  gatherdis_om<<<512, 256, 0, stream>>>(out + 131073, perm_d, w1d,
                                        deg1, dis1, omega1, omega2, SC, omA, omB);
  conv1f<<<1024, 256, 0, stream>>>(rp_d, col_d, w1d, h1, dis1, gcn1_b, x1);

  // ===================== layer 2 =====================
  gemm64<<<128, 256, 0, stream>>>(x1, p2w1, gcn2_w, x1w, h2);
  edge_gate2c<<<1024, 256, 0, stream>>>(x1w, rp_s, col_s, perm_s, p2b1, p2w2, p2b2,
                                        out + 262145, w2s, deg2, SC);
  gatherdis_om<<<512, 256, 0, stream>>>(out + 262145, perm_d, w2d,
                                        deg2, dis2, nullptr, nullptr, SC, 0, 0);
  conv2f<<<1024, 256, 0, stream>>>(rp_d, col_d, w2d, h2, dis2, gcn2_b, xo);
  softmax_calib<<<16, 256, 0, stream>>>(xo, out, out + 65536, SC);

  // ===================== batched SVD: one dispatch per power step ===========
  int g0a = NG(), g0b = NG(), g1a = NG(), g1b = NG(), g2a = NG(), g2b = NG();
  int g3a = NG(), g3b = NG(), g4a = NG(), g4b = NG(), g5a = NG(), g5b = NG();
  int c0a = NS(), c0b = NS(), c1a = NS(), c1b = NS(), c2a = NS(), c2b = NS();
  int c3a = NS(), c3b = NS(), c4a = NS(), c4b = NS(), c5a = NS(), c5b = NS();
  spmm8f<0, 6><<<512, 256, 0, stream>>>(rp_s, col_s, w1s, w2s, omega1, omega2,
                                        QA, QB, nullptr, nullptr, Gd + g0a, Gd + g0b,
                                        SC, omA, omB, c0a, c0b);
  spmm8f<1, 8><<<512, 256, 0, stream>>>(rp_d, col_d, w1d, w2d, QA, QB, ZA, ZB,
                                        Gd + g0a, Gd + g0b, Gd + g1a, Gd + g1b,
                                        SC, c0a, c0b, c1a, c1b);
  spmm8f<1, 8><<<512, 256, 0, stream>>>(rp_s, col_s, w1s, w2s, ZA, ZB, QA, QB,
                                        Gd + g1a, Gd + g1b, Gd + g2a, Gd + g2b,
                                        SC, c1a, c1b, c2a, c2b);
  spmm8f<1, 8><<<512, 256, 0, stream>>>(rp_d, col_d, w1d, w2d, QA, QB, ZA, ZB,
                                        Gd + g2a, Gd + g2b, Gd + g3a, Gd + g3b,
                                        SC, c2a, c2b, c3a, c3b);
  spmm8f<1, 8><<<512, 256, 0, stream>>>(rp_s, col_s, w1s, w2s, ZA, ZB, QA, QB,
                                        Gd + g3a, Gd + g3b, Gd + g4a, Gd + g4b,
                                        SC, c3a, c3b, c4a, c4b);
  spmm8f<1, 8><<<512, 256, 0, stream>>>(rp_d, col_d, w1d, w2d, QA, QB, BtA, BtB,
                                        Gd + g4a, Gd + g4b, Gd + g5a, Gd + g5b,
                                        SC, c4a, c4b, c5a, c5b);
  jacobi2<<<1, 64, 0, stream>>>(Gd + g5a, Gd + g5b, SMFA, SMFB);

  // ===================== batched batch3 =====================
  int sWa = NS(), sWb = NS();
  v_scale_pack<<<16, 256, 0, stream>>>(BtA, SMFA, BtB, SMFB, V8A, V8B, WA, WB,
                                       SC, sWa, sWb);
  int sTa = NS(), sTb = NS();
  spmm2<4, 4><<<1024, 256, 0, stream>>>(rp_d, col_d, w1d, w2d, WA, WB, TA, TB,
                                        SC, sWa, sWb, GEPS, sTa, -1, sTb, -1);
  int sYa = NS(), sYb = NS(), nyA = NS(), nyB = NS();
  spmm2<4, 4><<<1024, 256, 0, stream>>>(rp_s, col_s, w1s, w2s, TA, TB, YA, YB,
                                        SC, sTa, sTb, GEPS, sYa, nyA, sYb, nyB);
  int zzA = NS(), zzB = NS();
  spmm2<4, 4><<<1024, 256, 0, stream>>>(rp_d, col_d, w1d, w2d, YA, YB, ZZA, ZZB,
                                        SC, sYa, sYb, GEPS, -1, zzA, -1, zzB);
  int sWp = NS();
  b3post<<<16, 256, 0, stream>>>(YA, YB, ZZB, UvA, UvB, WB, SC, zzA, nyA, zzB, nyB, sWp);
  spmm<4, 0><<<1024, 256, 0, stream>>>(rp_s, col_s, w2s, WB, nullptr, P4, SC, sWp,
                                       GEPS, -1, -1);

  // ===================== batched deflation k=3,4,5 =====================
  int dp_prev = 0, ny_prev = 0;
  for (int k = 3; k <= 5; ++k) {
    const int nu = k - 2, nt = 1 << nu, nd = k - 2;
    const int FA = (k < 5) ? 4 : 8;
    int dWa = NS(), dWb = NS(), C = NS();
    int dTa = NS(), dTb = NS();
    int nyA2 = NS(), nyB2 = NS(), sW2a = NS(), sW2b = NS(), zzA2 = NS(), zzB2 = NS();
    int dp = NS(), sW3 = NS();
    const int pvmode = (k == 3) ? 1 : (k == 4 ? 2 : 3);
    buildAB<<<32, 256, 0, stream>>>(WA, FA, nt, nu, V8A, k, UvA, SC, dWa,
                                    WB, V8B, UvB, nd, dWb, C, P4, Pv,
                                    pvmode, dp_prev, ny_prev);
    if (FA == 4) {
      spmm2<4, 4><<<1024, 256, 0, stream>>>(rp_d, col_d, w1d, w2d, WA, WB, TA, TB,
                                            SC, dWa, dWb, GEPS, dTa, -1, dTb, -1);
      spmm2<4, 4><<<1024, 256, 0, stream>>>(rp_s, col_s, w1s, w2s, TA, TB, YA, YB,
                                            SC, dTa, dTb, GEPS, -1, -1, -1, -1);
    } else {
      spmm2<8, 4><<<1024, 256, 0, stream>>>(rp_d, col_d, w1d, w2d, WA, WB, TA, TB,
                                            SC, dWa, dWb, GEPS, dTa, -1, dTb, -1);
      spmm2<8, 4><<<1024, 256, 0, stream>>>(rp_s, col_s, w1s, w2s, TA, TB, YA, YB,
                                            SC, dTa, dTb, GEPS, -1, -1, -1, -1);
    }
    epibuild<<<32, 256, 0, stream>>>(YA, FA, nt, nu, UvA, yvA, nyA2, WA, sW2a,
                                     YB, Pv, UvB, nd, yvB, C, nyB2, dp, WB, sW2b, SC);
    if (FA == 4)
      spmm2<4, 4><<<1024, 256, 0, stream>>>(rp_d, col_d, w1d, w2d, WA, WB, ZZA, ZZB,
                                            SC, sW2a, sW2b, GEPS, -1, zzA2, -1, zzB2);
    else
      spmm2<8, 4><<<1024, 256, 0, stream>>>(rp_d, col_d, w1d, w2d, WA, WB, ZZA, ZZB,
                                            SC, sW2a, sW2b, GEPS, -1, zzA2, -1, zzB2);
    if (k < 5) {
      defpost<<<16, 256, 0, stream>>>(SC, zzA2, nt, nyA2, zzB2, nyB2, dp, nd,
                                      yvA, yvB, UvA, UvB, k, ZZB, WB, sW3, 1, 0, out);
      spmm<4, 0><<<1024, 256, 0, stream>>>(rp_s, col_s, w2s, WB, nullptr, P4, SC, sW3,
                                           GEPS, -1, -1);
    } else {
      defpost<<<1, 256, 0, stream>>>(SC, zzA2, nt, nyA2, zzB2, nyB2, dp, nd,
                                     yvA, yvB, UvA, UvB, k, ZZB, WB, sW3, 0, 1, out);
    }
    dp_prev = dp; ny_prev = nyB2;
  }
}

// Round 15
// 786.790 us; speedup vs baseline: 1.0433x; 1.0411x over previous
//
#include <hip/hip_runtime.h>
#include <cmath>

constexpr int N = 4096;
constexpr int EDG = 131072;
constexpr float GEPS = 1e-6f;

// ---------------------------------------------------------------------------
__device__ __forceinline__ float* blk_sums(float* vals, int cnt) {
  __shared__ float part[4][16];
  __shared__ float tot[16];
  const int lane = threadIdx.x & 63, wv = threadIdx.x >> 6;
  for (int c = 0; c < cnt; ++c) {
    float v = vals[c];
    for (int off = 32; off; off >>= 1) v += __shfl_down(v, off);
    if (lane == 0) part[wv][c] = v;
  }
  __syncthreads();
  if (threadIdx.x == 0)
    for (int c = 0; c < cnt; ++c)
      tot[c] = part[0][c] + part[1][c] + part[2][c] + part[3][c];
  __syncthreads();
  return tot;
}

// ---------------------------------------------------------------------------
// CSR build
__global__ void hist_edges(const int* __restrict__ ei, int* __restrict__ cnt) {
  int e = blockIdx.x * 256 + threadIdx.x;
  atomicAdd(&cnt[ei[e]], 1);
  atomicAdd(&cnt[N + ei[EDG + e]], 1);
}

__global__ __launch_bounds__(256) void scan2x(const int* __restrict__ cnt,
                                              int* __restrict__ rowptr,
                                              int* __restrict__ cur) {
  const int b = blockIdx.x;
  const int* c = cnt + b * N;
  int* rp = rowptr + b * (N + 1);
  int* cu = cur + b * N;
  __shared__ int part[256];
  const int t = threadIdx.x;
  int local[16], s = 0;
  const int base = t * 16;
  for (int i = 0; i < 16; ++i) { local[i] = s; s += c[base + i]; }
  part[t] = s;
  __syncthreads();
  if (t == 0) {
    int acc = 0;
    for (int i = 0; i < 256; ++i) { int v = part[i]; part[i] = acc; acc += v; }
  }
  __syncthreads();
  const int off = part[t];
  for (int i = 0; i < 16; ++i) { rp[base + i] = off + local[i]; cu[base + i] = off + local[i]; }
  if (t == 255) rp[N] = off + s;
}

__global__ void scatter_edges(const int* __restrict__ ei, int* __restrict__ cur,
                              int* __restrict__ col_s, int* __restrict__ perm_s,
                              int* __restrict__ col_d, int* __restrict__ perm_d) {
  int e = blockIdx.x * 256 + threadIdx.x;
  int s = ei[e], d = ei[EDG + e];
  int ps = atomicAdd(&cur[s], 1);
  col_s[ps] = d; perm_s[ps] = e;
  int pd = atomicAdd(&cur[N + d], 1);
  col_d[pd] = s; perm_d[pd] = e;
}

// gather edge weights into dst-CSR order + compute dis; optional omega colsums
__global__ void gatherdis_om(const float* __restrict__ s,
                             const int* __restrict__ perm_d,
                             float* __restrict__ wd_, const float* __restrict__ deg,
                             float* __restrict__ dis, const float* __restrict__ om1,
                             const float* __restrict__ om2, float* __restrict__ SC,
                             int omA, int omB) {
  int p = blockIdx.x * 256 + threadIdx.x;
  wd_[p] = s[perm_d[p]];
  if (p < N) dis[p] = rsqrtf(deg[p] + 1.0f);
  if (om1 && blockIdx.x < 16) {
    int n = p;  // < 4096
    float vals[12];
#pragma unroll
    for (int k = 0; k < 6; ++k) {
      vals[k] = om1[(size_t)n * 6 + k];
      vals[6 + k] = om2[(size_t)n * 6 + k];
    }
    float* tot = blk_sums(vals, 12);
    if (threadIdx.x == 0)
      for (int c = 0; c < 6; ++c) {
        atomicAdd(&SC[omA + c], tot[c]);
        atomicAdd(&SC[omB + c], tot[6 + c]);
      }
  }
}

// ---------------------------------------------------------------------------
// Split-K fused layer-1 GEMM (r13 validated: split-K 4)
__global__ __launch_bounds__(256) void gemm512k(const float* __restrict__ A,
                                                const float* __restrict__ W1,
                                                const float* __restrict__ W2,
                                                float* __restrict__ O1,
                                                float* __restrict__ O2) {
  __shared__ float As[16][33];
  __shared__ float Ws[32][128];
  const int t = threadIdx.x;
  const int rt = t >> 4;
  const int ct = t & 15;
  const int r0 = blockIdx.x * 16;
  const int kh = blockIdx.y * 128;
  float acc[8];
#pragma unroll
  for (int j = 0; j < 8; ++j) acc[j] = 0.f;
  for (int kc = 0; kc < 128; kc += 32) {
    const int kb = kh + kc;
    __syncthreads();
    for (int i = t; i < 512; i += 256) {
      int rr = i >> 5, kk = i & 31;
      As[rr][kk] = A[(size_t)(r0 + rr) * 512 + kb + kk];
    }
    for (int i = t; i < 1024; i += 256) {
      int row = i >> 5, c4 = i & 31;
      float4 v;
      if (c4 < 16) v = *(const float4*)&W1[(size_t)(kb + row) * 64 + c4 * 4];
      else         v = *(const float4*)&W2[(size_t)(kb + row) * 64 + (c4 - 16) * 4];
      *(float4*)&Ws[row][c4 * 4] = v;
    }
    __syncthreads();
#pragma unroll
    for (int kk = 0; kk < 32; ++kk) {
      float a = As[rt][kk];
      float4 b0 = *(const float4*)&Ws[kk][ct * 4];
      float4 b1 = *(const float4*)&Ws[kk][64 + ct * 4];
      acc[0] += a * b0.x; acc[1] += a * b0.y;
      acc[2] += a * b0.z; acc[3] += a * b0.w;
      acc[4] += a * b1.x; acc[5] += a * b1.y;
      acc[6] += a * b1.z; acc[7] += a * b1.w;
    }
  }
  const int r = r0 + rt;
#pragma unroll
  for (int j = 0; j < 4; ++j) {
    atomicAdd(&O1[(size_t)r * 64 + ct * 4 + j], acc[j]);
    atomicAdd(&O2[(size_t)r * 64 + ct * 4 + j], acc[4 + j]);
  }
}

// Fused layer-2 GEMM (validated)
__global__ __launch_bounds__(256) void gemm64(const float* __restrict__ A,
                                              const float* __restrict__ W1,
                                              const float* __restrict__ W2,
                                              float* __restrict__ O1,
                                              float* __restrict__ O2) {
  __shared__ float As[32][65];
  __shared__ float Ws[64][48];
  const int t = threadIdx.x;
  const int r = t >> 3;
  const int cg = t & 7;
  const int r0 = blockIdx.x * 32;
  for (int idx = t; idx < 32 * 64; idx += 256)
    As[idx >> 6][idx & 63] = A[(size_t)(r0 + (idx >> 6)) * 64 + (idx & 63)];
  for (int idx = t; idx < 64 * 48; idx += 256) {
    int kk = idx / 48, c = idx % 48;
    Ws[kk][c] = (c < 32) ? W1[kk * 32 + c] : W2[kk * 16 + c - 32];
  }
  __syncthreads();
  float acc[6] = {0.f, 0.f, 0.f, 0.f, 0.f, 0.f};
  for (int k = 0; k < 64; ++k) {
    float a = As[r][k];
#pragma unroll
    for (int j = 0; j < 6; ++j) acc[j] += a * Ws[k][cg + 8 * j];
  }
  int n = r0 + r;
#pragma unroll
  for (int j = 0; j < 6; ++j) {
    int c = cg + 8 * j;
    if (c < 32) O1[(size_t)n * 32 + c] = acc[j];
    else O2[(size_t)n * 16 + c - 32] = acc[j];
  }
}

// ---------------------------------------------------------------------------
// edge gate 1 (r12 validated)
__global__ void edge_gate1c(const float* __restrict__ xw, const int* __restrict__ rp,
                            const int* __restrict__ cl, const int* __restrict__ perm,
                            const float* __restrict__ b1, const float* __restrict__ w2,
                            const float* __restrict__ b2, float* __restrict__ s_out,
                            float* __restrict__ wcs, float* __restrict__ deg,
                            float* __restrict__ SCs) {
  const int lane = threadIdx.x & 63;
  const int wave = threadIdx.x >> 6;
  const int u = lane >> 4;
  const int q = lane & 15;
  const float4 b1q = ((const float4*)b1)[q];
  const float4 w2q = ((const float4*)w2)[q];
  const float b2s = b2[0];
  const float4* xw4 = (const float4*)xw;
  const int r = blockIdx.x * 4 + wave;
  const float4 xsr = xw4[(size_t)r * 16 + q];
  const int e0 = rp[r], e1 = rp[r + 1];
  float lsum = 0.f, lssq = 0.f;
  int e = e0 + u;
  for (; e + 4 < e1; e += 8) {
    int d0 = cl[e], d1 = cl[e + 4];
    float4 xd0 = xw4[(size_t)d0 * 16 + q];
    float4 xd1 = xw4[(size_t)d1 * 16 + q];
    float g0 = fmaxf(xsr.x - xd0.x + b1q.x, 0.f) * w2q.x
             + fmaxf(xsr.y - xd0.y + b1q.y, 0.f) * w2q.y
             + fmaxf(xsr.z - xd0.z + b1q.z, 0.f) * w2q.z
             + fmaxf(xsr.w - xd0.w + b1q.w, 0.f) * w2q.w;
    float g1 = fmaxf(xsr.x - xd1.x + b1q.x, 0.f) * w2q.x
             + fmaxf(xsr.y - xd1.y + b1q.y, 0.f) * w2q.y
             + fmaxf(xsr.z - xd1.z + b1q.z, 0.f) * w2q.z
             + fmaxf(xsr.w - xd1.w + b1q.w, 0.f) * w2q.w;
#pragma unroll
    for (int off = 1; off < 16; off <<= 1) {
      g0 += __shfl_xor(g0, off);
      g1 += __shfl_xor(g1, off);
    }
    if (q == 0) {
      float a0 = g0 + b2s; a0 *= a0;
      float a1 = g1 + b2s; a1 *= a1;
      float s0 = 1.f / (1.f + __expf(-a0));
      float s1 = 1.f / (1.f + __expf(-a1));
      s_out[perm[e]] = s0;     wcs[e] = s0;
      s_out[perm[e + 4]] = s1; wcs[e + 4] = s1;
      atomicAdd(&deg[d0], s0);
      atomicAdd(&deg[d1], s1);
      lsum += s0 + s1; lssq += s0 * s0 + s1 * s1;
    }
  }
  for (; e < e1; e += 4) {
    int d = cl[e];
    float4 xd = xw4[(size_t)d * 16 + q];
    float g = fmaxf(xsr.x - xd.x + b1q.x, 0.f) * w2q.x
            + fmaxf(xsr.y - xd.y + b1q.y, 0.f) * w2q.y
            + fmaxf(xsr.z - xd.z + b1q.z, 0.f) * w2q.z
            + fmaxf(xsr.w - xd.w + b1q.w, 0.f) * w2q.w;
#pragma unroll
    for (int off = 1; off < 16; off <<= 1) g += __shfl_xor(g, off);
    if (q == 0) {
      float a = g + b2s; a *= a;
      float sv = 1.f / (1.f + __expf(-a));
      s_out[perm[e]] = sv; wcs[e] = sv;
      atomicAdd(&deg[d], sv);
      lsum += sv; lssq += sv * sv;
    }
  }
  float* tot = blk_sums(&lsum, 1);
  float* tot2 = blk_sums(&lssq, 1);
  if (threadIdx.x == 0) {
    atomicAdd(&SCs[0], tot[0]);
    atomicAdd(&SCs[1], tot2[0]);
  }
}

// edge gate 2 (r12 validated)
__global__ void edge_gate2c(const float* __restrict__ xw, const int* __restrict__ rp,
                            const int* __restrict__ cl, const int* __restrict__ perm,
                            const float* __restrict__ b1, const float* __restrict__ w2,
                            const float* __restrict__ b2, float* __restrict__ s_out,
                            float* __restrict__ wcs, float* __restrict__ deg,
                            float* __restrict__ SCs) {
  const int lane = threadIdx.x & 63;
  const int wave = threadIdx.x >> 6;
  const int u = lane >> 3;
  const int q = lane & 7;
  const float4 b1q = ((const float4*)b1)[q];
  const float4 w2q = ((const float4*)w2)[q];
  const float b2s = b2[0];
  const float4* xw4 = (const float4*)xw;
  const int r = blockIdx.x * 4 + wave;
  const float4 xsr = xw4[(size_t)r * 8 + q];
  const int e0 = rp[r], e1 = rp[r + 1];
  float lsum = 0.f, lssq = 0.f;
  int e = e0 + u;
  for (; e + 8 < e1; e += 16) {
    int d0 = cl[e], d1 = cl[e + 8];
    float4 xd0 = xw4[(size_t)d0 * 8 + q];
    float4 xd1 = xw4[(size_t)d1 * 8 + q];
    float g0 = fmaxf(xsr.x - xd0.x + b1q.x, 0.f) * w2q.x
             + fmaxf(xsr.y - xd0.y + b1q.y, 0.f) * w2q.y
             + fmaxf(xsr.z - xd0.z + b1q.z, 0.f) * w2q.z
             + fmaxf(xsr.w - xd0.w + b1q.w, 0.f) * w2q.w;
    float g1 = fmaxf(xsr.x - xd1.x + b1q.x, 0.f) * w2q.x
             + fmaxf(xsr.y - xd1.y + b1q.y, 0.f) * w2q.y
             + fmaxf(xsr.z - xd1.z + b1q.z, 0.f) * w2q.z
             + fmaxf(xsr.w - xd1.w + b1q.w, 0.f) * w2q.w;
#pragma unroll
    for (int off = 1; off < 8; off <<= 1) {
      g0 += __shfl_xor(g0, off);
      g1 += __shfl_xor(g1, off);
    }
    if (q == 0) {
      float a0 = g0 + b2s; a0 *= a0;
      float a1 = g1 + b2s; a1 *= a1;
      float s0 = 1.f / (1.f + __expf(-a0));
      float s1 = 1.f / (1.f + __expf(-a1));
      s_out[perm[e]] = s0;     wcs[e] = s0;
      s_out[perm[e + 8]] = s1; wcs[e + 8] = s1;
      atomicAdd(&deg[d0], s0);
      atomicAdd(&deg[d1], s1);
      lsum += s0 + s1; lssq += s0 * s0 + s1 * s1;
    }
  }
  for (; e < e1; e += 8) {
    int d = cl[e];
    float4 xd = xw4[(size_t)d * 8 + q];
    float g = fmaxf(xsr.x - xd.x + b1q.x, 0.f) * w2q.x
            + fmaxf(xsr.y - xd.y + b1q.y, 0.f) * w2q.y
            + fmaxf(xsr.z - xd.z + b1q.z, 0.f) * w2q.z
            + fmaxf(xsr.w - xd.w + b1q.w, 0.f) * w2q.w;
#pragma unroll
    for (int off = 1; off < 8; off <<= 1) g += __shfl_xor(g, off);
    if (q == 0) {
      float a = g + b2s; a *= a;
      float sv = 1.f / (1.f + __expf(-a));
      s_out[perm[e]] = sv; wcs[e] = sv;
      atomicAdd(&deg[d], sv);
      lsum += sv; lssq += sv * sv;
    }
  }
  float* tot = blk_sums(&lsum, 1);
  float* tot2 = blk_sums(&lssq, 1);
  if (threadIdx.x == 0) {
    atomicAdd(&SCs[2], tot[0]);
    atomicAdd(&SCs[3], tot2[0]);
  }
}

// conv1 fused (r11 validated)
__global__ void conv1f(const int* __restrict__ rp, const int* __restrict__ cl,
                       const float* __restrict__ w, const float* __restrict__ h1,
                       const float* __restrict__ dis, const float* __restrict__ bias,
                       float* __restrict__ x1) {
  const int lane = threadIdx.x & 63, wv = threadIdx.x >> 6;
  const int es = lane >> 4;
  const int q = lane & 15;
  const int r = blockIdx.x * 4 + wv;
  const int e0 = rp[r], e1 = rp[r + 1];
  const float4* h14 = (const float4*)h1;
  float ax = 0.f, ay = 0.f, az = 0.f, aw = 0.f;
  int e = e0 + es;
  for (; e + 4 < e1; e += 8) {
    int c0 = cl[e], c1 = cl[e + 4];
    float w0 = w[e] * dis[c0], w1_ = w[e + 4] * dis[c1];
    float4 h0 = h14[(size_t)c0 * 16 + q];
    float4 h1v = h14[(size_t)c1 * 16 + q];
    ax += w0 * h0.x + w1_ * h1v.x;
    ay += w0 * h0.y + w1_ * h1v.y;
    az += w0 * h0.z + w1_ * h1v.z;
    aw += w0 * h0.w + w1_ * h1v.w;
  }
  for (; e < e1; e += 4) {
    int c = cl[e];
    float wx = w[e] * dis[c];
    float4 hv = h14[(size_t)c * 16 + q];
    ax += wx * hv.x; ay += wx * hv.y; az += wx * hv.z; aw += wx * hv.w;
  }
  ax += __shfl_xor(ax, 16); ax += __shfl_xor(ax, 32);
  ay += __shfl_xor(ay, 16); ay += __shfl_xor(ay, 32);
  az += __shfl_xor(az, 16); az += __shfl_xor(az, 32);
  aw += __shfl_xor(aw, 16); aw += __shfl_xor(aw, 32);
  if (es == 0) {
    float d = dis[r];
    float4 hh = h14[(size_t)r * 16 + q];
    float4 bq = ((const float4*)bias)[q];
    float4 o;
    o.x = fmaxf(d * (ax + d * hh.x) + bq.x, 0.f);
    o.y = fmaxf(d * (ay + d * hh.y) + bq.y, 0.f);
    o.z = fmaxf(d * (az + d * hh.z) + bq.z, 0.f);
    o.w = fmaxf(d * (aw + d * hh.w) + bq.w, 0.f);
    ((float4*)x1)[(size_t)r * 16 + q] = o;
  }
}

// conv2 fused -> logits (r11 validated)
__global__ void conv2f(const int* __restrict__ rp, const int* __restrict__ cl,
                       const float* __restrict__ w, const float* __restrict__ h2,
                       const float* __restrict__ dis, const float* __restrict__ bias,
                       float* __restrict__ xo) {
  const int lane = threadIdx.x & 63, wv = threadIdx.x >> 6;
  const int es = lane >> 2;
  const int q = lane & 3;
  const int r = blockIdx.x * 4 + wv;
  const int e0 = rp[r], e1 = rp[r + 1];
  const float4* h24 = (const float4*)h2;
  float ax = 0.f, ay = 0.f, az = 0.f, aw = 0.f;
  for (int e = e0 + es; e < e1; e += 16) {
    int c = cl[e];
    float wx = w[e] * dis[c];
    float4 hv = h24[(size_t)c * 4 + q];
    ax += wx * hv.x; ay += wx * hv.y; az += wx * hv.z; aw += wx * hv.w;
  }
#pragma unroll
  for (int off = 4; off < 64; off <<= 1) {
    ax += __shfl_xor(ax, off);
    ay += __shfl_xor(ay, off);
    az += __shfl_xor(az, off);
    aw += __shfl_xor(aw, off);
  }
  if (es == 0) {
    float d = dis[r];
    float4 hh = h24[(size_t)r * 4 + q];
    float4 bq = ((const float4*)bias)[q];
    float4 o;
    o.x = d * (ax + d * hh.x) + bq.x;
    o.y = d * (ay + d * hh.y) + bq.y;
    o.z = d * (az + d * hh.z) + bq.z;
    o.w = d * (aw + d * hh.w) + bq.w;
    ((float4*)xo)[(size_t)r * 4 + q] = o;
  }
}

// softmax + calib from logits (validated r3/r5)
__global__ void softmax_calib(const float* __restrict__ xo, float* __restrict__ ls,
                              float* __restrict__ sm, float* __restrict__ SC) {
  const int t = threadIdx.x;
  const int r = blockIdx.x * 256 + t;
  float v[16];
  float mx = -3.0e38f, mx2 = -3.0e38f;
#pragma unroll
  for (int c = 0; c < 16; ++c) {
    v[c] = xo[(size_t)r * 16 + c];
    if (v[c] > mx) { mx2 = mx; mx = v[c]; }
    else if (v[c] > mx2) mx2 = v[c];
  }
  float se = 0.f;
#pragma unroll
  for (int c = 0; c < 16; ++c) se += expf(v[c] - mx);
  const float lse = mx + logf(se);
#pragma unroll
  for (int c = 0; c < 16; ++c) {
    float z = v[c] - lse;
    ls[(size_t)r * 16 + c] = z;
    sm[(size_t)r * 16 + c] = expf(z);
  }
  float calib = mx2 - mx;
  float* tot = blk_sums(&calib, 1);
  if (t == 0) atomicAdd(&SC[4], tot[0]);
}

// ---------------------------------------------------------------------------
// Fused SVD power step (r8) with fp32 Cholesky prologue (r9).
template<int NORM, int SX>
__global__ __launch_bounds__(256) void spmm8f(
    const int* __restrict__ rp, const int* __restrict__ cl,
    const float* __restrict__ wA, const float* __restrict__ wB,
    const float* __restrict__ XA, const float* __restrict__ XB,
    float* __restrict__ OA, float* __restrict__ OB,
    const double* __restrict__ GpA, const double* __restrict__ GpB,
    double* __restrict__ GnA, double* __restrict__ GnB,
    float* __restrict__ SC, int cspA, int cspB, int csoA, int csoB) {
  __shared__ float Rinv[2][36];
  __shared__ float csn[2][8];
  __shared__ float bs[2][8];
  __shared__ float gpart[8][21];
  const int t = threadIdx.x;
  if (NORM) {
    if (t < 2) {
      const double* G = t ? GpB : GpA;
      const float* csp = SC + (t ? cspB : cspA);
      float Gf[6][6];
      int p = 0;
      for (int i = 0; i < 6; ++i)
        for (int j = i; j < 6; ++j) { float gv = (float)G[p]; Gf[i][j] = gv; Gf[j][i] = gv; ++p; }
      float Rm[6][6];
      for (int i = 0; i < 6; ++i) for (int j = 0; j < 6; ++j) Rm[i][j] = 0.f;
      for (int j = 0; j < 6; ++j) {
        float s = Gf[j][j];
        for (int k = 0; k < j; ++k) s -= Rm[k][j] * Rm[k][j];
        float dj = sqrtf(fmaxf(s, 1e-30f));
        Rm[j][j] = dj;
        for (int i = j + 1; i < 6; ++i) {
          float v = Gf[j][i];
          for (int k = 0; k < j; ++k) v -= Rm[k][j] * Rm[k][i];
          Rm[j][i] = v / dj;
        }
      }
      float Ri[6][6];
      for (int j = 0; j < 6; ++j) {
        Ri[j][j] = 1.f / Rm[j][j];
        for (int i = j - 1; i >= 0; --i) {
          float s = 0.f;
          for (int k = i + 1; k <= j; ++k) s += Rm[i][k] * Ri[k][j];
          Ri[i][j] = -s / Rm[i][i];
        }
      }
      for (int i = 0; i < 6; ++i)
        for (int j = 0; j < 6; ++j)
          Rinv[t][i * 6 + j] = (j >= i) ? Ri[i][j] : 0.f;
      for (int f = 0; f < 8; ++f) {
        float s = 0.f;
        if (f < 6)
          for (int j = 0; j <= f; ++j) s += csp[j] * Ri[j][f];
        csn[t][f] = s;
      }
    }
  } else {
    if (t < 16) {
      int h = t >> 3, f = t & 7;
      csn[h][f] = (f < 6) ? SC[(h ? cspB : cspA) + f] : 0.f;
    }
  }
  if (t < 16) bs[t >> 3][t & 7] = 0.f;
  __syncthreads();
  const int lane = t & 63, wv = t >> 6;
  const int half = lane >> 5, la = lane & 31;
  const int f = la & 7, es = la >> 3;
  const float* w = half ? wB : wA;
  const float* X = half ? XB : XA;
  float* O = half ? OB : OA;
  const float* Ri = Rinv[half];
  const float epsf = csn[half][f] * GEPS;
  float gp[6];
#pragma unroll
  for (int j = 0; j < 6; ++j) gp[j] = 0.f;
  for (int rr = 0; rr < 2; ++rr) {
    const int r = blockIdx.x * 8 + wv * 2 + rr;
    const int e0 = rp[r], e1 = rp[r + 1];
    float acc = 0.f;
    if (f < 6) {
      for (int e = e0 + es; e < e1; e += 4) {
        int c = cl[e];
        const float* xr = X + (size_t)c * SX;
        float xn;
        if (NORM) {
          xn = 0.f;
          for (int j = 0; j <= f; ++j) xn += xr[j] * Ri[j * 6 + f];
        } else {
          xn = xr[f];
        }
        acc += w[e] * xn;
      }
    }
    acc += __shfl_xor(acc, 8);
    acc += __shfl_xor(acc, 16);
    float o = acc + epsf;
    float ov[6];
#pragma unroll
    for (int j = 0; j < 6; ++j) ov[j] = __shfl(o, half * 32 + j);
    if (es == 0) {
      O[((size_t)r << 3) + f] = o;
      if (f < 6) {
        atomicAdd(&bs[half][f], o);
#pragma unroll
        for (int j = 0; j < 6; ++j)
          if (j >= f) gp[j - f] += o * ov[j];
      }
    }
  }
  if (es == 0 && f < 6) {
    int p0 = f * 6 - (f * (f - 1)) / 2;
    for (int j = 0; j < 6 - f; ++j) gpart[wv * 2 + half][p0 + j] = gp[j];
  }
  __syncthreads();
  if (t < 42) {
    int h = t / 21, p = t % 21;
    float s = gpart[h][p] + gpart[2 + h][p] + gpart[4 + h][p] + gpart[6 + h][p];
    atomicAdd(&(h ? GnB : GnA)[p], (double)s);
  }
  if (t < 16) {
    int h = t >> 3, ff = t & 7;
    if (ff < 6) atomicAdd(&SC[(h ? csoB : csoA) + ff], bs[h][ff]);
  }
}

// ---------------------------------------------------------------------------
// single-graph SpMM (p-passes)
template<int F, int DIS>
__global__ __launch_bounds__(256) void spmm(const int* __restrict__ rowptr,
                                            const int* __restrict__ col,
                                            const float* __restrict__ w,
                                            const float* __restrict__ X,
                                            const float* __restrict__ dis,
                                            float* __restrict__ OUT,
                                            float* __restrict__ SC, int cs_idx,
                                            float eps, int osum, int ossq) {
  constexpr int ES = 64 / F;
  const int lane = threadIdx.x & 63;
  const int wv = threadIdx.x >> 6;
  const int f = lane & (F - 1);
  const int es = lane / F;
  const int r = blockIdx.x * 4 + wv;
  const int e0 = rowptr[r], e1 = rowptr[r + 1];
  float acc = 0.f;
  for (int e = e0 + es; e < e1; e += ES) {
    int c = col[e];
    float wx = w[e];
    if (DIS) wx *= dis[c];
    acc += wx * X[(size_t)c * F + f];
  }
#pragma unroll
  for (int off = F; off < 64; off <<= 1) acc += __shfl_xor(acc, off);
  float o = acc + ((cs_idx >= 0) ? eps * SC[cs_idx + f] : 0.f);
  if (es == 0) OUT[(size_t)r * F + f] = o;
  if (osum >= 0 || ossq >= 0) {
    __shared__ float bs[8], bq[8];
    if (threadIdx.x < F) { bs[threadIdx.x] = 0.f; bq[threadIdx.x] = 0.f; }
    __syncthreads();
    if (es == 0) {
      if (osum >= 0) atomicAdd(&bs[f], o);
      if (ossq >= 0) atomicAdd(&bq[f], o * o);
    }
    __syncthreads();
    if (threadIdx.x < F) {
      if (osum >= 0) atomicAdd(&SC[osum + threadIdx.x], bs[threadIdx.x]);
      if (ossq >= 0) atomicAdd(&SC[ossq + threadIdx.x], bq[threadIdx.x]);
    }
  }
}

// Batched two-graph SpMM (validated r5)
template<int FA, int FB>
__global__ __launch_bounds__(256) void spmm2(const int* __restrict__ rowptr,
                                             const int* __restrict__ col,
                                             const float* __restrict__ wA,
                                             const float* __restrict__ wB,
                                             const float* __restrict__ XA,
                                             const float* __restrict__ XB,
                                             float* __restrict__ OA,
                                             float* __restrict__ OB,
                                             float* __restrict__ SC,
                                             int csA, int csB, float eps,
                                             int osumA, int ossqA, int osumB, int ossqB) {
  const int lane = threadIdx.x & 63;
  const int wv = threadIdx.x >> 6;
  const int half = lane >> 5;
  const int la = lane & 31;
  const int F = half ? FB : FA;
  const int f = la & (F - 1);
  const int es = la / F;
  const int ES = 32 / F;
  const int r = blockIdx.x * 4 + wv;
  const int e0 = rowptr[r], e1 = rowptr[r + 1];
  const float* w = half ? wB : wA;
  const float* X = half ? XB : XA;
  float acc = 0.f;
  for (int e = e0 + es; e < e1; e += ES)
    acc += w[e] * X[(size_t)col[e] * F + f];
  for (int off = F; off < 32; off <<= 1) acc += __shfl_xor(acc, off);
  const int cs = half ? csB : csA;
  float o = acc + ((cs >= 0) ? eps * SC[cs + f] : 0.f);
  if (es == 0) {
    float* O = half ? OB : OA;
    O[(size_t)r * F + f] = o;
  }
  if (osumA >= 0 || ossqA >= 0 || osumB >= 0 || ossqB >= 0) {
    __shared__ float bs[2][8], bq[2][8];
    if (threadIdx.x < 16) { bs[threadIdx.x >> 3][threadIdx.x & 7] = 0.f;
                            bq[threadIdx.x >> 3][threadIdx.x & 7] = 0.f; }
    __syncthreads();
    const int osum = half ? osumB : osumA, ossq = half ? ossqB : ossqA;
    if (es == 0) {
      if (osum >= 0) atomicAdd(&bs[half][f], o);
      if (ossq >= 0) atomicAdd(&bq[half][f], o * o);
    }
    __syncthreads();
    if (threadIdx.x < 16) {
      int h = threadIdx.x >> 3, ff = threadIdx.x & 7;
      int os_ = h ? osumB : osumA, oq_ = h ? ossqB : ossqA;
      int Fh = h ? FB : FA;
      if (os_ >= 0 && ff < Fh) atomicAdd(&SC[os_ + ff], bs[h][ff]);
      if (oq_ >= 0 && ff < Fh) atomicAdd(&SC[oq_ + ff], bq[h][ff]);
    }
  }
}

// ---------------------------------------------------------------------------
// r15: serial fp32 6x6 Jacobi, fully unrolled, __launch_bounds__(64,1) so the
// allocator may use up to 512 VGPRs (r14's spill cause: default 64-VGPR cap).
__global__ __launch_bounds__(64, 1) void jacobi2(const double* __restrict__ GA,
                                                 const double* __restrict__ GB,
                                                 float* __restrict__ SMFA,
                                                 float* __restrict__ SMFB) {
  __shared__ float diag_s[2][6];
  __shared__ float V_s[2][36];
  __shared__ int idx_s[2][6];
  const int t = threadIdx.x;
  if (t < 2) {
    const double* G = t ? GB : GA;
    float A[6][6], V[6][6];
    {
      int p = 0;
#pragma unroll
      for (int i = 0; i < 6; ++i)
#pragma unroll
        for (int j = i; j < 6; ++j) {
          float gv = (float)G[p];
          A[i][j] = gv; A[j][i] = gv; ++p;
        }
    }
#pragma unroll
    for (int i = 0; i < 6; ++i)
#pragma unroll
      for (int j = 0; j < 6; ++j) V[i][j] = (i == j) ? 1.f : 0.f;
#pragma unroll
    for (int sweep = 0; sweep < 5; ++sweep) {
#pragma unroll
      for (int pi = 0; pi < 5; ++pi) {
#pragma unroll
        for (int qi = pi + 1; qi < 6; ++qi) {
          float apq = A[pi][qi];
          float app = A[pi][pi], aqq = A[qi][qi];
          float tau = (aqq - app) / (2.f * apq);
          float rt_ = sqrtf(1.f + tau * tau);
          float tt = (tau >= 0.f) ? 1.f / (tau + rt_) : 1.f / (tau - rt_);
          bool ok = fabsf(apq) > 1e-30f;
          float cc = rsqrtf(1.f + tt * tt);
          float c = ok ? cc : 1.f;
          float s = ok ? tt * cc : 0.f;
#pragma unroll
          for (int k = 0; k < 6; ++k) {
            float akp = A[k][pi], akq = A[k][qi];
            A[k][pi] = c * akp - s * akq;
            A[k][qi] = s * akp + c * akq;
          }
#pragma unroll
          for (int k = 0; k < 6; ++k) {
            float apk = A[pi][k], aqk = A[qi][k];
            A[pi][k] = c * apk - s * aqk;
            A[qi][k] = s * apk + c * aqk;
          }
#pragma unroll
          for (int k = 0; k < 6; ++k) {
            float vkp = V[k][pi], vkq = V[k][qi];
            V[k][pi] = c * vkp - s * vkq;
            V[k][qi] = s * vkp + c * vkq;
          }
        }
      }
    }
#pragma unroll
    for (int i = 0; i < 6; ++i) diag_s[t][i] = A[i][i];
#pragma unroll
    for (int i = 0; i < 6; ++i)
#pragma unroll
      for (int j = 0; j < 6; ++j) V_s[t][i * 6 + j] = V[i][j];
    for (int i = 0; i < 6; ++i) idx_s[t][i] = i;
    for (int a = 0; a < 5; ++a)
      for (int b = 0; b < 5 - a; ++b) {
        int i0 = idx_s[t][b], i1 = idx_s[t][b + 1];
        if (diag_s[t][i0] < diag_s[t][i1]) {
          idx_s[t][b] = i1; idx_s[t][b + 1] = i0;
        }
      }
    float* SMF = t ? SMFB : SMFA;
    for (int k = 0; k < 6; ++k) {
      int ik = idx_s[t][k];
      float lam = diag_s[t][ik];
      SMF[36 + k] = rsqrtf(fmaxf(lam, 1e-30f));
      for (int j = 0; j < 6; ++j) SMF[j * 6 + k] = V_s[t][j * 6 + ik];
    }
  }
}

// v_scale2 + pack3 fused (r9)
__global__ void v_scale_pack(const float* __restrict__ BtA, const float* __restrict__ SMFA,
                             const float* __restrict__ BtB, const float* __restrict__ SMFB,
                             float* __restrict__ V8A, float* __restrict__ V8B,
                             float* __restrict__ WA, float* __restrict__ WB,
                             float* __restrict__ SC, int sA, int sB) {
  __shared__ float WsA[36], rsA[6], WsB[36], rsB[6];
  if (threadIdx.x < 36) { WsA[threadIdx.x] = SMFA[threadIdx.x]; WsB[threadIdx.x] = SMFB[threadIdx.x]; }
  if (threadIdx.x < 6) { rsA[threadIdx.x] = SMFA[36 + threadIdx.x]; rsB[threadIdx.x] = SMFB[36 + threadIdx.x]; }
  __syncthreads();
  int n = blockIdx.x * 256 + threadIdx.x;
  float ba[6], bb[6];
#pragma unroll
  for (int j = 0; j < 6; ++j) { ba[j] = BtA[(size_t)n * 8 + j]; bb[j] = BtB[(size_t)n * 8 + j]; }
  float vals[6];
#pragma unroll
  for (int k = 0; k < 6; ++k) {
    float sa = 0.f, sb = 0.f;
#pragma unroll
    for (int j = 0; j < 6; ++j) { sa += ba[j] * WsA[j * 6 + k]; sb += bb[j] * WsB[j * 6 + k]; }
    sa *= rsA[k]; sb *= rsB[k];
    V8A[(size_t)n * 8 + k] = sa;
    V8B[(size_t)n * 8 + k] = sb;
    if (k < 3) {
      WA[(size_t)n * 4 + k] = sa;
      WB[(size_t)n * 4 + k] = sb;
      vals[k] = sa; vals[3 + k] = sb;
    }
  }
  V8A[(size_t)n * 8 + 6] = 0.f; V8A[(size_t)n * 8 + 7] = 0.f;
  V8B[(size_t)n * 8 + 6] = 0.f; V8B[(size_t)n * 8 + 7] = 0.f;
  WA[(size_t)n * 4 + 3] = 0.f;
  WB[(size_t)n * 4 + 3] = 0.f;
  float* tot = blk_sums(vals, 6);
  if (threadIdx.x == 0)
    for (int c = 0; c < 3; ++c) {
      atomicAdd(&SC[sA + c], tot[c]);
      atomicAdd(&SC[sB + c], tot[3 + c]);
    }
}

// after 3rd batch3 spmm: accum sigma0-2 + Uv0 scale + p0-W build
__global__ void b3post(const float* __restrict__ YA, const float* __restrict__ YB,
                       const float* __restrict__ ZZB, float* __restrict__ UvA,
                       float* __restrict__ UvB, float* __restrict__ WB,
                       float* __restrict__ SC, int zzA, int nyA, int zzB, int nyB,
                       int sWp) {
  if (blockIdx.x == 0 && threadIdx.x == 0) {
    float add = 0.f;
    for (int k = 0; k < 3; ++k) add += sqrtf(fabsf(SC[zzA + k] / SC[nyA + k]));
    for (int k = 0; k < 3; ++k) add += sqrtf(fabsf(SC[zzB + k] / SC[nyB + k]));
    SC[5] += add;
  }
  int n = blockIdx.x * 256 + threadIdx.x;
  UvA[n] = YA[(size_t)n * 4 + 2] * rsqrtf(SC[nyA + 2]);
  UvB[n] = YB[(size_t)n * 4 + 2] * rsqrtf(SC[nyB + 2]);
  float v = ZZB[(size_t)n * 4 + 2] * rsqrtf(SC[nyB + 2]);
  WB[(size_t)n * 4 + 0] = v;
  WB[(size_t)n * 4 + 1] = 0.f;
  WB[(size_t)n * 4 + 2] = 0.f;
  WB[(size_t)n * 4 + 3] = 0.f;
  float* tot = blk_sums(&v, 1);
  if (threadIdx.x == 0) atomicAdd(&SC[sWp], tot[0]);
}

// batched deflation builds (r5/r9 validated)
__global__ void buildAB(float* __restrict__ WA, int FCpad, int nt, int nu,
                        const float* __restrict__ V8A, int kcol,
                        const float* __restrict__ UvA, float* __restrict__ SC, int sWa,
                        float* __restrict__ WB, const float* __restrict__ V8B,
                        const float* __restrict__ UvB, int nd, int sWb, int Cidx,
                        const float* __restrict__ P4, float* __restrict__ Pv,
                        int pvmode, int prevdp, int prevny) {
  const int bid = blockIdx.x;
  const int n = (bid & 15) * 256 + threadIdx.x;
  if (bid < 16) {
    float bv = V8A[(size_t)n * 8 + kcol];
    float uv[3];
    for (int b = 0; b < 3; ++b) uv[b] = (b < nu) ? UvA[(size_t)b * N + n] : 0.f;
    float vals[8];
    for (int t = 0; t < FCpad; ++t) {
      float v = 0.f;
      if (t < nt) {
        v = bv;
        for (int b = 0; b < nu; ++b)
          if ((t >> b) & 1) v *= uv[b];
      }
      WA[(size_t)n * FCpad + t] = v;
      vals[t] = v;
    }
    float* tot = blk_sums(vals, nt);
    if (threadIdx.x == 0)
      for (int c = 0; c < nt; ++c) atomicAdd(&SC[sWa + c], tot[c]);
  } else {
    if (pvmode == 1) {
      Pv[n] = P4[(size_t)n * 4];
    } else if (pvmode >= 2) {
      float crs = rsqrtf(SC[prevny]);
      float s = P4[(size_t)n * 4];
      s -= SC[prevdp + 1] * crs * Pv[n];
      if (pvmode == 3) s -= SC[prevdp + 3] * crs * Pv[(size_t)N + n];
      Pv[(size_t)(pvmode - 1) * N + n] = s;
    }
    float v = V8B[(size_t)n * 8 + kcol];
    WB[(size_t)n * 4 + 0] = v;
    WB[(size_t)n * 4 + 1] = 0.f;
    WB[(size_t)n * 4 + 2] = 0.f;
    WB[(size_t)n * 4 + 3] = 0.f;
    float vals[4];
    vals[0] = v;
    for (int t = 0; t < 3; ++t) vals[1 + t] = (t < nd) ? UvB[(size_t)t * N + n] * v : 0.f;
    float* tot = blk_sums(vals, 1 + nd);
    if (threadIdx.x == 0) {
      atomicAdd(&SC[sWb], tot[0]);
      for (int t = 0; t < nd; ++t) atomicAdd(&SC[Cidx + t], tot[1 + t]);
    }
  }
}

// fused epilogue + 2nd build (r9 validated)
__global__ void epibuild(const float* __restrict__ YA, int FA, int nt, int nu,
                         const float* __restrict__ UvA, float* __restrict__ yvA, int nyA2,
                         float* __restrict__ WA, int sW2a,
                         const float* __restrict__ YB, const float* __restrict__ Pv,
                         const float* __restrict__ UvB, int nd, float* __restrict__ yvB,
                         int Cidx, int nyB2, int dp, float* __restrict__ WB, int sW2b,
                         float* __restrict__ SC) {
  const int bid = blockIdx.x;
  const int n = (bid & 15) * 256 + threadIdx.x;
  if (bid < 16) {
    float uv[3];
    for (int b = 0; b < 3; ++b) uv[b] = (b < nu) ? UvA[(size_t)b * N + n] : 0.f;
    float s = 0.f;
    for (int t = 0; t < nt; ++t) {
      float w = YA[(size_t)n * FA + t];
      int pc = 0;
      for (int b = 0; b < nu; ++b)
        if ((t >> b) & 1) { w *= uv[b]; ++pc; }
      s += (pc & 1) ? -w : w;
    }
    yvA[n] = s;
    float v = s * s;
    float* tot = blk_sums(&v, 1);
    if (threadIdx.x == 0) atomicAdd(&SC[nyA2], tot[0]);
    float vals[8];
    for (int t = 0; t < FA; ++t) {
      float v2 = 0.f;
      if (t < nt) {
        v2 = s;
        for (int b = 0; b < nu; ++b)
          if ((t >> b) & 1) v2 *= uv[b];
      }
      WA[(size_t)n * FA + t] = v2;
      vals[t] = v2;
    }
    float* tot2 = blk_sums(vals, nt);
    if (threadIdx.x == 0)
      for (int c = 0; c < nt; ++c) atomicAdd(&SC[sW2a + c], tot2[c]);
  } else {
    float y = YB[(size_t)n * 4];
    for (int t = 0; t < nd; ++t) y -= SC[Cidx + t] * Pv[(size_t)t * N + n];
    yvB[n] = y;
    float vals[7];
    vals[0] = y * y;
    for (int t = 0; t < 3; ++t) {
      vals[1 + 2 * t] = (t < nd) ? y * Pv[(size_t)t * N + n] : 0.f;
      vals[2 + 2 * t] = (t < nd) ? UvB[(size_t)t * N + n] * y : 0.f;
    }
    float* tot = blk_sums(vals, 1 + 2 * nd);
    if (threadIdx.x == 0) {
      atomicAdd(&SC[nyB2], tot[0]);
      for (int i = 0; i < 2 * nd; ++i) atomicAdd(&SC[dp + i], tot[1 + i]);
    }
    WB[(size_t)n * 4 + 0] = y;
    WB[(size_t)n * 4 + 1] = 0.f;
    WB[(size_t)n * 4 + 2] = 0.f;
    WB[(size_t)n * 4 + 3] = 0.f;
    float yy = y;
    float* tot2 = blk_sums(&yy, 1);
    if (threadIdx.x == 0) atomicAdd(&SC[sW2b], tot2[0]);
  }
}

// per-k post: accum + (dobuild) Uv scale + next-p W build + (dofin) finalize
__global__ void defpost(float* __restrict__ SC, int zzA2, int nt, int nyA2,
                        int zzB2, int nyB2, int dp, int nd,
                        const float* __restrict__ yvA, const float* __restrict__ yvB,
                        float* __restrict__ UvA, float* __restrict__ UvB, int k,
                        const float* __restrict__ ZZB, float* __restrict__ WB,
                        int sW3, int dobuild, int dofin, float* __restrict__ outp) {
  if (blockIdx.x == 0 && threadIdx.x == 0) {
    float vmv = 0.f;
    for (int t = 0; t < nt; ++t) {
      int pc = __popc(t);
      vmv += (pc & 1) ? -SC[zzA2 + t] : SC[zzA2 + t];
    }
    float add = sqrtf(fabsf(vmv / SC[nyA2]));
    float vb = SC[zzB2];
    for (int t = 0; t < nd; ++t) vb -= SC[dp + 2 * t] * SC[dp + 2 * t + 1];
    add += sqrtf(fabsf(vb / SC[nyB2]));
    SC[5] += add;
    if (dofin) {
      const float Ef = (float)EDG;
      float m1 = SC[0] / Ef, v1 = SC[1] / Ef - m1 * m1;
      float m2 = SC[2] / Ef, v2 = SC[3] / Ef - m2 * m2;
      outp[131072] = 0.01f * (v1 + v2) + 0.01f * SC[5];
      outp[393217] = SC[4] / (float)N;
    }
  }
  if (dobuild) {
    int n = blockIdx.x * 256 + threadIdx.x;
    UvA[(size_t)(k - 2) * N + n] = yvA[n] * rsqrtf(SC[nyA2]);
    UvB[(size_t)(k - 2) * N + n] = yvB[n] * rsqrtf(SC[nyB2]);
    float v = ZZB[(size_t)n * 4 + 0] * rsqrtf(SC[nyB2]);
    WB[(size_t)n * 4 + 0] = v;
    WB[(size_t)n * 4 + 1] = 0.f;
    WB[(size_t)n * 4 + 2] = 0.f;
    WB[(size_t)n * 4 + 3] = 0.f;
    float* tot = blk_sums(&v, 1);
    if (threadIdx.x == 0) atomicAdd(&SC[sW3], tot[0]);
  }
}

// ---------------------------------------------------------------------------
extern "C" void kernel_launch(void* const* d_in, const int* in_sizes, int n_in,
                              void* d_out, int out_size, void* d_ws, size_t ws_size,
                              hipStream_t stream) {
  const float* x      = (const float*)d_in[0];
  const int*   ei     = (const int*)  d_in[1];
  const float* gcn1_w = (const float*)d_in[2];
  const float* gcn1_b = (const float*)d_in[3];
  const float* gcn2_w = (const float*)d_in[4];
  const float* gcn2_b = (const float*)d_in[5];
  const float* p1w1   = (const float*)d_in[6];
  const float* p1b1   = (const float*)d_in[7];
  const float* p1w2   = (const float*)d_in[8];
  const float* p1b2   = (const float*)d_in[9];
  const float* p2w1   = (const float*)d_in[10];
  const float* p2b1   = (const float*)d_in[11];
  const float* p2w2   = (const float*)d_in[12];
  const float* p2b2   = (const float*)d_in[13];
  const float* omega1 = (const float*)d_in[14];
  const float* omega2 = (const float*)d_in[15];
  float* out = (float*)d_out;

  float* ws = (float*)d_ws;
  size_t o = 0;
  auto alloc = [&](size_t nf) { float* p = ws + o; o += nf; return p; };
  // ---- zeroed region (one memset): xw1 | h1 | Gd | cnt | deg1 | deg2 | SC ----
  float* xw1  = alloc((size_t)N * 64);
  float* h1   = alloc((size_t)N * 64);
  double* Gd  = (double*)(ws + o); o += 576;
  int* cnt    = (int*)(ws + o);    o += 2 * N;
  float* deg1 = alloc(N);
  float* deg2 = alloc(N);
  float* SC   = alloc(1024);
  const size_t zero_bytes = o * sizeof(float);
  // ---- rest ----
  float* x1   = alloc((size_t)N * 64);
  float* x1w  = alloc((size_t)N * 32);
  float* h2   = alloc((size_t)N * 16);
  float* xo   = alloc((size_t)N * 16);
  float* dis1 = alloc(N);
  float* dis2 = alloc(N);
  float* QA   = alloc((size_t)N * 8);
  float* QB   = alloc((size_t)N * 8);
  float* ZA   = alloc((size_t)N * 8);
  float* ZB   = alloc((size_t)N * 8);
  float* BtA  = alloc((size_t)N * 8);
  float* BtB  = alloc((size_t)N * 8);
  float* V8A  = alloc((size_t)N * 8);
  float* V8B  = alloc((size_t)N * 8);
  float* WA   = alloc((size_t)N * 8);
  float* WB   = alloc((size_t)N * 4);
  float* TA   = alloc((size_t)N * 8);
  float* TB   = alloc((size_t)N * 4);
  float* YA   = alloc((size_t)N * 8);
  float* YB   = alloc((size_t)N * 4);
  float* ZZA  = alloc((size_t)N * 8);
  float* ZZB  = alloc((size_t)N * 4);
  float* P4   = alloc((size_t)N * 4);
  float* yvA  = alloc(N);
  float* yvB  = alloc(N);
  float* UvA  = alloc((size_t)3 * N);
  float* UvB  = alloc((size_t)3 * N);
  float* Pv   = alloc((size_t)3 * N);
  float* SMFA = alloc(64);
  float* SMFB = alloc(64);
  int* rowptr = (int*)alloc(2 * (N + 1) + 2);
  int* cur    = (int*)alloc(2 * N);
  int* col_s  = (int*)alloc(EDG);
  int* perm_s = (int*)alloc(EDG);
  int* col_d  = (int*)alloc(EDG);
  int* perm_d = (int*)alloc(EDG);
  float* w1s  = alloc(EDG);
  float* w1d  = alloc(EDG);
  float* w2s  = alloc(EDG);
  float* w2d  = alloc(EDG);
  if (ws_size < o * sizeof(float)) return;

  const int* rp_s = rowptr;
  const int* rp_d = rowptr + (N + 1);

  int cs = 8;
  auto NS = [&]() { int s = cs; cs += 8; return s; };
  int gslot = 0;
  auto NG = [&]() { int g = gslot; gslot += 24; return g; };

  // ===================== init + CSR =====================
  hipMemsetAsync(ws, 0, zero_bytes, stream);
  hist_edges<<<512, 256, 0, stream>>>(ei, cnt);
  scan2x<<<2, 256, 0, stream>>>(cnt, rowptr, cur);
  scatter_edges<<<512, 256, 0, stream>>>(ei, cur, col_s, perm_s, col_d, perm_d);

  int omA = NS(), omB = NS();

  // ===================== layer 1 =====================
  gemm512k<<<dim3(256, 4), 256, 0, stream>>>(x, p1w1, gcn1_w, xw1, h1);
  edge_gate1c<<<1024, 256, 0, stream>>>(xw1, rp_s, col_s, perm_s, p1b1, p1w2, p1b2,
                                        out + 131073, w1s, deg1, SC);
  gatherdis_om<<<512, 256, 0, stream>>>(out + 131073, perm_d, w1d,
                                        deg1, dis1, omega1, omega2, SC, omA, omB);
  conv1f<<<1024, 256, 0, stream>>>(rp_d, col_d, w1d, h1, dis1, gcn1_b, x1);

  // ===================== layer 2 =====================
  gemm64<<<128, 256, 0, stream>>>(x1, p2w1, gcn2_w, x1w, h2);
  edge_gate2c<<<1024, 256, 0, stream>>>(x1w, rp_s, col_s, perm_s, p2b1, p2w2, p2b2,
                                        out + 262145, w2s, deg2, SC);
  gatherdis_om<<<512, 256, 0, stream>>>(out + 262145, perm_d, w2d,
                                        deg2, dis2, nullptr, nullptr, SC, 0, 0);
  conv2f<<<1024, 256, 0, stream>>>(rp_d, col_d, w2d, h2, dis2, gcn2_b, xo);
  softmax_calib<<<16, 256, 0, stream>>>(xo, out, out + 65536, SC);

  // ===================== batched SVD: one dispatch per power step ===========
  int g0a = NG(), g0b = NG(), g1a = NG(), g1b = NG(), g2a = NG(), g2b = NG();
  int g3a = NG(), g3b = NG(), g4a = NG(), g4b = NG(), g5a = NG(), g5b = NG();
  int c0a = NS(), c0b = NS(), c1a = NS(), c1b = NS(), c2a = NS(), c2b = NS();
  int c3a = NS(), c3b = NS(), c4a = NS(), c4b = NS(), c5a = NS(), c5b = NS();
  spmm8f<0, 6><<<512, 256, 0, stream>>>(rp_s, col_s, w1s, w2s, omega1, omega2,
                                        QA, QB, nullptr, nullptr, Gd + g0a, Gd + g0b,
                                        SC, omA, omB, c0a, c0b);
  spmm8f<1, 8><<<512, 256, 0, stream>>>(rp_d, col_d, w1d, w2d, QA, QB, ZA, ZB,
                                        Gd + g0a, Gd + g0b, Gd + g1a, Gd + g1b,
                                        SC, c0a, c0b, c1a, c1b);
  spmm8f<1, 8><<<512, 256, 0, stream>>>(rp_s, col_s, w1s, w2s, ZA, ZB, QA, QB,
                                        Gd + g1a, Gd + g1b, Gd + g2a, Gd + g2b,
                                        SC, c1a, c1b, c2a, c2b);
  spmm8f<1, 8><<<512, 256, 0, stream>>>(rp_d, col_d, w1d, w2d, QA, QB, ZA, ZB,
                                        Gd + g2a, Gd + g2b, Gd + g3a, Gd + g3b,
                                        SC, c2a, c2b, c3a, c3b);
  spmm8f<1, 8><<<512, 256, 0, stream>>>(rp_s, col_s, w1s, w2s, ZA, ZB, QA, QB,
                                        Gd + g3a, Gd + g3b, Gd + g4a, Gd + g4b,
                                        SC, c3a, c3b, c4a, c4b);
  spmm8f<1, 8><<<512, 256, 0, stream>>>(rp_d, col_d, w1d, w2d, QA, QB, BtA, BtB,
                                        Gd + g4a, Gd + g4b, Gd + g5a, Gd + g5b,
                                        SC, c4a, c4b, c5a, c5b);
  jacobi2<<<1, 64, 0, stream>>>(Gd + g5a, Gd + g5b, SMFA, SMFB);

  // ===================== batched batch3 =====================
  int sWa = NS(), sWb = NS();
  v_scale_pack<<<16, 256, 0, stream>>>(BtA, SMFA, BtB, SMFB, V8A, V8B, WA, WB,
                                       SC, sWa, sWb);
  int sTa = NS(), sTb = NS();
  spmm2<4, 4><<<1024, 256, 0, stream>>>(rp_d, col_d, w1d, w2d, WA, WB, TA, TB,
                                        SC, sWa, sWb, GEPS, sTa, -1, sTb, -1);
  int sYa = NS(), sYb = NS(), nyA = NS(), nyB = NS();
  spmm2<4, 4><<<1024, 256, 0, stream>>>(rp_s, col_s, w1s, w2s, TA, TB, YA, YB,
                                        SC, sTa, sTb, GEPS, sYa, nyA, sYb, nyB);
  int zzA = NS(), zzB = NS();
  spmm2<4, 4><<<1024, 256, 0, stream>>>(rp_d, col_d, w1d, w2d, YA, YB, ZZA, ZZB,
                                        SC, sYa, sYb, GEPS, -1, zzA, -1, zzB);
  int sWp = NS();
  b3post<<<16, 256, 0, stream>>>(YA, YB, ZZB, UvA, UvB, WB, SC, zzA, nyA, zzB, nyB, sWp);
  spmm<4, 0><<<1024, 256, 0, stream>>>(rp_s, col_s, w2s, WB, nullptr, P4, SC, sWp,
                                       GEPS, -1, -1);

  // ===================== batched deflation k=3,4,5 =====================
  int dp_prev = 0, ny_prev = 0;
  for (int k = 3; k <= 5; ++k) {
    const int nu = k - 2, nt = 1 << nu, nd = k - 2;
    const int FA = (k < 5) ? 4 : 8;
    int dWa = NS(), dWb = NS(), C = NS();
    int dTa = NS(), dTb = NS();
    int nyA2 = NS(), nyB2 = NS(), sW2a = NS(), sW2b = NS(), zzA2 = NS(), zzB2 = NS();
    int dp = NS(), sW3 = NS();
    const int pvmode = (k == 3) ? 1 : (k == 4 ? 2 : 3);
    buildAB<<<32, 256, 0, stream>>>(WA, FA, nt, nu, V8A, k, UvA, SC, dWa,
                                    WB, V8B, UvB, nd, dWb, C, P4, Pv,
                                    pvmode, dp_prev, ny_prev);
    if (FA == 4) {
      spmm2<4, 4><<<1024, 256, 0, stream>>>(rp_d, col_d, w1d, w2d, WA, WB, TA, TB,
                                            SC, dWa, dWb, GEPS, dTa, -1, dTb, -1);
      spmm2<4, 4><<<1024, 256, 0, stream>>>(rp_s, col_s, w1s, w2s, TA, TB, YA, YB,
                                            SC, dTa, dTb, GEPS, -1, -1, -1, -1);
    } else {
      spmm2<8, 4><<<1024, 256, 0, stream>>>(rp_d, col_d, w1d, w2d, WA, WB, TA, TB,
                                            SC, dWa, dWb, GEPS, dTa, -1, dTb, -1);
      spmm2<8, 4><<<1024, 256, 0, stream>>>(rp_s, col_s, w1s, w2s, TA, TB, YA, YB,
                                            SC, dTa, dTb, GEPS, -1, -1, -1, -1);
    }
    epibuild<<<32, 256, 0, stream>>>(YA, FA, nt, nu, UvA, yvA, nyA2, WA, sW2a,
                                     YB, Pv, UvB, nd, yvB, C, nyB2, dp, WB, sW2b, SC);
    if (FA == 4)
      spmm2<4, 4><<<1024, 256, 0, stream>>>(rp_d, col_d, w1d, w2d, WA, WB, ZZA, ZZB,
                                            SC, sW2a, sW2b, GEPS, -1, zzA2, -1, zzB2);
    else
      spmm2<8, 4><<<1024, 256, 0, stream>>>(rp_d, col_d, w1d, w2d, WA, WB, ZZA, ZZB,
                                            SC, sW2a, sW2b, GEPS, -1, zzA2, -1, zzB2);
    if (k < 5) {
      defpost<<<16, 256, 0, stream>>>(SC, zzA2, nt, nyA2, zzB2, nyB2, dp, nd,
                                      yvA, yvB, UvA, UvB, k, ZZB, WB, sW3, 1, 0, out);
      spmm<4, 0><<<1024, 256, 0, stream>>>(rp_s, col_s, w2s, WB, nullptr, P4, SC, sW3,
                                           GEPS, -1, -1);
    } else {
      defpost<<<1, 256, 0, stream>>>(SC, zzA2, nt, nyA2, zzB2, nyB2, dp, nd,
                                     yvA, yvB, UvA, UvB, k, ZZB, WB, sW3, 0, 1, out);
    }
    dp_prev = dp; ny_prev = nyB2;
  }
}

// Round 16
// 758.559 us; speedup vs baseline: 1.0822x; 1.0372x over previous
//
#include <hip/hip_runtime.h>
#include <cmath>

constexpr int N = 4096;
constexpr int EDG = 131072;
constexpr float GEPS = 1e-6f;

// ---------------------------------------------------------------------------
__device__ __forceinline__ float* blk_sums(float* vals, int cnt) {
  __shared__ float part[4][16];
  __shared__ float tot[16];
  const int lane = threadIdx.x & 63, wv = threadIdx.x >> 6;
  for (int c = 0; c < cnt; ++c) {
    float v = vals[c];
    for (int off = 32; off; off >>= 1) v += __shfl_down(v, off);
    if (lane == 0) part[wv][c] = v;
  }
  __syncthreads();
  if (threadIdx.x == 0)
    for (int c = 0; c < cnt; ++c)
      tot[c] = part[0][c] + part[1][c] + part[2][c] + part[3][c];
  __syncthreads();
  return tot;
}

// ---------------------------------------------------------------------------
// CSR build
__global__ void hist_edges(const int* __restrict__ ei, int* __restrict__ cnt) {
  int e = blockIdx.x * 256 + threadIdx.x;
  atomicAdd(&cnt[ei[e]], 1);
  atomicAdd(&cnt[N + ei[EDG + e]], 1);
}

__global__ __launch_bounds__(256) void scan2x(const int* __restrict__ cnt,
                                              int* __restrict__ rowptr,
                                              int* __restrict__ cur) {
  const int b = blockIdx.x;
  const int* c = cnt + b * N;
  int* rp = rowptr + b * (N + 1);
  int* cu = cur + b * N;
  __shared__ int part[256];
  const int t = threadIdx.x;
  int local[16], s = 0;
  const int base = t * 16;
  for (int i = 0; i < 16; ++i) { local[i] = s; s += c[base + i]; }
  part[t] = s;
  __syncthreads();
  if (t == 0) {
    int acc = 0;
    for (int i = 0; i < 256; ++i) { int v = part[i]; part[i] = acc; acc += v; }
  }
  __syncthreads();
  const int off = part[t];
  for (int i = 0; i < 16; ++i) { rp[base + i] = off + local[i]; cu[base + i] = off + local[i]; }
  if (t == 255) rp[N] = off + s;
}

__global__ void scatter_edges(const int* __restrict__ ei, int* __restrict__ cur,
                              int* __restrict__ col_s, int* __restrict__ perm_s,
                              int* __restrict__ col_d, int* __restrict__ perm_d) {
  int e = blockIdx.x * 256 + threadIdx.x;
  int s = ei[e], d = ei[EDG + e];
  int ps = atomicAdd(&cur[s], 1);
  col_s[ps] = d; perm_s[ps] = e;
  int pd = atomicAdd(&cur[N + d], 1);
  col_d[pd] = s; perm_d[pd] = e;
}

// gather edge weights into dst-CSR order + compute dis; optional omega colsums
__global__ void gatherdis_om(const float* __restrict__ s,
                             const int* __restrict__ perm_d,
                             float* __restrict__ wd_, const float* __restrict__ deg,
                             float* __restrict__ dis, const float* __restrict__ om1,
                             const float* __restrict__ om2, float* __restrict__ SC,
                             int omA, int omB) {
  int p = blockIdx.x * 256 + threadIdx.x;
  wd_[p] = s[perm_d[p]];
  if (p < N) dis[p] = rsqrtf(deg[p] + 1.0f);
  if (om1 && blockIdx.x < 16) {
    int n = p;  // < 4096
    float vals[12];
#pragma unroll
    for (int k = 0; k < 6; ++k) {
      vals[k] = om1[(size_t)n * 6 + k];
      vals[6 + k] = om2[(size_t)n * 6 + k];
    }
    float* tot = blk_sums(vals, 12);
    if (threadIdx.x == 0)
      for (int c = 0; c < 6; ++c) {
        atomicAdd(&SC[omA + c], tot[c]);
        atomicAdd(&SC[omB + c], tot[6 + c]);
      }
  }
}

// ---------------------------------------------------------------------------
// Split-K fused layer-1 GEMM (r13 validated: split-K 4)
__global__ __launch_bounds__(256) void gemm512k(const float* __restrict__ A,
                                                const float* __restrict__ W1,
                                                const float* __restrict__ W2,
                                                float* __restrict__ O1,
                                                float* __restrict__ O2) {
  __shared__ float As[16][33];
  __shared__ float Ws[32][128];
  const int t = threadIdx.x;
  const int rt = t >> 4;
  const int ct = t & 15;
  const int r0 = blockIdx.x * 16;
  const int kh = blockIdx.y * 128;
  float acc[8];
#pragma unroll
  for (int j = 0; j < 8; ++j) acc[j] = 0.f;
  for (int kc = 0; kc < 128; kc += 32) {
    const int kb = kh + kc;
    __syncthreads();
    for (int i = t; i < 512; i += 256) {
      int rr = i >> 5, kk = i & 31;
      As[rr][kk] = A[(size_t)(r0 + rr) * 512 + kb + kk];
    }
    for (int i = t; i < 1024; i += 256) {
      int row = i >> 5, c4 = i & 31;
      float4 v;
      if (c4 < 16) v = *(const float4*)&W1[(size_t)(kb + row) * 64 + c4 * 4];
      else         v = *(const float4*)&W2[(size_t)(kb + row) * 64 + (c4 - 16) * 4];
      *(float4*)&Ws[row][c4 * 4] = v;
    }
    __syncthreads();
#pragma unroll
    for (int kk = 0; kk < 32; ++kk) {
      float a = As[rt][kk];
      float4 b0 = *(const float4*)&Ws[kk][ct * 4];
      float4 b1 = *(const float4*)&Ws[kk][64 + ct * 4];
      acc[0] += a * b0.x; acc[1] += a * b0.y;
      acc[2] += a * b0.z; acc[3] += a * b0.w;
      acc[4] += a * b1.x; acc[5] += a * b1.y;
      acc[6] += a * b1.z; acc[7] += a * b1.w;
    }
  }
  const int r = r0 + rt;
#pragma unroll
  for (int j = 0; j < 4; ++j) {
    atomicAdd(&O1[(size_t)r * 64 + ct * 4 + j], acc[j]);
    atomicAdd(&O2[(size_t)r * 64 + ct * 4 + j], acc[4 + j]);
  }
}

// Fused layer-2 GEMM (validated)
__global__ __launch_bounds__(256) void gemm64(const float* __restrict__ A,
                                              const float* __restrict__ W1,
                                              const float* __restrict__ W2,
                                              float* __restrict__ O1,
                                              float* __restrict__ O2) {
  __shared__ float As[32][65];
  __shared__ float Ws[64][48];
  const int t = threadIdx.x;
  const int r = t >> 3;
  const int cg = t & 7;
  const int r0 = blockIdx.x * 32;
  for (int idx = t; idx < 32 * 64; idx += 256)
    As[idx >> 6][idx & 63] = A[(size_t)(r0 + (idx >> 6)) * 64 + (idx & 63)];
  for (int idx = t; idx < 64 * 48; idx += 256) {
    int kk = idx / 48, c = idx % 48;
    Ws[kk][c] = (c < 32) ? W1[kk * 32 + c] : W2[kk * 16 + c - 32];
  }
  __syncthreads();
  float acc[6] = {0.f, 0.f, 0.f, 0.f, 0.f, 0.f};
  for (int k = 0; k < 64; ++k) {
    float a = As[r][k];
#pragma unroll
    for (int j = 0; j < 6; ++j) acc[j] += a * Ws[k][cg + 8 * j];
  }
  int n = r0 + r;
#pragma unroll
  for (int j = 0; j < 6; ++j) {
    int c = cg + 8 * j;
    if (c < 32) O1[(size_t)n * 32 + c] = acc[j];
    else O2[(size_t)n * 16 + c - 32] = acc[j];
  }
}

// ---------------------------------------------------------------------------
// edge gate 1 (r16: unroll-4 — 16 dest gathers in flight)
__global__ void edge_gate1c(const float* __restrict__ xw, const int* __restrict__ rp,
                            const int* __restrict__ cl, const int* __restrict__ perm,
                            const float* __restrict__ b1, const float* __restrict__ w2,
                            const float* __restrict__ b2, float* __restrict__ s_out,
                            float* __restrict__ wcs, float* __restrict__ deg,
                            float* __restrict__ SCs) {
  const int lane = threadIdx.x & 63;
  const int wave = threadIdx.x >> 6;
  const int u = lane >> 4;
  const int q = lane & 15;
  const float4 b1q = ((const float4*)b1)[q];
  const float4 w2q = ((const float4*)w2)[q];
  const float b2s = b2[0];
  const float4* xw4 = (const float4*)xw;
  const int r = blockIdx.x * 4 + wave;
  const float4 xsr = xw4[(size_t)r * 16 + q];
  const int e0 = rp[r], e1 = rp[r + 1];
  float lsum = 0.f, lssq = 0.f;
  int e = e0 + u;
  for (; e + 12 < e1; e += 16) {
    int d0 = cl[e], d1 = cl[e + 4], d2 = cl[e + 8], d3 = cl[e + 12];
    float4 xd0 = xw4[(size_t)d0 * 16 + q];
    float4 xd1 = xw4[(size_t)d1 * 16 + q];
    float4 xd2 = xw4[(size_t)d2 * 16 + q];
    float4 xd3 = xw4[(size_t)d3 * 16 + q];
    float g0 = fmaxf(xsr.x - xd0.x + b1q.x, 0.f) * w2q.x
             + fmaxf(xsr.y - xd0.y + b1q.y, 0.f) * w2q.y
             + fmaxf(xsr.z - xd0.z + b1q.z, 0.f) * w2q.z
             + fmaxf(xsr.w - xd0.w + b1q.w, 0.f) * w2q.w;
    float g1 = fmaxf(xsr.x - xd1.x + b1q.x, 0.f) * w2q.x
             + fmaxf(xsr.y - xd1.y + b1q.y, 0.f) * w2q.y
             + fmaxf(xsr.z - xd1.z + b1q.z, 0.f) * w2q.z
             + fmaxf(xsr.w - xd1.w + b1q.w, 0.f) * w2q.w;
    float g2 = fmaxf(xsr.x - xd2.x + b1q.x, 0.f) * w2q.x
             + fmaxf(xsr.y - xd2.y + b1q.y, 0.f) * w2q.y
             + fmaxf(xsr.z - xd2.z + b1q.z, 0.f) * w2q.z
             + fmaxf(xsr.w - xd2.w + b1q.w, 0.f) * w2q.w;
    float g3 = fmaxf(xsr.x - xd3.x + b1q.x, 0.f) * w2q.x
             + fmaxf(xsr.y - xd3.y + b1q.y, 0.f) * w2q.y
             + fmaxf(xsr.z - xd3.z + b1q.z, 0.f) * w2q.z
             + fmaxf(xsr.w - xd3.w + b1q.w, 0.f) * w2q.w;
#pragma unroll
    for (int off = 1; off < 16; off <<= 1) {
      g0 += __shfl_xor(g0, off);
      g1 += __shfl_xor(g1, off);
      g2 += __shfl_xor(g2, off);
      g3 += __shfl_xor(g3, off);
    }
    if (q == 0) {
      float a0 = g0 + b2s; a0 *= a0;
      float a1 = g1 + b2s; a1 *= a1;
      float a2 = g2 + b2s; a2 *= a2;
      float a3 = g3 + b2s; a3 *= a3;
      float s0 = 1.f / (1.f + __expf(-a0));
      float s1 = 1.f / (1.f + __expf(-a1));
      float s2 = 1.f / (1.f + __expf(-a2));
      float s3 = 1.f / (1.f + __expf(-a3));
      s_out[perm[e]] = s0;      wcs[e] = s0;
      s_out[perm[e + 4]] = s1;  wcs[e + 4] = s1;
      s_out[perm[e + 8]] = s2;  wcs[e + 8] = s2;
      s_out[perm[e + 12]] = s3; wcs[e + 12] = s3;
      atomicAdd(&deg[d0], s0);
      atomicAdd(&deg[d1], s1);
      atomicAdd(&deg[d2], s2);
      atomicAdd(&deg[d3], s3);
      lsum += (s0 + s1) + (s2 + s3);
      lssq += (s0 * s0 + s1 * s1) + (s2 * s2 + s3 * s3);
    }
  }
  for (; e < e1; e += 4) {
    int d = cl[e];
    float4 xd = xw4[(size_t)d * 16 + q];
    float g = fmaxf(xsr.x - xd.x + b1q.x, 0.f) * w2q.x
            + fmaxf(xsr.y - xd.y + b1q.y, 0.f) * w2q.y
            + fmaxf(xsr.z - xd.z + b1q.z, 0.f) * w2q.z
            + fmaxf(xsr.w - xd.w + b1q.w, 0.f) * w2q.w;
#pragma unroll
    for (int off = 1; off < 16; off <<= 1) g += __shfl_xor(g, off);
    if (q == 0) {
      float a = g + b2s; a *= a;
      float sv = 1.f / (1.f + __expf(-a));
      s_out[perm[e]] = sv; wcs[e] = sv;
      atomicAdd(&deg[d], sv);
      lsum += sv; lssq += sv * sv;
    }
  }
  float* tot = blk_sums(&lsum, 1);
  float* tot2 = blk_sums(&lssq, 1);
  if (threadIdx.x == 0) {
    atomicAdd(&SCs[0], tot[0]);
    atomicAdd(&SCs[1], tot2[0]);
  }
}

// edge gate 2 (r16: unroll-4)
__global__ void edge_gate2c(const float* __restrict__ xw, const int* __restrict__ rp,
                            const int* __restrict__ cl, const int* __restrict__ perm,
                            const float* __restrict__ b1, const float* __restrict__ w2,
                            const float* __restrict__ b2, float* __restrict__ s_out,
                            float* __restrict__ wcs, float* __restrict__ deg,
                            float* __restrict__ SCs) {
  const int lane = threadIdx.x & 63;
  const int wave = threadIdx.x >> 6;
  const int u = lane >> 3;
  const int q = lane & 7;
  const float4 b1q = ((const float4*)b1)[q];
  const float4 w2q = ((const float4*)w2)[q];
  const float b2s = b2[0];
  const float4* xw4 = (const float4*)xw;
  const int r = blockIdx.x * 4 + wave;
  const float4 xsr = xw4[(size_t)r * 8 + q];
  const int e0 = rp[r], e1 = rp[r + 1];
  float lsum = 0.f, lssq = 0.f;
  int e = e0 + u;
  for (; e + 24 < e1; e += 32) {
    int d0 = cl[e], d1 = cl[e + 8], d2 = cl[e + 16], d3 = cl[e + 24];
    float4 xd0 = xw4[(size_t)d0 * 8 + q];
    float4 xd1 = xw4[(size_t)d1 * 8 + q];
    float4 xd2 = xw4[(size_t)d2 * 8 + q];
    float4 xd3 = xw4[(size_t)d3 * 8 + q];
    float g0 = fmaxf(xsr.x - xd0.x + b1q.x, 0.f) * w2q.x
             + fmaxf(xsr.y - xd0.y + b1q.y, 0.f) * w2q.y
             + fmaxf(xsr.z - xd0.z + b1q.z, 0.f) * w2q.z
             + fmaxf(xsr.w - xd0.w + b1q.w, 0.f) * w2q.w;
    float g1 = fmaxf(xsr.x - xd1.x + b1q.x, 0.f) * w2q.x
             + fmaxf(xsr.y - xd1.y + b1q.y, 0.f) * w2q.y
             + fmaxf(xsr.z - xd1.z + b1q.z, 0.f) * w2q.z
             + fmaxf(xsr.w - xd1.w + b1q.w, 0.f) * w2q.w;
    float g2 = fmaxf(xsr.x - xd2.x + b1q.x, 0.f) * w2q.x
             + fmaxf(xsr.y - xd2.y + b1q.y, 0.f) * w2q.y
             + fmaxf(xsr.z - xd2.z + b1q.z, 0.f) * w2q.z
             + fmaxf(xsr.w - xd2.w + b1q.w, 0.f) * w2q.w;
    float g3 = fmaxf(xsr.x - xd3.x + b1q.x, 0.f) * w2q.x
             + fmaxf(xsr.y - xd3.y + b1q.y, 0.f) * w2q.y
             + fmaxf(xsr.z - xd3.z + b1q.z, 0.f) * w2q.z
             + fmaxf(xsr.w - xd3.w + b1q.w, 0.f) * w2q.w;
#pragma unroll
    for (int off = 1; off < 8; off <<= 1) {
      g0 += __shfl_xor(g0, off);
      g1 += __shfl_xor(g1, off);
      g2 += __shfl_xor(g2, off);
      g3 += __shfl_xor(g3, off);
    }
    if (q == 0) {
      float a0 = g0 + b2s; a0 *= a0;
      float a1 = g1 + b2s; a1 *= a1;
      float a2 = g2 + b2s; a2 *= a2;
      float a3 = g3 + b2s; a3 *= a3;
      float s0 = 1.f / (1.f + __expf(-a0));
      float s1 = 1.f / (1.f + __expf(-a1));
      float s2 = 1.f / (1.f + __expf(-a2));
      float s3 = 1.f / (1.f + __expf(-a3));
      s_out[perm[e]] = s0;      wcs[e] = s0;
      s_out[perm[e + 8]] = s1;  wcs[e + 8] = s1;
      s_out[perm[e + 16]] = s2; wcs[e + 16] = s2;
      s_out[perm[e + 24]] = s3; wcs[e + 24] = s3;
      atomicAdd(&deg[d0], s0);
      atomicAdd(&deg[d1], s1);
      atomicAdd(&deg[d2], s2);
      atomicAdd(&deg[d3], s3);
      lsum += (s0 + s1) + (s2 + s3);
      lssq += (s0 * s0 + s1 * s1) + (s2 * s2 + s3 * s3);
    }
  }
  for (; e < e1; e += 8) {
    int d = cl[e];
    float4 xd = xw4[(size_t)d * 8 + q];
    float g = fmaxf(xsr.x - xd.x + b1q.x, 0.f) * w2q.x
            + fmaxf(xsr.y - xd.y + b1q.y, 0.f) * w2q.y
            + fmaxf(xsr.z - xd.z + b1q.z, 0.f) * w2q.z
            + fmaxf(xsr.w - xd.w + b1q.w, 0.f) * w2q.w;
#pragma unroll
    for (int off = 1; off < 8; off <<= 1) g += __shfl_xor(g, off);
    if (q == 0) {
      float a = g + b2s; a *= a;
      float sv = 1.f / (1.f + __expf(-a));
      s_out[perm[e]] = sv; wcs[e] = sv;
      atomicAdd(&deg[d], sv);
      lsum += sv; lssq += sv * sv;
    }
  }
  float* tot = blk_sums(&lsum, 1);
  float* tot2 = blk_sums(&lssq, 1);
  if (threadIdx.x == 0) {
    atomicAdd(&SCs[2], tot[0]);
    atomicAdd(&SCs[3], tot2[0]);
  }
}

// conv1 fused (r11 validated)
__global__ void conv1f(const int* __restrict__ rp, const int* __restrict__ cl,
                       const float* __restrict__ w, const float* __restrict__ h1,
                       const float* __restrict__ dis, const float* __restrict__ bias,
                       float* __restrict__ x1) {
  const int lane = threadIdx.x & 63, wv = threadIdx.x >> 6;
  const int es = lane >> 4;
  const int q = lane & 15;
  const int r = blockIdx.x * 4 + wv;
  const int e0 = rp[r], e1 = rp[r + 1];
  const float4* h14 = (const float4*)h1;
  float ax = 0.f, ay = 0.f, az = 0.f, aw = 0.f;
  int e = e0 + es;
  for (; e + 4 < e1; e += 8) {
    int c0 = cl[e], c1 = cl[e + 4];
    float w0 = w[e] * dis[c0], w1_ = w[e + 4] * dis[c1];
    float4 h0 = h14[(size_t)c0 * 16 + q];
    float4 h1v = h14[(size_t)c1 * 16 + q];
    ax += w0 * h0.x + w1_ * h1v.x;
    ay += w0 * h0.y + w1_ * h1v.y;
    az += w0 * h0.z + w1_ * h1v.z;
    aw += w0 * h0.w + w1_ * h1v.w;
  }
  for (; e < e1; e += 4) {
    int c = cl[e];
    float wx = w[e] * dis[c];
    float4 hv = h14[(size_t)c * 16 + q];
    ax += wx * hv.x; ay += wx * hv.y; az += wx * hv.z; aw += wx * hv.w;
  }
  ax += __shfl_xor(ax, 16); ax += __shfl_xor(ax, 32);
  ay += __shfl_xor(ay, 16); ay += __shfl_xor(ay, 32);
  az += __shfl_xor(az, 16); az += __shfl_xor(az, 32);
  aw += __shfl_xor(aw, 16); aw += __shfl_xor(aw, 32);
  if (es == 0) {
    float d = dis[r];
    float4 hh = h14[(size_t)r * 16 + q];
    float4 bq = ((const float4*)bias)[q];
    float4 o;
    o.x = fmaxf(d * (ax + d * hh.x) + bq.x, 0.f);
    o.y = fmaxf(d * (ay + d * hh.y) + bq.y, 0.f);
    o.z = fmaxf(d * (az + d * hh.z) + bq.z, 0.f);
    o.w = fmaxf(d * (aw + d * hh.w) + bq.w, 0.f);
    ((float4*)x1)[(size_t)r * 16 + q] = o;
  }
}

// conv2 fused -> logits (r11 validated)
__global__ void conv2f(const int* __restrict__ rp, const int* __restrict__ cl,
                       const float* __restrict__ w, const float* __restrict__ h2,
                       const float* __restrict__ dis, const float* __restrict__ bias,
                       float* __restrict__ xo) {
  const int lane = threadIdx.x & 63, wv = threadIdx.x >> 6;
  const int es = lane >> 2;
  const int q = lane & 3;
  const int r = blockIdx.x * 4 + wv;
  const int e0 = rp[r], e1 = rp[r + 1];
  const float4* h24 = (const float4*)h2;
  float ax = 0.f, ay = 0.f, az = 0.f, aw = 0.f;
  for (int e = e0 + es; e < e1; e += 16) {
    int c = cl[e];
    float wx = w[e] * dis[c];
    float4 hv = h24[(size_t)c * 4 + q];
    ax += wx * hv.x; ay += wx * hv.y; az += wx * hv.z; aw += wx * hv.w;
  }
#pragma unroll
  for (int off = 4; off < 64; off <<= 1) {
    ax += __shfl_xor(ax, off);
    ay += __shfl_xor(ay, off);
    az += __shfl_xor(az, off);
    aw += __shfl_xor(aw, off);
  }
  if (es == 0) {
    float d = dis[r];
    float4 hh = h24[(size_t)r * 4 + q];
    float4 bq = ((const float4*)bias)[q];
    float4 o;
    o.x = d * (ax + d * hh.x) + bq.x;
    o.y = d * (ay + d * hh.y) + bq.y;
    o.z = d * (az + d * hh.z) + bq.z;
    o.w = d * (aw + d * hh.w) + bq.w;
    ((float4*)xo)[(size_t)r * 4 + q] = o;
  }
}

// softmax + calib from logits (validated r3/r5)
__global__ void softmax_calib(const float* __restrict__ xo, float* __restrict__ ls,
                              float* __restrict__ sm, float* __restrict__ SC) {
  const int t = threadIdx.x;
  const int r = blockIdx.x * 256 + t;
  float v[16];
  float mx = -3.0e38f, mx2 = -3.0e38f;
#pragma unroll
  for (int c = 0; c < 16; ++c) {
    v[c] = xo[(size_t)r * 16 + c];
    if (v[c] > mx) { mx2 = mx; mx = v[c]; }
    else if (v[c] > mx2) mx2 = v[c];
  }
  float se = 0.f;
#pragma unroll
  for (int c = 0; c < 16; ++c) se += expf(v[c] - mx);
  const float lse = mx + logf(se);
#pragma unroll
  for (int c = 0; c < 16; ++c) {
    float z = v[c] - lse;
    ls[(size_t)r * 16 + c] = z;
    sm[(size_t)r * 16 + c] = expf(z);
  }
  float calib = mx2 - mx;
  float* tot = blk_sums(&calib, 1);
  if (t == 0) atomicAdd(&SC[4], tot[0]);
}

// ---------------------------------------------------------------------------
// Fused SVD power step (r8/r9) — r16: dual-accumulator edge loop.
template<int NORM, int SX>
__global__ __launch_bounds__(256) void spmm8f(
    const int* __restrict__ rp, const int* __restrict__ cl,
    const float* __restrict__ wA, const float* __restrict__ wB,
    const float* __restrict__ XA, const float* __restrict__ XB,
    float* __restrict__ OA, float* __restrict__ OB,
    const double* __restrict__ GpA, const double* __restrict__ GpB,
    double* __restrict__ GnA, double* __restrict__ GnB,
    float* __restrict__ SC, int cspA, int cspB, int csoA, int csoB) {
  __shared__ float Rinv[2][36];
  __shared__ float csn[2][8];
  __shared__ float bs[2][8];
  __shared__ float gpart[8][21];
  const int t = threadIdx.x;
  if (NORM) {
    if (t < 2) {
      const double* G = t ? GpB : GpA;
      const float* csp = SC + (t ? cspB : cspA);
      float Gf[6][6];
      int p = 0;
      for (int i = 0; i < 6; ++i)
        for (int j = i; j < 6; ++j) { float gv = (float)G[p]; Gf[i][j] = gv; Gf[j][i] = gv; ++p; }
      float Rm[6][6];
      for (int i = 0; i < 6; ++i) for (int j = 0; j < 6; ++j) Rm[i][j] = 0.f;
      for (int j = 0; j < 6; ++j) {
        float s = Gf[j][j];
        for (int k = 0; k < j; ++k) s -= Rm[k][j] * Rm[k][j];
        float dj = sqrtf(fmaxf(s, 1e-30f));
        Rm[j][j] = dj;
        for (int i = j + 1; i < 6; ++i) {
          float v = Gf[j][i];
          for (int k = 0; k < j; ++k) v -= Rm[k][j] * Rm[k][i];
          Rm[j][i] = v / dj;
        }
      }
      float Ri[6][6];
      for (int j = 0; j < 6; ++j) {
        Ri[j][j] = 1.f / Rm[j][j];
        for (int i = j - 1; i >= 0; --i) {
          float s = 0.f;
          for (int k = i + 1; k <= j; ++k) s += Rm[i][k] * Ri[k][j];
          Ri[i][j] = -s / Rm[i][i];
        }
      }
      for (int i = 0; i < 6; ++i)
        for (int j = 0; j < 6; ++j)
          Rinv[t][i * 6 + j] = (j >= i) ? Ri[i][j] : 0.f;
      for (int f = 0; f < 8; ++f) {
        float s = 0.f;
        if (f < 6)
          for (int j = 0; j <= f; ++j) s += csp[j] * Ri[j][f];
        csn[t][f] = s;
      }
    }
  } else {
    if (t < 16) {
      int h = t >> 3, f = t & 7;
      csn[h][f] = (f < 6) ? SC[(h ? cspB : cspA) + f] : 0.f;
    }
  }
  if (t < 16) bs[t >> 3][t & 7] = 0.f;
  __syncthreads();
  const int lane = t & 63, wv = t >> 6;
  const int half = lane >> 5, la = lane & 31;
  const int f = la & 7, es = la >> 3;
  const float* w = half ? wB : wA;
  const float* X = half ? XB : XA;
  float* O = half ? OB : OA;
  const float* Ri = Rinv[half];
  const float epsf = csn[half][f] * GEPS;
  float gp[6];
#pragma unroll
  for (int j = 0; j < 6; ++j) gp[j] = 0.f;
  for (int rr = 0; rr < 2; ++rr) {
    const int r = blockIdx.x * 8 + wv * 2 + rr;
    const int e0 = rp[r], e1 = rp[r + 1];
    float acc0 = 0.f, acc1 = 0.f;
    if (f < 6) {
      int e = e0 + es;
      for (; e + 4 < e1; e += 8) {
        int c0 = cl[e], c1 = cl[e + 4];
        const float* xr0 = X + (size_t)c0 * SX;
        const float* xr1 = X + (size_t)c1 * SX;
        float xn0, xn1;
        if (NORM) {
          xn0 = 0.f; xn1 = 0.f;
          for (int j = 0; j <= f; ++j) {
            xn0 += xr0[j] * Ri[j * 6 + f];
            xn1 += xr1[j] * Ri[j * 6 + f];
          }
        } else {
          xn0 = xr0[f];
          xn1 = xr1[f];
        }
        acc0 += w[e] * xn0;
        acc1 += w[e + 4] * xn1;
      }
      for (; e < e1; e += 4) {
        int c = cl[e];
        const float* xr = X + (size_t)c * SX;
        float xn;
        if (NORM) {
          xn = 0.f;
          for (int j = 0; j <= f; ++j) xn += xr[j] * Ri[j * 6 + f];
        } else {
          xn = xr[f];
        }
        acc0 += w[e] * xn;
      }
    }
    float acc = acc0 + acc1;
    acc += __shfl_xor(acc, 8);
    acc += __shfl_xor(acc, 16);
    float o = acc + epsf;
    float ov[6];
#pragma unroll
    for (int j = 0; j < 6; ++j) ov[j] = __shfl(o, half * 32 + j);
    if (es == 0) {
      O[((size_t)r << 3) + f] = o;
      if (f < 6) {
        atomicAdd(&bs[half][f], o);
#pragma unroll
        for (int j = 0; j < 6; ++j)
          if (j >= f) gp[j - f] += o * ov[j];
      }
    }
  }
  if (es == 0 && f < 6) {
    int p0 = f * 6 - (f * (f - 1)) / 2;
    for (int j = 0; j < 6 - f; ++j) gpart[wv * 2 + half][p0 + j] = gp[j];
  }
  __syncthreads();
  if (t < 42) {
    int h = t / 21, p = t % 21;
    float s = gpart[h][p] + gpart[2 + h][p] + gpart[4 + h][p] + gpart[6 + h][p];
    atomicAdd(&(h ? GnB : GnA)[p], (double)s);
  }
  if (t < 16) {
    int h = t >> 3, ff = t & 7;
    if (ff < 6) atomicAdd(&SC[(h ? csoB : csoA) + ff], bs[h][ff]);
  }
}

// ---------------------------------------------------------------------------
// single-graph SpMM (p-passes) — r16: dual accumulators
template<int F, int DIS>
__global__ __launch_bounds__(256) void spmm(const int* __restrict__ rowptr,
                                            const int* __restrict__ col,
                                            const float* __restrict__ w,
                                            const float* __restrict__ X,
                                            const float* __restrict__ dis,
                                            float* __restrict__ OUT,
                                            float* __restrict__ SC, int cs_idx,
                                            float eps, int osum, int ossq) {
  constexpr int ES = 64 / F;
  const int lane = threadIdx.x & 63;
  const int wv = threadIdx.x >> 6;
  const int f = lane & (F - 1);
  const int es = lane / F;
  const int r = blockIdx.x * 4 + wv;
  const int e0 = rowptr[r], e1 = rowptr[r + 1];
  float a0 = 0.f, a1 = 0.f;
  int e = e0 + es;
  for (; e + ES < e1; e += 2 * ES) {
    int c0 = col[e], c1 = col[e + ES];
    float w0 = w[e], w1_ = w[e + ES];
    if (DIS) { w0 *= dis[c0]; w1_ *= dis[c1]; }
    a0 += w0 * X[(size_t)c0 * F + f];
    a1 += w1_ * X[(size_t)c1 * F + f];
  }
  for (; e < e1; e += ES) {
    int c = col[e];
    float wx = w[e];
    if (DIS) wx *= dis[c];
    a0 += wx * X[(size_t)c * F + f];
  }
  float acc = a0 + a1;
#pragma unroll
  for (int off = F; off < 64; off <<= 1) acc += __shfl_xor(acc, off);
  float o = acc + ((cs_idx >= 0) ? eps * SC[cs_idx + f] : 0.f);
  if (es == 0) OUT[(size_t)r * F + f] = o;
  if (osum >= 0 || ossq >= 0) {
    __shared__ float bs[8], bq[8];
    if (threadIdx.x < F) { bs[threadIdx.x] = 0.f; bq[threadIdx.x] = 0.f; }
    __syncthreads();
    if (es == 0) {
      if (osum >= 0) atomicAdd(&bs[f], o);
      if (ossq >= 0) atomicAdd(&bq[f], o * o);
    }
    __syncthreads();
    if (threadIdx.x < F) {
      if (osum >= 0) atomicAdd(&SC[osum + threadIdx.x], bs[threadIdx.x]);
      if (ossq >= 0) atomicAdd(&SC[ossq + threadIdx.x], bq[threadIdx.x]);
    }
  }
}

// Batched two-graph SpMM (r5 validated) — r16: dual accumulators
template<int FA, int FB>
__global__ __launch_bounds__(256) void spmm2(const int* __restrict__ rowptr,
                                             const int* __restrict__ col,
                                             const float* __restrict__ wA,
                                             const float* __restrict__ wB,
                                             const float* __restrict__ XA,
                                             const float* __restrict__ XB,
                                             float* __restrict__ OA,
                                             float* __restrict__ OB,
                                             float* __restrict__ SC,
                                             int csA, int csB, float eps,
                                             int osumA, int ossqA, int osumB, int ossqB) {
  const int lane = threadIdx.x & 63;
  const int wv = threadIdx.x >> 6;
  const int half = lane >> 5;
  const int la = lane & 31;
  const int F = half ? FB : FA;
  const int f = la & (F - 1);
  const int es = la / F;
  const int ES = 32 / F;
  const int r = blockIdx.x * 4 + wv;
  const int e0 = rowptr[r], e1 = rowptr[r + 1];
  const float* w = half ? wB : wA;
  const float* X = half ? XB : XA;
  float a0 = 0.f, a1 = 0.f;
  int e = e0 + es;
  for (; e + ES < e1; e += 2 * ES) {
    int c0 = col[e], c1 = col[e + ES];
    a0 += w[e] * X[(size_t)c0 * F + f];
    a1 += w[e + ES] * X[(size_t)c1 * F + f];
  }
  for (; e < e1; e += ES)
    a0 += w[e] * X[(size_t)col[e] * F + f];
  float acc = a0 + a1;
  for (int off = F; off < 32; off <<= 1) acc += __shfl_xor(acc, off);
  const int cs = half ? csB : csA;
  float o = acc + ((cs >= 0) ? eps * SC[cs + f] : 0.f);
  if (es == 0) {
    float* O = half ? OB : OA;
    O[(size_t)r * F + f] = o;
  }
  if (osumA >= 0 || ossqA >= 0 || osumB >= 0 || ossqB >= 0) {
    __shared__ float bs[2][8], bq[2][8];
    if (threadIdx.x < 16) { bs[threadIdx.x >> 3][threadIdx.x & 7] = 0.f;
                            bq[threadIdx.x >> 3][threadIdx.x & 7] = 0.f; }
    __syncthreads();
    const int osum = half ? osumB : osumA, ossq = half ? ossqB : ossqA;
    if (es == 0) {
      if (osum >= 0) atomicAdd(&bs[half][f], o);
      if (ossq >= 0) atomicAdd(&bq[half][f], o * o);
    }
    __syncthreads();
    if (threadIdx.x < 16) {
      int h = threadIdx.x >> 3, ff = threadIdx.x & 7;
      int os_ = h ? osumB : osumA, oq_ = h ? ossqB : ossqA;
      int Fh = h ? FB : FA;
      if (os_ >= 0 && ff < Fh) atomicAdd(&SC[os_ + ff], bs[h][ff]);
      if (oq_ >= 0 && ff < Fh) atomicAdd(&SC[oq_ + ff], bq[h][ff]);
    }
  }
}

// ---------------------------------------------------------------------------
// r15 validated: serial fp32 6x6 Jacobi, fully unrolled, launch_bounds(64,1).
__global__ __launch_bounds__(64, 1) void jacobi2(const double* __restrict__ GA,
                                                 const double* __restrict__ GB,
                                                 float* __restrict__ SMFA,
                                                 float* __restrict__ SMFB) {
  __shared__ float diag_s[2][6];
  __shared__ float V_s[2][36];
  __shared__ int idx_s[2][6];
  const int t = threadIdx.x;
  if (t < 2) {
    const double* G = t ? GB : GA;
    float A[6][6], V[6][6];
    {
      int p = 0;
#pragma unroll
      for (int i = 0; i < 6; ++i)
#pragma unroll
        for (int j = i; j < 6; ++j) {
          float gv = (float)G[p];
          A[i][j] = gv; A[j][i] = gv; ++p;
        }
    }
#pragma unroll
    for (int i = 0; i < 6; ++i)
#pragma unroll
      for (int j = 0; j < 6; ++j) V[i][j] = (i == j) ? 1.f : 0.f;
#pragma unroll
    for (int sweep = 0; sweep < 5; ++sweep) {
#pragma unroll
      for (int pi = 0; pi < 5; ++pi) {
#pragma unroll
        for (int qi = pi + 1; qi < 6; ++qi) {
          float apq = A[pi][qi];
          float app = A[pi][pi], aqq = A[qi][qi];
          float tau = (aqq - app) / (2.f * apq);
          float rt_ = sqrtf(1.f + tau * tau);
          float tt = (tau >= 0.f) ? 1.f / (tau + rt_) : 1.f / (tau - rt_);
          bool ok = fabsf(apq) > 1e-30f;
          float cc = rsqrtf(1.f + tt * tt);
          float c = ok ? cc : 1.f;
          float s = ok ? tt * cc : 0.f;
#pragma unroll
          for (int k = 0; k < 6; ++k) {
            float akp = A[k][pi], akq = A[k][qi];
            A[k][pi] = c * akp - s * akq;
            A[k][qi] = s * akp + c * akq;
          }
#pragma unroll
          for (int k = 0; k < 6; ++k) {
            float apk = A[pi][k], aqk = A[qi][k];
            A[pi][k] = c * apk - s * aqk;
            A[qi][k] = s * apk + c * aqk;
          }
#pragma unroll
          for (int k = 0; k < 6; ++k) {
            float vkp = V[k][pi], vkq = V[k][qi];
            V[k][pi] = c * vkp - s * vkq;
            V[k][qi] = s * vkp + c * vkq;
          }
        }
      }
    }
#pragma unroll
    for (int i = 0; i < 6; ++i) diag_s[t][i] = A[i][i];
#pragma unroll
    for (int i = 0; i < 6; ++i)
#pragma unroll
      for (int j = 0; j < 6; ++j) V_s[t][i * 6 + j] = V[i][j];
    for (int i = 0; i < 6; ++i) idx_s[t][i] = i;
    for (int a = 0; a < 5; ++a)
      for (int b = 0; b < 5 - a; ++b) {
        int i0 = idx_s[t][b], i1 = idx_s[t][b + 1];
        if (diag_s[t][i0] < diag_s[t][i1]) {
          idx_s[t][b] = i1; idx_s[t][b + 1] = i0;
        }
      }
    float* SMF = t ? SMFB : SMFA;
    for (int k = 0; k < 6; ++k) {
      int ik = idx_s[t][k];
      float lam = diag_s[t][ik];
      SMF[36 + k] = rsqrtf(fmaxf(lam, 1e-30f));
      for (int j = 0; j < 6; ++j) SMF[j * 6 + k] = V_s[t][j * 6 + ik];
    }
  }
}

// v_scale2 + pack3 fused (r9)
__global__ void v_scale_pack(const float* __restrict__ BtA, const float* __restrict__ SMFA,
                             const float* __restrict__ BtB, const float* __restrict__ SMFB,
                             float* __restrict__ V8A, float* __restrict__ V8B,
                             float* __restrict__ WA, float* __restrict__ WB,
                             float* __restrict__ SC, int sA, int sB) {
  __shared__ float WsA[36], rsA[6], WsB[36], rsB[6];
  if (threadIdx.x < 36) { WsA[threadIdx.x] = SMFA[threadIdx.x]; WsB[threadIdx.x] = SMFB[threadIdx.x]; }
  if (threadIdx.x < 6) { rsA[threadIdx.x] = SMFA[36 + threadIdx.x]; rsB[threadIdx.x] = SMFB[36 + threadIdx.x]; }
  __syncthreads();
  int n = blockIdx.x * 256 + threadIdx.x;
  float ba[6], bb[6];
#pragma unroll
  for (int j = 0; j < 6; ++j) { ba[j] = BtA[(size_t)n * 8 + j]; bb[j] = BtB[(size_t)n * 8 + j]; }
  float vals[6];
#pragma unroll
  for (int k = 0; k < 6; ++k) {
    float sa = 0.f, sb = 0.f;
#pragma unroll
    for (int j = 0; j < 6; ++j) { sa += ba[j] * WsA[j * 6 + k]; sb += bb[j] * WsB[j * 6 + k]; }
    sa *= rsA[k]; sb *= rsB[k];
    V8A[(size_t)n * 8 + k] = sa;
    V8B[(size_t)n * 8 + k] = sb;
    if (k < 3) {
      WA[(size_t)n * 4 + k] = sa;
      WB[(size_t)n * 4 + k] = sb;
      vals[k] = sa; vals[3 + k] = sb;
    }
  }
  V8A[(size_t)n * 8 + 6] = 0.f; V8A[(size_t)n * 8 + 7] = 0.f;
  V8B[(size_t)n * 8 + 6] = 0.f; V8B[(size_t)n * 8 + 7] = 0.f;
  WA[(size_t)n * 4 + 3] = 0.f;
  WB[(size_t)n * 4 + 3] = 0.f;
  float* tot = blk_sums(vals, 6);
  if (threadIdx.x == 0)
    for (int c = 0; c < 3; ++c) {
      atomicAdd(&SC[sA + c], tot[c]);
      atomicAdd(&SC[sB + c], tot[3 + c]);
    }
}

// after 3rd batch3 spmm: accum sigma0-2 + Uv0 scale + p0-W build
__global__ void b3post(const float* __restrict__ YA, const float* __restrict__ YB,
                       const float* __restrict__ ZZB, float* __restrict__ UvA,
                       float* __restrict__ UvB, float* __restrict__ WB,
                       float* __restrict__ SC, int zzA, int nyA, int zzB, int nyB,
                       int sWp) {
  if (blockIdx.x == 0 && threadIdx.x == 0) {
    float add = 0.f;
    for (int k = 0; k < 3; ++k) add += sqrtf(fabsf(SC[zzA + k] / SC[nyA + k]));
    for (int k = 0; k < 3; ++k) add += sqrtf(fabsf(SC[zzB + k] / SC[nyB + k]));
    SC[5] += add;
  }
  int n = blockIdx.x * 256 + threadIdx.x;
  UvA[n] = YA[(size_t)n * 4 + 2] * rsqrtf(SC[nyA + 2]);
  UvB[n] = YB[(size_t)n * 4 + 2] * rsqrtf(SC[nyB + 2]);
  float v = ZZB[(size_t)n * 4 + 2] * rsqrtf(SC[nyB + 2]);
  WB[(size_t)n * 4 + 0] = v;
  WB[(size_t)n * 4 + 1] = 0.f;
  WB[(size_t)n * 4 + 2] = 0.f;
  WB[(size_t)n * 4 + 3] = 0.f;
  float* tot = blk_sums(&v, 1);
  if (threadIdx.x == 0) atomicAdd(&SC[sWp], tot[0]);
}

// batched deflation builds (r5/r9 validated)
__global__ void buildAB(float* __restrict__ WA, int FCpad, int nt, int nu,
                        const float* __restrict__ V8A, int kcol,
                        const float* __restrict__ UvA, float* __restrict__ SC, int sWa,
                        float* __restrict__ WB, const float* __restrict__ V8B,
                        const float* __restrict__ UvB, int nd, int sWb, int Cidx,
                        const float* __restrict__ P4, float* __restrict__ Pv,
                        int pvmode, int prevdp, int prevny) {
  const int bid = blockIdx.x;
  const int n = (bid & 15) * 256 + threadIdx.x;
  if (bid < 16) {
    float bv = V8A[(size_t)n * 8 + kcol];
    float uv[3];
    for (int b = 0; b < 3; ++b) uv[b] = (b < nu) ? UvA[(size_t)b * N + n] : 0.f;
    float vals[8];
    for (int t = 0; t < FCpad; ++t) {
      float v = 0.f;
      if (t < nt) {
        v = bv;
        for (int b = 0; b < nu; ++b)
          if ((t >> b) & 1) v *= uv[b];
      }
      WA[(size_t)n * FCpad + t] = v;
      vals[t] = v;
    }
    float* tot = blk_sums(vals, nt);
    if (threadIdx.x == 0)
      for (int c = 0; c < nt; ++c) atomicAdd(&SC[sWa + c], tot[c]);
  } else {
    if (pvmode == 1) {
      Pv[n] = P4[(size_t)n * 4];
    } else if (pvmode >= 2) {
      float crs = rsqrtf(SC[prevny]);
      float s = P4[(size_t)n * 4];
      s -= SC[prevdp + 1] * crs * Pv[n];
      if (pvmode == 3) s -= SC[prevdp + 3] * crs * Pv[(size_t)N + n];
      Pv[(size_t)(pvmode - 1) * N + n] = s;
    }
    float v = V8B[(size_t)n * 8 + kcol];
    WB[(size_t)n * 4 + 0] = v;
    WB[(size_t)n * 4 + 1] = 0.f;
    WB[(size_t)n * 4 + 2] = 0.f;
    WB[(size_t)n * 4 + 3] = 0.f;
    float vals[4];
    vals[0] = v;
    for (int t = 0; t < 3; ++t) vals[1 + t] = (t < nd) ? UvB[(size_t)t * N + n] * v : 0.f;
    float* tot = blk_sums(vals, 1 + nd);
    if (threadIdx.x == 0) {
      atomicAdd(&SC[sWb], tot[0]);
      for (int t = 0; t < nd; ++t) atomicAdd(&SC[Cidx + t], tot[1 + t]);
    }
  }
}

// fused epilogue + 2nd build (r9 validated)
__global__ void epibuild(const float* __restrict__ YA, int FA, int nt, int nu,
                         const float* __restrict__ UvA, float* __restrict__ yvA, int nyA2,
                         float* __restrict__ WA, int sW2a,
                         const float* __restrict__ YB, const float* __restrict__ Pv,
                         const float* __restrict__ UvB, int nd, float* __restrict__ yvB,
                         int Cidx, int nyB2, int dp, float* __restrict__ WB, int sW2b,
                         float* __restrict__ SC) {
  const int bid = blockIdx.x;
  const int n = (bid & 15) * 256 + threadIdx.x;
  if (bid < 16) {
    float uv[3];
    for (int b = 0; b < 3; ++b) uv[b] = (b < nu) ? UvA[(size_t)b * N + n] : 0.f;
    float s = 0.f;
    for (int t = 0; t < nt; ++t) {
      float w = YA[(size_t)n * FA + t];
      int pc = 0;
      for (int b = 0; b < nu; ++b)
        if ((t >> b) & 1) { w *= uv[b]; ++pc; }
      s += (pc & 1) ? -w : w;
    }
    yvA[n] = s;
    float v = s * s;
    float* tot = blk_sums(&v, 1);
    if (threadIdx.x == 0) atomicAdd(&SC[nyA2], tot[0]);
    float vals[8];
    for (int t = 0; t < FA; ++t) {
      float v2 = 0.f;
      if (t < nt) {
        v2 = s;
        for (int b = 0; b < nu; ++b)
          if ((t >> b) & 1) v2 *= uv[b];
      }
      WA[(size_t)n * FA + t] = v2;
      vals[t] = v2;
    }
    float* tot2 = blk_sums(vals, nt);
    if (threadIdx.x == 0)
      for (int c = 0; c < nt; ++c) atomicAdd(&SC[sW2a + c], tot2[c]);
  } else {
    float y = YB[(size_t)n * 4];
    for (int t = 0; t < nd; ++t) y -= SC[Cidx + t] * Pv[(size_t)t * N + n];
    yvB[n] = y;
    float vals[7];
    vals[0] = y * y;
    for (int t = 0; t < 3; ++t) {
      vals[1 + 2 * t] = (t < nd) ? y * Pv[(size_t)t * N + n] : 0.f;
      vals[2 + 2 * t] = (t < nd) ? UvB[(size_t)t * N + n] * y : 0.f;
    }
    float* tot = blk_sums(vals, 1 + 2 * nd);
    if (threadIdx.x == 0) {
      atomicAdd(&SC[nyB2], tot[0]);
      for (int i = 0; i < 2 * nd; ++i) atomicAdd(&SC[dp + i], tot[1 + i]);
    }
    WB[(size_t)n * 4 + 0] = y;
    WB[(size_t)n * 4 + 1] = 0.f;
    WB[(size_t)n * 4 + 2] = 0.f;
    WB[(size_t)n * 4 + 3] = 0.f;
    float yy = y;
    float* tot2 = blk_sums(&yy, 1);
    if (threadIdx.x == 0) atomicAdd(&SC[sW2b], tot2[0]);
  }
}

// per-k post: accum + (dobuild) Uv scale + next-p W build + (dofin) finalize
__global__ void defpost(float* __restrict__ SC, int zzA2, int nt, int nyA2,
                        int zzB2, int nyB2, int dp, int nd,
                        const float* __restrict__ yvA, const float* __restrict__ yvB,
                        float* __restrict__ UvA, float* __restrict__ UvB, int k,
                        const float* __restrict__ ZZB, float* __restrict__ WB,
                        int sW3, int dobuild, int dofin, float* __restrict__ outp) {
  if (blockIdx.x == 0 && threadIdx.x == 0) {
    float vmv = 0.f;
    for (int t = 0; t < nt; ++t) {
      int pc = __popc(t);
      vmv += (pc & 1) ? -SC[zzA2 + t] : SC[zzA2 + t];
    }
    float add = sqrtf(fabsf(vmv / SC[nyA2]));
    float vb = SC[zzB2];
    for (int t = 0; t < nd; ++t) vb -= SC[dp + 2 * t] * SC[dp + 2 * t + 1];
    add += sqrtf(fabsf(vb / SC[nyB2]));
    SC[5] += add;
    if (dofin) {
      const float Ef = (float)EDG;
      float m1 = SC[0] / Ef, v1 = SC[1] / Ef - m1 * m1;
      float m2 = SC[2] / Ef, v2 = SC[3] / Ef - m2 * m2;
      outp[131072] = 0.01f * (v1 + v2) + 0.01f * SC[5];
      outp[393217] = SC[4] / (float)N;
    }
  }
  if (dobuild) {
    int n = blockIdx.x * 256 + threadIdx.x;
    UvA[(size_t)(k - 2) * N + n] = yvA[n] * rsqrtf(SC[nyA2]);
    UvB[(size_t)(k - 2) * N + n] = yvB[n] * rsqrtf(SC[nyB2]);
    float v = ZZB[(size_t)n * 4 + 0] * rsqrtf(SC[nyB2]);
    WB[(size_t)n * 4 + 0] = v;
    WB[(size_t)n * 4 + 1] = 0.f;
    WB[(size_t)n * 4 + 2] = 0.f;
    WB[(size_t)n * 4 + 3] = 0.f;
    float* tot = blk_sums(&v, 1);
    if (threadIdx.x == 0) atomicAdd(&SC[sW3], tot[0]);
  }
}

// ---------------------------------------------------------------------------
extern "C" void kernel_launch(void* const* d_in, const int* in_sizes, int n_in,
                              void* d_out, int out_size, void* d_ws, size_t ws_size,
                              hipStream_t stream) {
  const float* x      = (const float*)d_in[0];
  const int*   ei     = (const int*)  d_in[1];
  const float* gcn1_w = (const float*)d_in[2];
  const float* gcn1_b = (const float*)d_in[3];
  const float* gcn2_w = (const float*)d_in[4];
  const float* gcn2_b = (const float*)d_in[5];
  const float* p1w1   = (const float*)d_in[6];
  const float* p1b1   = (const float*)d_in[7];
  const float* p1w2   = (const float*)d_in[8];
  const float* p1b2   = (const float*)d_in[9];
  const float* p2w1   = (const float*)d_in[10];
  const float* p2b1   = (const float*)d_in[11];
  const float* p2w2   = (const float*)d_in[12];
  const float* p2b2   = (const float*)d_in[13];
  const float* omega1 = (const float*)d_in[14];
  const float* omega2 = (const float*)d_in[15];
  float* out = (float*)d_out;

  float* ws = (float*)d_ws;
  size_t o = 0;
  auto alloc = [&](size_t nf) { float* p = ws + o; o += nf; return p; };
  // ---- zeroed region (one memset): xw1 | h1 | Gd | cnt | deg1 | deg2 | SC ----
  float* xw1  = alloc((size_t)N * 64);
  float* h1   = alloc((size_t)N * 64);
  double* Gd  = (double*)(ws + o); o += 576;
  int* cnt    = (int*)(ws + o);    o += 2 * N;
  float* deg1 = alloc(N);
  float* deg2 = alloc(N);
  float* SC   = alloc(1024);
  const size_t zero_bytes = o * sizeof(float);
  // ---- rest ----
  float* x1   = alloc((size_t)N * 64);
  float* x1w  = alloc((size_t)N * 32);
  float* h2   = alloc((size_t)N * 16);
  float* xo   = alloc((size_t)N * 16);
  float* dis1 = alloc(N);
  float* dis2 = alloc(N);
  float* QA   = alloc((size_t)N * 8);
  float* QB   = alloc((size_t)N * 8);
  float* ZA   = alloc((size_t)N * 8);
  float* ZB   = alloc((size_t)N * 8);
  float* BtA  = alloc((size_t)N * 8);
  float* BtB  = alloc((size_t)N * 8);
  float* V8A  = alloc((size_t)N * 8);
  float* V8B  = alloc((size_t)N * 8);
  float* WA   = alloc((size_t)N * 8);
  float* WB   = alloc((size_t)N * 4);
  float* TA   = alloc((size_t)N * 8);
  float* TB   = alloc((size_t)N * 4);
  float* YA   = alloc((size_t)N * 8);
  float* YB   = alloc((size_t)N * 4);
  float* ZZA  = alloc((size_t)N * 8);
  float* ZZB  = alloc((size_t)N * 4);
  float* P4   = alloc((size_t)N * 4);
  float* yvA  = alloc(N);
  float* yvB  = alloc(N);
  float* UvA  = alloc((size_t)3 * N);
  float* UvB  = alloc((size_t)3 * N);
  float* Pv   = alloc((size_t)3 * N);
  float* SMFA = alloc(64);
  float* SMFB = alloc(64);
  int* rowptr = (int*)alloc(2 * (N + 1) + 2);
  int* cur    = (int*)alloc(2 * N);
  int* col_s  = (int*)alloc(EDG);
  int* perm_s = (int*)alloc(EDG);
  int* col_d  = (int*)alloc(EDG);
  int* perm_d = (int*)alloc(EDG);
  float* w1s  = alloc(EDG);
  float* w1d  = alloc(EDG);
  float* w2s  = alloc(EDG);
  float* w2d  = alloc(EDG);
  if (ws_size < o * sizeof(float)) return;

  const int* rp_s = rowptr;
  const int* rp_d = rowptr + (N + 1);

  int cs = 8;
  auto NS = [&]() { int s = cs; cs += 8; return s; };
  int gslot = 0;
  auto NG = [&]() { int g = gslot; gslot += 24; return g; };

  // ===================== init + CSR =====================
  hipMemsetAsync(ws, 0, zero_bytes, stream);
  hist_edges<<<512, 256, 0, stream>>>(ei, cnt);
  scan2x<<<2, 256, 0, stream>>>(cnt, rowptr, cur);
  scatter_edges<<<512, 256, 0, stream>>>(ei, cur, col_s, perm_s, col_d, perm_d);

  int omA = NS(), omB = NS();

  // ===================== layer 1 =====================
  gemm512k<<<dim3(256, 4), 256, 0, stream>>>(x, p1w1, gcn1_w, xw1, h1);
  edge_gate1c<<<1024, 256, 0, stream>>>(xw1, rp_s, col_s, perm_s, p1b1, p1w2, p1b2,
                                        out + 131073, w1s, deg1, SC);
  gatherdis_om<<<512, 256, 0, stream>>>(out + 131073, perm_d, w1d,
                                        deg1, dis1, omega1, omega2, SC, omA, omB);
  conv1f<<<1024, 256, 0, stream>>>(rp_d, col_d, w1d, h1, dis1, gcn1_b, x1);

  // ===================== layer 2 =====================
  gemm64<<<128, 256, 0, stream>>>(x1, p2w1, gcn2_w, x1w, h2);
  edge_gate2c<<<1024, 256, 0, stream>>>(x1w, rp_s, col_s, perm_s, p2b1, p2w2, p2b2,
                                        out + 262145, w2s, deg2, SC);
  gatherdis_om<<<512, 256, 0, stream>>>(out + 262145, perm_d, w2d,
                                        deg2, dis2, nullptr, nullptr, SC, 0, 0);
  conv2f<<<1024, 256, 0, stream>>>(rp_d, col_d, w2d, h2, dis2, gcn2_b, xo);
  softmax_calib<<<16, 256, 0, stream>>>(xo, out, out + 65536, SC);

  // ===================== batched SVD: one dispatch per power step ===========
  int g0a = NG(), g0b = NG(), g1a = NG(), g1b = NG(), g2a = NG(), g2b = NG();
  int g3a = NG(), g3b = NG(), g4a = NG(), g4b = NG(), g5a = NG(), g5b = NG();
  int c0a = NS(), c0b = NS(), c1a = NS(), c1b = NS(), c2a = NS(), c2b = NS();
  int c3a = NS(), c3b = NS(), c4a = NS(), c4b = NS(), c5a = NS(), c5b = NS();
  spmm8f<0, 6><<<512, 256, 0, stream>>>(rp_s, col_s, w1s, w2s, omega1, omega2,
                                        QA, QB, nullptr, nullptr, Gd + g0a, Gd + g0b,
                                        SC, omA, omB, c0a, c0b);
  spmm8f<1, 8><<<512, 256, 0, stream>>>(rp_d, col_d, w1d, w2d, QA, QB, ZA, ZB,
                                        Gd + g0a, Gd + g0b, Gd + g1a, Gd + g1b,
                                        SC, c0a, c0b, c1a, c1b);
  spmm8f<1, 8><<<512, 256, 0, stream>>>(rp_s, col_s, w1s, w2s, ZA, ZB, QA, QB,
                                        Gd + g1a, Gd + g1b, Gd + g2a, Gd + g2b,
                                        SC, c1a, c1b, c2a, c2b);
  spmm8f<1, 8><<<512, 256, 0, stream>>>(rp_d, col_d, w1d, w2d, QA, QB, ZA, ZB,
                                        Gd + g2a, Gd + g2b, Gd + g3a, Gd + g3b,
                                        SC, c2a, c2b, c3a, c3b);
  spmm8f<1, 8><<<512, 256, 0, stream>>>(rp_s, col_s, w1s, w2s, ZA, ZB, QA, QB,
                                        Gd + g3a, Gd + g3b, Gd + g4a, Gd + g4b,
                                        SC, c3a, c3b, c4a, c4b);
  spmm8f<1, 8><<<512, 256, 0, stream>>>(rp_d, col_d, w1d, w2d, QA, QB, BtA, BtB,
                                        Gd + g4a, Gd + g4b, Gd + g5a, Gd + g5b,
                                        SC, c4a, c4b, c5a, c5b);
  jacobi2<<<1, 64, 0, stream>>>(Gd + g5a, Gd + g5b, SMFA, SMFB);

  // ===================== batched batch3 =====================
  int sWa = NS(), sWb = NS();
  v_scale_pack<<<16, 256, 0, stream>>>(BtA, SMFA, BtB, SMFB, V8A, V8B, WA, WB,
                                       SC, sWa, sWb);
  int sTa = NS(), sTb = NS();
  spmm2<4, 4><<<1024, 256, 0, stream>>>(rp_d, col_d, w1d, w2d, WA, WB, TA, TB,
                                        SC, sWa, sWb, GEPS, sTa, -1, sTb, -1);
  int sYa = NS(), sYb = NS(), nyA = NS(), nyB = NS();
  spmm2<4, 4><<<1024, 256, 0, stream>>>(rp_s, col_s, w1s, w2s, TA, TB, YA, YB,
                                        SC, sTa, sTb, GEPS, sYa, nyA, sYb, nyB);
  int zzA = NS(), zzB = NS();
  spmm2<4, 4><<<1024, 256, 0, stream>>>(rp_d, col_d, w1d, w2d, YA, YB, ZZA, ZZB,
                                        SC, sYa, sYb, GEPS, -1, zzA, -1, zzB);
  int sWp = NS();
  b3post<<<16, 256, 0, stream>>>(YA, YB, ZZB, UvA, UvB, WB, SC, zzA, nyA, zzB, nyB, sWp);
  spmm<4, 0><<<1024, 256, 0, stream>>>(rp_s, col_s, w2s, WB, nullptr, P4, SC, sWp,
                                       GEPS, -1, -1);

  // ===================== batched deflation k=3,4,5 =====================
  int dp_prev = 0, ny_prev = 0;
  for (int k = 3; k <= 5; ++k) {
    const int nu = k - 2, nt = 1 << nu, nd = k - 2;
    const int FA = (k < 5) ? 4 : 8;
    int dWa = NS(), dWb = NS(), C = NS();
    int dTa = NS(), dTb = NS();
    int nyA2 = NS(), nyB2 = NS(), sW2a = NS(), sW2b = NS(), zzA2 = NS(), zzB2 = NS();
    int dp = NS(), sW3 = NS();
    const int pvmode = (k == 3) ? 1 : (k == 4 ? 2 : 3);
    buildAB<<<32, 256, 0, stream>>>(WA, FA, nt, nu, V8A, k, UvA, SC, dWa,
                                    WB, V8B, UvB, nd, dWb, C, P4, Pv,
                                    pvmode, dp_prev, ny_prev);
    if (FA == 4) {
      spmm2<4, 4><<<1024, 256, 0, stream>>>(rp_d, col_d, w1d, w2d, WA, WB, TA, TB,
                                            SC, dWa, dWb, GEPS, dTa, -1, dTb, -1);
      spmm2<4, 4><<<1024, 256, 0, stream>>>(rp_s, col_s, w1s, w2s, TA, TB, YA, YB,
                                            SC, dTa, dTb, GEPS, -1, -1, -1, -1);
    } else {
      spmm2<8, 4><<<1024, 256, 0, stream>>>(rp_d, col_d, w1d, w2d, WA, WB, TA, TB,
                                            SC, dWa, dWb, GEPS, dTa, -1, dTb, -1);
      spmm2<8, 4><<<1024, 256, 0, stream>>>(rp_s, col_s, w1s, w2s, TA, TB, YA, YB,
                                            SC, dTa, dTb, GEPS, -1, -1, -1, -1);
    }
    epibuild<<<32, 256, 0, stream>>>(YA, FA, nt, nu, UvA, yvA, nyA2, WA, sW2a,
                                     YB, Pv, UvB, nd, yvB, C, nyB2, dp, WB, sW2b, SC);
    if (FA == 4)
      spmm2<4, 4><<<1024, 256, 0, stream>>>(rp_d, col_d, w1d, w2d, WA, WB, ZZA, ZZB,
                                            SC, sW2a, sW2b, GEPS, -1, zzA2, -1, zzB2);
    else
      spmm2<8, 4><<<1024, 256, 0, stream>>>(rp_d, col_d, w1d, w2d, WA, WB, ZZA, ZZB,
                                            SC, sW2a, sW2b, GEPS, -1, zzA2, -1, zzB2);
    if (k < 5) {
      defpost<<<16, 256, 0, stream>>>(SC, zzA2, nt, nyA2, zzB2, nyB2, dp, nd,
                                      yvA, yvB, UvA, UvB, k, ZZB, WB, sW3, 1, 0, out);
      spmm<4, 0><<<1024, 256, 0, stream>>>(rp_s, col_s, w2s, WB, nullptr, P4, SC, sW3,
                                           GEPS, -1, -1);
    } else {
      defpost<<<1, 256, 0, stream>>>(SC, zzA2, nt, nyA2, zzB2, nyB2, dp, nd,
                                     yvA, yvB, UvA, UvB, k, ZZB, WB, sW3, 0, 1, out);
    }
    dp_prev = dp; ny_prev = nyB2;
  }
}